// Round 4
// baseline (873.801 us; speedup 1.0000x reference)
//
#include <hip/hip_runtime.h>
#include <math.h>

#define Nn 100000
#define Ee 1600000
#define Gg 2048
#define HH 128
#define BN_EPS 1e-5f

#define NBK 196        // ceil(100000/512) buckets of 512 nodes
#define NSEG 8         // cursor segments (~XCD)
#define CHUNK 3125     // Ee / 512 blocks
#define NBLK_E 512

typedef unsigned int uint32;
typedef unsigned short ushort_t;
typedef __attribute__((ext_vector_type(8))) short short8_t;
typedef __attribute__((ext_vector_type(8))) unsigned short ushort8_t;
typedef __attribute__((ext_vector_type(4))) float f32x4_t;

__device__ __forceinline__ ushort_t f2bf(float f) {
    union { float f; uint32 u; } c; c.f = f;
    uint32 r = (c.u + 0x7FFFu + ((c.u >> 16) & 1u)) >> 16;   // RTNE
    return (ushort_t)r;
}
__device__ __forceinline__ float bflo(uint32 v) {
    union { uint32 u; float f; } c; c.u = v << 16; return c.f;
}
__device__ __forceinline__ float bfhi(uint32 v) {
    union { uint32 u; float f; } c; c.u = v & 0xFFFF0000u; return c.f;
}

// ---------------------------------------------------------------------------
// Count: per-node degree (dst side) + per-(seg,bucket) histogram.
// ---------------------------------------------------------------------------
__global__ __launch_bounds__(256) void k_count(const int* __restrict__ dst,
                                               unsigned* __restrict__ cnt,
                                               unsigned* __restrict__ cnt8) {
    __shared__ unsigned h[NBK];
    int tid = threadIdx.x;
    for (int i = tid; i < NBK; i += 256) h[i] = 0;
    __syncthreads();
    int base = blockIdx.x * CHUNK;
    for (int i = tid; i < CHUNK; i += 256) {
        int d = dst[base + i];
        atomicAdd(&cnt[d], 1u);
        atomicAdd(&h[d >> 9], 1u);
    }
    __syncthreads();
    int seg = blockIdx.x & (NSEG - 1);
    for (int i = tid; i < NBK; i += 256)
        if (h[i]) atomicAdd(&cnt8[seg * NBK + i], h[i]);
}

__global__ __launch_bounds__(256) void k_dis(const unsigned* __restrict__ cnt,
                                             float* __restrict__ dis) {
    int i = blockIdx.x * 256 + threadIdx.x;
    if (i < Nn) dis[i] = rsqrtf((float)cnt[i] + 1.0f);
}

// ---------------------------------------------------------------------------
// Exclusive prefix scan of cnt -> rowptr (3 kernels). 391 blocks of 256.
// ---------------------------------------------------------------------------
__global__ __launch_bounds__(256) void k_scan1(const unsigned* __restrict__ cnt,
                                               int* __restrict__ rowptr,
                                               int* __restrict__ bsum) {
    __shared__ int tmp[256];
    int t = threadIdx.x;
    int i = blockIdx.x * 256 + t;
    int v = (i < Nn) ? (int)cnt[i] : 0;
    tmp[t] = v;
    __syncthreads();
    for (int off = 1; off < 256; off <<= 1) {
        int u = (t >= off) ? tmp[t - off] : 0;
        __syncthreads();
        tmp[t] += u;
        __syncthreads();
    }
    if (i < Nn) rowptr[i] = tmp[t] - v;
    if (t == 255) bsum[blockIdx.x] = tmp[t];
}

__global__ void k_scan2(int* __restrict__ bsum, int nb) {
    __shared__ int tmp[512];
    int t = threadIdx.x;
    int v = (t < nb) ? bsum[t] : 0;
    tmp[t] = v;
    __syncthreads();
    for (int off = 1; off < 512; off <<= 1) {
        int u = (t >= off) ? tmp[t - off] : 0;
        __syncthreads();
        tmp[t] += u;
        __syncthreads();
    }
    if (t < nb) bsum[t] = tmp[t] - v;
}

__global__ __launch_bounds__(256) void k_scan3(int* __restrict__ rowptr,
                                               const int* __restrict__ bsum) {
    int i = blockIdx.x * 256 + threadIdx.x;
    if (i < Nn) rowptr[i] += bsum[blockIdx.x];
    if (i == 0) rowptr[Nn] = Ee;
}

// cursor8[s][b] = rowptr[bucket_start] + prefix of cnt8 over segments
__global__ void k_bscan(const int* __restrict__ rowptr,
                        const unsigned* __restrict__ cnt8,
                        int* __restrict__ cursor8) {
    int b = threadIdx.x;
    if (b < NBK) {
        int n0 = b * 512; if (n0 > Nn) n0 = Nn;
        int run = rowptr[n0];
        for (int s = 0; s < NSEG; ++s) {
            cursor8[s * NBK + b] = run;
            run += (int)cnt8[s * NBK + b];
        }
    }
}

// ---------------------------------------------------------------------------
// Fill pass 1: append packed (dst_local<<17 | src) into bucket regions.
// Segmented cursors keep concurrent appends on few hot lines per segment.
// ---------------------------------------------------------------------------
__global__ __launch_bounds__(256) void k_fill1(const int* __restrict__ src,
                                               const int* __restrict__ dst,
                                               int* __restrict__ cursor8,
                                               uint32* __restrict__ pairs) {
    int base = blockIdx.x * CHUNK;
    int seg = blockIdx.x & (NSEG - 1);
    for (int i = threadIdx.x; i < CHUNK; i += 256) {
        int e = base + i;
        int s = src[e], d = dst[e];
        int b = d >> 9;
        int pos = atomicAdd(&cursor8[seg * NBK + b], 1);
        pairs[pos] = ((uint32)(d & 511) << 17) | (uint32)s;
    }
}

// ---------------------------------------------------------------------------
// Fill pass 2: one block per bucket; scatter within a 32KB region via LDS
// per-node cursors.
// ---------------------------------------------------------------------------
__global__ __launch_bounds__(256) void k_fill2(const int* __restrict__ rowptr,
                                               const uint32* __restrict__ pairs,
                                               int* __restrict__ csr_src) {
    __shared__ int lcur[512];
    int b = blockIdx.x;
    int node0 = b * 512;
    for (int i = threadIdx.x; i < 512; i += 256) {
        int n = node0 + i;
        lcur[i] = (n < Nn) ? rowptr[n] : 0;
    }
    int beg = rowptr[node0 < Nn ? node0 : Nn];
    int nend = node0 + 512; if (nend > Nn) nend = Nn;
    int endp = rowptr[nend];
    __syncthreads();
    for (int j = beg + threadIdx.x; j < endp; j += 256) {
        uint32 p = pairs[j];
        int dl = (int)(p >> 17);
        int s = (int)(p & 0x1FFFFu);
        int pos = atomicAdd(&lcur[dl], 1);
        csr_src[pos] = s;
    }
}

// ---------------------------------------------------------------------------
// MFMA GEMM: XW' = dis * (Xin @ W + b), bf16 out.
// Xin: layer 0 = fp32 raw; layers 1,2 = packed-bf16 HP with fused BN+ReLU.
// Block 256 thr = 4 waves; 64 rows/block; N=128 (8 ntiles), K=128 (4 ktiles).
// Wlds col-major [col][k] stride 136 (2-way conflicts only, free).
// ---------------------------------------------------------------------------
__global__ __launch_bounds__(256) void k_gemm(const float* __restrict__ Xf,
                                              const uint32* __restrict__ Xb,
                                              const float* __restrict__ W,
                                              const float* __restrict__ Bv,
                                              const float* __restrict__ bnp,
                                              const float* __restrict__ dis,
                                              ushort_t* __restrict__ XWb) {
    __shared__ ushort_t Wlds[128 * 136];
    __shared__ ushort_t Xlds[64 * 136];
    const int tid = threadIdx.x;
    const int rowbase = blockIdx.x * 64;

    // Stage W: Wlds[col][k] = bf16(W[k][col])
    {
        int col4 = tid & 31, krow = tid >> 5;
        const float4* W4 = (const float4*)W;
#pragma unroll
        for (int it = 0; it < 16; ++it) {
            int k = krow + it * 8;
            float4 v = W4[k * 32 + col4];
            int c0 = col4 * 4;
            Wlds[(c0 + 0) * 136 + k] = f2bf(v.x);
            Wlds[(c0 + 1) * 136 + k] = f2bf(v.y);
            Wlds[(c0 + 2) * 136 + k] = f2bf(v.z);
            Wlds[(c0 + 3) * 136 + k] = f2bf(v.w);
        }
    }
    // Stage X tile (64 rows x 128), fused BN+ReLU on bf16 path
    {
        int row = tid >> 2, q = tid & 3;
        int g = rowbase + row;
        if (bnp == nullptr) {
            const float4* Xr = (const float4*)(Xf + (size_t)g * 128);
#pragma unroll
            for (int it = 0; it < 8; ++it) {
                int c4 = q + it * 4;
                float4 v;
                if (g < Nn) v = Xr[c4];
                else { v.x = v.y = v.z = v.w = 0.f; }
                ushort4 o;
                o.x = f2bf(v.x); o.y = f2bf(v.y); o.z = f2bf(v.z); o.w = f2bf(v.w);
                *(ushort4*)&Xlds[row * 136 + c4 * 4] = o;
            }
        } else {
            const uint4* Hr = (const uint4*)(Xb + (size_t)g * 64);
#pragma unroll
            for (int it = 0; it < 4; ++it) {
                int i4 = q + it * 4;
                int c0 = i4 * 8;
                ushort8_t o;
                if (g < Nn) {
                    uint4 u = Hr[i4];
                    float4 sca = *(const float4*)&bnp[c0];
                    float4 scb = *(const float4*)&bnp[c0 + 4];
                    float4 sha = *(const float4*)&bnp[128 + c0];
                    float4 shb = *(const float4*)&bnp[128 + c0 + 4];
                    o[0] = f2bf(fmaxf(fmaf(bflo(u.x), sca.x, sha.x), 0.f));
                    o[1] = f2bf(fmaxf(fmaf(bfhi(u.x), sca.y, sha.y), 0.f));
                    o[2] = f2bf(fmaxf(fmaf(bflo(u.y), sca.z, sha.z), 0.f));
                    o[3] = f2bf(fmaxf(fmaf(bfhi(u.y), sca.w, sha.w), 0.f));
                    o[4] = f2bf(fmaxf(fmaf(bflo(u.z), scb.x, shb.x), 0.f));
                    o[5] = f2bf(fmaxf(fmaf(bfhi(u.z), scb.y, shb.y), 0.f));
                    o[6] = f2bf(fmaxf(fmaf(bflo(u.w), scb.z, shb.z), 0.f));
                    o[7] = f2bf(fmaxf(fmaf(bfhi(u.w), scb.w, shb.w), 0.f));
                } else {
                    for (int j = 0; j < 8; ++j) o[j] = 0;
                }
                *(ushort8_t*)&Xlds[row * 136 + c0] = o;
            }
        }
    }
    __syncthreads();

    const int wid = tid >> 6, lane = tid & 63;
    const int arow = wid * 16 + (lane & 15);
    const int koff = (lane >> 4) * 8;
    const int bcol = lane & 15;

    f32x4_t acc[8];
#pragma unroll
    for (int nt = 0; nt < 8; ++nt) acc[nt] = (f32x4_t){0.f, 0.f, 0.f, 0.f};

#pragma unroll
    for (int kt = 0; kt < 4; ++kt) {
        short8_t a = *(const short8_t*)&Xlds[arow * 136 + kt * 32 + koff];
#pragma unroll
        for (int nt = 0; nt < 8; ++nt) {
            short8_t b = *(const short8_t*)&Wlds[(nt * 16 + bcol) * 136 + kt * 32 + koff];
            acc[nt] = __builtin_amdgcn_mfma_f32_16x16x32_bf16(a, b, acc[nt], 0, 0, 0);
        }
    }

    // Epilogue: out[row][col] = bf16((acc + bias[col]) * dis[row])
    int r0 = rowbase + wid * 16 + (lane >> 4) * 4;
    float dv[4];
#pragma unroll
    for (int i = 0; i < 4; ++i) dv[i] = (r0 + i < Nn) ? dis[r0 + i] : 0.f;
#pragma unroll
    for (int nt = 0; nt < 8; ++nt) {
        int col = nt * 16 + bcol;
        float bs = Bv[col];
#pragma unroll
        for (int i = 0; i < 4; ++i) {
            int rg = r0 + i;
            if (rg < Nn) XWb[(size_t)rg * 128 + col] = f2bf((acc[nt][i] + bs) * dv[i]);
        }
    }
}

// ---------------------------------------------------------------------------
// Aggregate: HP[i] = dis[i] * (sum_{e:dst=i} XW'[src_e] + XW'[i]); bf16 out.
// One wave per node; lane holds one packed bf16x2 word. Unroll x4 for MLP.
// ---------------------------------------------------------------------------
__global__ __launch_bounds__(256) void k_agg(const uint32* __restrict__ XW32,
                                             const float* __restrict__ dis,
                                             const int* __restrict__ rowptr,
                                             const int* __restrict__ csr_src,
                                             uint32* __restrict__ HP32) {
    int node = blockIdx.x * 4 + (threadIdx.x >> 6);
    int l = threadIdx.x & 63;
    int beg = rowptr[node], end = rowptr[node + 1];
    float ax = 0.f, ay = 0.f;
    int j = beg;
    for (; j + 4 <= end; j += 4) {
        int s0 = csr_src[j + 0];
        int s1 = csr_src[j + 1];
        int s2 = csr_src[j + 2];
        int s3 = csr_src[j + 3];
        uint32 v0 = XW32[(size_t)s0 * 64 + l];
        uint32 v1 = XW32[(size_t)s1 * 64 + l];
        uint32 v2 = XW32[(size_t)s2 * 64 + l];
        uint32 v3 = XW32[(size_t)s3 * 64 + l];
        ax += bflo(v0); ay += bfhi(v0);
        ax += bflo(v1); ay += bfhi(v1);
        ax += bflo(v2); ay += bfhi(v2);
        ax += bflo(v3); ay += bfhi(v3);
    }
    for (; j < end; ++j) {
        int s = csr_src[j];
        uint32 v = XW32[(size_t)s * 64 + l];
        ax += bflo(v); ay += bfhi(v);
    }
    uint32 vs = XW32[(size_t)node * 64 + l];
    ax += bflo(vs); ay += bfhi(vs);
    float d = dis[node];
    HP32[(size_t)node * 64 + l] =
        (uint32)f2bf(ax * d) | ((uint32)f2bf(ay * d) << 16);
}

// ---------------------------------------------------------------------------
// BN stats over packed-bf16 HP: per-feature sum & sumsq.
// ---------------------------------------------------------------------------
__global__ __launch_bounds__(256) void k_stats(const uint32* __restrict__ HP32,
                                               float* __restrict__ stats) {
    int l = threadIdx.x & 63;
    int rg = threadIdx.x >> 6;
    float s0 = 0.f, s1 = 0.f, q0 = 0.f, q1 = 0.f;
    for (int r = blockIdx.x * 4 + rg; r < Nn; r += gridDim.x * 4) {
        uint32 v = HP32[(size_t)r * 64 + l];
        float a = bflo(v), b = bfhi(v);
        s0 += a; s1 += b;
        q0 = fmaf(a, a, q0); q1 = fmaf(b, b, q1);
    }
    __shared__ float sh[256];
    sh[threadIdx.x] = s0; __syncthreads();
    if (rg == 0) atomicAdd(&stats[2 * l], sh[l] + sh[l + 64] + sh[l + 128] + sh[l + 192]);
    __syncthreads();
    sh[threadIdx.x] = s1; __syncthreads();
    if (rg == 0) atomicAdd(&stats[2 * l + 1], sh[l] + sh[l + 64] + sh[l + 128] + sh[l + 192]);
    __syncthreads();
    sh[threadIdx.x] = q0; __syncthreads();
    if (rg == 0) atomicAdd(&stats[128 + 2 * l], sh[l] + sh[l + 64] + sh[l + 128] + sh[l + 192]);
    __syncthreads();
    sh[threadIdx.x] = q1; __syncthreads();
    if (rg == 0) atomicAdd(&stats[128 + 2 * l + 1], sh[l] + sh[l + 64] + sh[l + 128] + sh[l + 192]);
}

__global__ void k_bnfinal(const float* __restrict__ stats,
                          const float* __restrict__ g,
                          const float* __restrict__ bt,
                          float* __restrict__ bnp) {
    int f = threadIdx.x;
    float mu  = stats[f] * (1.0f / Nn);
    float var = stats[128 + f] * (1.0f / Nn) - mu * mu;
    float sc  = g[f] * rsqrtf(var + BN_EPS);
    bnp[f]       = sc;
    bnp[128 + f] = bt[f] - mu * sc;
}

// ---------------------------------------------------------------------------
// Fused BN+ReLU + mean-pool + FC1(relu) + FC2. One block (128 thr) per graph.
// ---------------------------------------------------------------------------
__global__ __launch_bounds__(128) void k_pool_fc(const ushort_t* __restrict__ HP16,
                                                 const float* __restrict__ bnp,
                                                 const int* __restrict__ batch,
                                                 const float* __restrict__ fcw1,
                                                 const float* __restrict__ fcb1,
                                                 const float* __restrict__ fcw2,
                                                 const float* __restrict__ fcb2,
                                                 float* __restrict__ out) {
    int g = blockIdx.x;
    int t = threadIdx.x;
    int lo = 0, hi = Nn;
    while (lo < hi) { int mid = (lo + hi) >> 1; if (batch[mid] < g) lo = mid + 1; else hi = mid; }
    int start = lo;
    hi = Nn;
    while (lo < hi) { int mid = (lo + hi) >> 1; if (batch[mid] < g + 1) lo = mid + 1; else hi = mid; }
    int end = lo;

    float sc = bnp[t], sh = bnp[128 + t];
    float acc = 0.f;
    for (int i = start; i < end; ++i) {
        union { uint32 u; float f; } c;
        c.u = (uint32)HP16[(size_t)i * 128 + t] << 16;
        acc += fmaxf(fmaf(c.f, sc, sh), 0.f);
    }
    float inv = 1.0f / fmaxf((float)(end - start), 1.0f);

    __shared__ float p[128];
    __shared__ float h1[64];
    p[t] = acc * inv;
    __syncthreads();
    if (t < 64) {
        float s = fcb1[t];
        for (int k = 0; k < 128; ++k) s = fmaf(p[k], fcw1[k * 64 + t], s);
        h1[t] = fmaxf(s, 0.f);
    }
    __syncthreads();
    if (t < 64) {
        float v = h1[t] * fcw2[t];
        for (int off = 32; off > 0; off >>= 1) v += __shfl_down(v, off, 64);
        if (t == 0) out[g] = v + fcb2[0];
    }
}

// ---------------------------------------------------------------------------
extern "C" void kernel_launch(void* const* d_in, const int* in_sizes, int n_in,
                              void* d_out, int out_size, void* d_ws, size_t ws_size,
                              hipStream_t stream) {
    const float* x     = (const float*)d_in[0];
    const int*   ei    = (const int*)d_in[1];
    const int*   batch = (const int*)d_in[2];
    const float* W1  = (const float*)d_in[3];
    const float* b1  = (const float*)d_in[4];
    const float* g1  = (const float*)d_in[5];
    const float* bt1 = (const float*)d_in[6];
    const float* W2  = (const float*)d_in[7];
    const float* b2  = (const float*)d_in[8];
    const float* g2  = (const float*)d_in[9];
    const float* bt2 = (const float*)d_in[10];
    const float* W3  = (const float*)d_in[11];
    const float* b3  = (const float*)d_in[12];
    const float* g3  = (const float*)d_in[13];
    const float* bt3 = (const float*)d_in[14];
    const float* fcw1 = (const float*)d_in[15];
    const float* fcb1 = (const float*)d_in[16];
    const float* fcw2 = (const float*)d_in[17];
    const float* fcb2 = (const float*)d_in[18];
    float* out = (float*)d_out;

    // Workspace layout
    ushort_t* XWb    = (ushort_t*)d_ws;                       // [N*128] bf16
    uint32*   HP32   = (uint32*)(XWb + (size_t)Nn * HH);      // [N*64] bf16x2
    float*    dis    = (float*)(HP32 + (size_t)Nn * 64);      // [N]
    unsigned* cnt    = (unsigned*)(dis + Nn);                 // [N]
    unsigned* cnt8   = cnt + Nn;                              // [8*196]
    int*      rowptr = (int*)(cnt8 + NSEG * NBK);             // [N+1]
    int*      bsum   = rowptr + (Nn + 1);                     // [512]
    int*      cursor8 = bsum + 512;                           // [8*196]
    uint32*   pairs  = (uint32*)(cursor8 + NSEG * NBK);       // [E]
    int*      csr_src = (int*)(pairs + Ee);                   // [E]
    float*    stats  = (float*)(csr_src + Ee);                // [3*256]
    float*    bnp    = stats + 768;                           // [3*256]

    hipMemsetAsync(cnt, 0, (size_t)(Nn + NSEG * NBK) * sizeof(unsigned), stream);
    hipMemsetAsync(stats, 0, 768 * sizeof(float), stream);

    const int* src = ei;
    const int* dst = ei + Ee;

    k_count<<<NBLK_E, 256, 0, stream>>>(dst, cnt, cnt8);
    k_dis<<<(Nn + 255) / 256, 256, 0, stream>>>(cnt, dis);
    int nblk = (Nn + 255) / 256;  // 391
    k_scan1<<<nblk, 256, 0, stream>>>(cnt, rowptr, bsum);
    k_scan2<<<1, 512, 0, stream>>>(bsum, nblk);
    k_scan3<<<nblk, 256, 0, stream>>>(rowptr, bsum);
    k_bscan<<<1, 256, 0, stream>>>(rowptr, cnt8, cursor8);
    k_fill1<<<NBLK_E, 256, 0, stream>>>(src, dst, cursor8, pairs);
    k_fill2<<<NBK, 256, 0, stream>>>(rowptr, pairs, csr_src);

    const float* Ws_[3]  = {W1, W2, W3};
    const float* bs_[3]  = {b1, b2, b3};
    const float* gs_[3]  = {g1, g2, g3};
    const float* bts_[3] = {bt1, bt2, bt3};
    const int ngemm = (Nn + 63) / 64;  // 1563
    for (int l = 0; l < 3; ++l) {
        const float* bnp_in = (l == 0) ? nullptr : (bnp + (l - 1) * 256);
        k_gemm<<<ngemm, 256, 0, stream>>>(x, HP32, Ws_[l], bs_[l], bnp_in, dis, XWb);
        k_agg<<<Nn / 4, 256, 0, stream>>>((const uint32*)XWb, dis, rowptr, csr_src, HP32);
        k_stats<<<1024, 256, 0, stream>>>(HP32, stats + l * 256);
        k_bnfinal<<<1, 128, 0, stream>>>(stats + l * 256, gs_[l], bts_[l], bnp + l * 256);
    }
    k_pool_fc<<<Gg, 128, 0, stream>>>((const ushort_t*)HP32, bnp + 512, batch,
                                      fcw1, fcb1, fcw2, fcb2, out);
}

// Round 5
// 621.126 us; speedup vs baseline: 1.4068x; 1.4068x over previous
//
#include <hip/hip_runtime.h>
#include <math.h>

#define Nn 100000
#define Ee 1600000
#define Gg 2048
#define HH 128
#define BN_EPS 1e-5f

#define NBK 196        // ceil(100000/512) buckets of 512 nodes
#define CHUNK 3125     // Ee / 512 blocks
#define NBLK_E 512

typedef unsigned int uint32;
typedef unsigned short ushort_t;
typedef __attribute__((ext_vector_type(8))) short short8_t;
typedef __attribute__((ext_vector_type(8))) unsigned short ushort8_t;
typedef __attribute__((ext_vector_type(4))) float f32x4_t;

__device__ __forceinline__ ushort_t f2bf(float f) {
    union { float f; uint32 u; } c; c.f = f;
    uint32 r = (c.u + 0x7FFFu + ((c.u >> 16) & 1u)) >> 16;   // RTNE
    return (ushort_t)r;
}
__device__ __forceinline__ float bflo(uint32 v) {
    union { uint32 u; float f; } c; c.u = v << 16; return c.f;
}
__device__ __forceinline__ float bfhi(uint32 v) {
    union { uint32 u; float f; } c; c.u = v & 0xFFFF0000u; return c.f;
}

// ---------------------------------------------------------------------------
// Count: per-node degree (dst side) + per-BLOCK bucket histogram (stored).
// ---------------------------------------------------------------------------
__global__ __launch_bounds__(256) void k_count(const int* __restrict__ dst,
                                               unsigned* __restrict__ cnt,
                                               int* __restrict__ blkhist) {
    __shared__ unsigned h[NBK];
    int tid = threadIdx.x;
    for (int i = tid; i < NBK; i += 256) h[i] = 0;
    __syncthreads();
    int base = blockIdx.x * CHUNK;
    for (int i = tid; i < CHUNK; i += 256) {
        int d = dst[base + i];
        atomicAdd(&cnt[d], 1u);
        atomicAdd(&h[d >> 9], 1u);
    }
    __syncthreads();
    for (int i = tid; i < NBK; i += 256)
        blkhist[blockIdx.x * NBK + i] = (int)h[i];
}

__global__ __launch_bounds__(256) void k_dis(const unsigned* __restrict__ cnt,
                                             float* __restrict__ dis) {
    int i = blockIdx.x * 256 + threadIdx.x;
    if (i < Nn) dis[i] = rsqrtf((float)cnt[i] + 1.0f);
}

// ---------------------------------------------------------------------------
// Exclusive prefix scan of cnt -> rowptr (3 kernels). 391 blocks of 256.
// ---------------------------------------------------------------------------
__global__ __launch_bounds__(256) void k_scan1(const unsigned* __restrict__ cnt,
                                               int* __restrict__ rowptr,
                                               int* __restrict__ bsum) {
    __shared__ int tmp[256];
    int t = threadIdx.x;
    int i = blockIdx.x * 256 + t;
    int v = (i < Nn) ? (int)cnt[i] : 0;
    tmp[t] = v;
    __syncthreads();
    for (int off = 1; off < 256; off <<= 1) {
        int u = (t >= off) ? tmp[t - off] : 0;
        __syncthreads();
        tmp[t] += u;
        __syncthreads();
    }
    if (i < Nn) rowptr[i] = tmp[t] - v;
    if (t == 255) bsum[blockIdx.x] = tmp[t];
}

__global__ void k_scan2(int* __restrict__ bsum, int nb) {
    __shared__ int tmp[512];
    int t = threadIdx.x;
    int v = (t < nb) ? bsum[t] : 0;
    tmp[t] = v;
    __syncthreads();
    for (int off = 1; off < 512; off <<= 1) {
        int u = (t >= off) ? tmp[t - off] : 0;
        __syncthreads();
        tmp[t] += u;
        __syncthreads();
    }
    if (t < nb) bsum[t] = tmp[t] - v;
}

__global__ __launch_bounds__(256) void k_scan3(int* __restrict__ rowptr,
                                               const int* __restrict__ bsum) {
    int i = blockIdx.x * 256 + threadIdx.x;
    if (i < Nn) rowptr[i] += bsum[blockIdx.x];
    if (i == 0) rowptr[Nn] = Ee;
}

// ---------------------------------------------------------------------------
// Per-bucket scan across blocks: blkoff[b][bucket] = rowptr[bucket_base] +
// sum_{b'<b} blkhist[b'][bucket]. One workgroup (512 thr) per bucket.
// ---------------------------------------------------------------------------
__global__ __launch_bounds__(512) void k_bscan(const int* __restrict__ rowptr,
                                               const int* __restrict__ blkhist,
                                               int* __restrict__ blkoff) {
    __shared__ int tmp[512];
    int bucket = blockIdx.x;
    int t = threadIdx.x;
    int v = blkhist[t * NBK + bucket];
    tmp[t] = v;
    __syncthreads();
    for (int off = 1; off < 512; off <<= 1) {
        int u = (t >= off) ? tmp[t - off] : 0;
        __syncthreads();
        tmp[t] += u;
        __syncthreads();
    }
    int base = rowptr[bucket * 512];   // bucket*512 <= 99840 < Nn
    blkoff[t * NBK + bucket] = base + tmp[t] - v;
}

// ---------------------------------------------------------------------------
// Fill pass 1: counting-sort append. Local rank via LDS atomics only;
// each (block,bucket) writes a private contiguous run. NO global atomics.
// ---------------------------------------------------------------------------
__global__ __launch_bounds__(256) void k_fill1(const int* __restrict__ src,
                                               const int* __restrict__ dst,
                                               const int* __restrict__ blkoff,
                                               uint32* __restrict__ pairs) {
    __shared__ int loff[NBK];
    __shared__ unsigned lh[NBK];
    int tid = threadIdx.x;
    for (int i = tid; i < NBK; i += 256) {
        loff[i] = blkoff[blockIdx.x * NBK + i];
        lh[i] = 0;
    }
    __syncthreads();
    int base = blockIdx.x * CHUNK;
    for (int i = tid; i < CHUNK; i += 256) {
        int e = base + i;
        int s = src[e], d = dst[e];
        int b = d >> 9;
        int r = (int)atomicAdd(&lh[b], 1u);
        pairs[loff[b] + r] = ((uint32)(d & 511) << 17) | (uint32)s;
    }
}

// ---------------------------------------------------------------------------
// Fill pass 2: one block (1024 thr) per bucket; scatter within the 32KB
// bucket region via LDS per-node cursors.
// ---------------------------------------------------------------------------
__global__ __launch_bounds__(1024) void k_fill2(const int* __restrict__ rowptr,
                                                const uint32* __restrict__ pairs,
                                                int* __restrict__ csr_src) {
    __shared__ int lcur[512];
    int b = blockIdx.x;
    int node0 = b * 512;
    for (int i = threadIdx.x; i < 512; i += 1024) {
        int n = node0 + i;
        lcur[i] = (n < Nn) ? rowptr[n] : 0;
    }
    int beg = rowptr[node0];
    int nend = node0 + 512; if (nend > Nn) nend = Nn;
    int endp = rowptr[nend];
    __syncthreads();
    for (int j = beg + threadIdx.x; j < endp; j += 1024) {
        uint32 p = pairs[j];
        int dl = (int)(p >> 17);
        int s = (int)(p & 0x1FFFFu);
        int pos = atomicAdd(&lcur[dl], 1);
        csr_src[pos] = s;
    }
}

// ---------------------------------------------------------------------------
// MFMA GEMM: XW' = dis * (Xin @ W + b), bf16 out. W staged once per block;
// grid-stride over 64-row tiles.
// ---------------------------------------------------------------------------
__global__ __launch_bounds__(256) void k_gemm(const float* __restrict__ Xf,
                                              const uint32* __restrict__ Xb,
                                              const float* __restrict__ W,
                                              const float* __restrict__ Bv,
                                              const float* __restrict__ bnp,
                                              const float* __restrict__ dis,
                                              ushort_t* __restrict__ XWb) {
    __shared__ ushort_t Wlds[128 * 136];
    __shared__ ushort_t Xlds[64 * 136];
    const int tid = threadIdx.x;

    // Stage W: Wlds[col][k] = bf16(W[k][col])
    {
        int col4 = tid & 31, krow = tid >> 5;
        const float4* W4 = (const float4*)W;
#pragma unroll
        for (int it = 0; it < 16; ++it) {
            int k = krow + it * 8;
            float4 v = W4[k * 32 + col4];
            int c0 = col4 * 4;
            Wlds[(c0 + 0) * 136 + k] = f2bf(v.x);
            Wlds[(c0 + 1) * 136 + k] = f2bf(v.y);
            Wlds[(c0 + 2) * 136 + k] = f2bf(v.z);
            Wlds[(c0 + 3) * 136 + k] = f2bf(v.w);
        }
    }

    const int wid = tid >> 6, lane = tid & 63;
    const int arow = wid * 16 + (lane & 15);
    const int koff = (lane >> 4) * 8;
    const int bcol = lane & 15;
    const int ntiles = (Nn + 63) / 64;  // 1563

    for (int t = blockIdx.x; t < ntiles; t += gridDim.x) {
        const int rowbase = t * 64;
        __syncthreads();  // previous tile's Xlds fully consumed
        {
            int row = tid >> 2, q = tid & 3;
            int g = rowbase + row;
            if (bnp == nullptr) {
                const float4* Xr = (const float4*)(Xf + (size_t)g * 128);
#pragma unroll
                for (int it = 0; it < 8; ++it) {
                    int c4 = q + it * 4;
                    float4 v;
                    if (g < Nn) v = Xr[c4];
                    else { v.x = v.y = v.z = v.w = 0.f; }
                    ushort4 o;
                    o.x = f2bf(v.x); o.y = f2bf(v.y); o.z = f2bf(v.z); o.w = f2bf(v.w);
                    *(ushort4*)&Xlds[row * 136 + c4 * 4] = o;
                }
            } else {
                const uint4* Hr = (const uint4*)(Xb + (size_t)g * 64);
#pragma unroll
                for (int it = 0; it < 4; ++it) {
                    int i4 = q + it * 4;
                    int c0 = i4 * 8;
                    ushort8_t o;
                    if (g < Nn) {
                        uint4 u = Hr[i4];
                        float4 sca = *(const float4*)&bnp[c0];
                        float4 scb = *(const float4*)&bnp[c0 + 4];
                        float4 sha = *(const float4*)&bnp[128 + c0];
                        float4 shb = *(const float4*)&bnp[128 + c0 + 4];
                        o[0] = f2bf(fmaxf(fmaf(bflo(u.x), sca.x, sha.x), 0.f));
                        o[1] = f2bf(fmaxf(fmaf(bfhi(u.x), sca.y, sha.y), 0.f));
                        o[2] = f2bf(fmaxf(fmaf(bflo(u.y), sca.z, sha.z), 0.f));
                        o[3] = f2bf(fmaxf(fmaf(bfhi(u.y), sca.w, sha.w), 0.f));
                        o[4] = f2bf(fmaxf(fmaf(bflo(u.z), scb.x, shb.x), 0.f));
                        o[5] = f2bf(fmaxf(fmaf(bfhi(u.z), scb.y, shb.y), 0.f));
                        o[6] = f2bf(fmaxf(fmaf(bflo(u.w), scb.z, shb.z), 0.f));
                        o[7] = f2bf(fmaxf(fmaf(bfhi(u.w), scb.w, shb.w), 0.f));
                    } else {
                        for (int j = 0; j < 8; ++j) o[j] = 0;
                    }
                    *(ushort8_t*)&Xlds[row * 136 + c0] = o;
                }
            }
        }
        __syncthreads();

        f32x4_t acc[8];
#pragma unroll
        for (int nt = 0; nt < 8; ++nt) acc[nt] = (f32x4_t){0.f, 0.f, 0.f, 0.f};

#pragma unroll
        for (int kt = 0; kt < 4; ++kt) {
            short8_t a = *(const short8_t*)&Xlds[arow * 136 + kt * 32 + koff];
#pragma unroll
            for (int nt = 0; nt < 8; ++nt) {
                short8_t b = *(const short8_t*)&Wlds[(nt * 16 + bcol) * 136 + kt * 32 + koff];
                acc[nt] = __builtin_amdgcn_mfma_f32_16x16x32_bf16(a, b, acc[nt], 0, 0, 0);
            }
        }

        int r0 = rowbase + wid * 16 + (lane >> 4) * 4;
        float dv[4];
#pragma unroll
        for (int i = 0; i < 4; ++i) dv[i] = (r0 + i < Nn) ? dis[r0 + i] : 0.f;
#pragma unroll
        for (int nt = 0; nt < 8; ++nt) {
            int col = nt * 16 + bcol;
            float bs = Bv[col];
#pragma unroll
            for (int i = 0; i < 4; ++i) {
                int rg = r0 + i;
                if (rg < Nn) XWb[(size_t)rg * 128 + col] = f2bf((acc[nt][i] + bs) * dv[i]);
            }
        }
    }
}

// ---------------------------------------------------------------------------
// Aggregate: HP[i] = dis[i]*(sum XW'[src] + XW'[i]); bf16 out.
// 2 nodes per wave: lanes 0-31 node A, lanes 32-63 node B, 8B/lane rows.
// 4-deep unroll per half -> 8 gathers in flight per wave.
// ---------------------------------------------------------------------------
__global__ __launch_bounds__(256) void k_agg(const uint32* __restrict__ XW32,
                                             const float* __restrict__ dis,
                                             const int* __restrict__ rowptr,
                                             const int* __restrict__ csr_src,
                                             uint32* __restrict__ HP32) {
    int wv = blockIdx.x * 4 + (threadIdx.x >> 6);   // 12500*4 waves
    int lane = threadIdx.x & 63;
    int half = lane >> 5, li = lane & 31;
    int node = wv * 2 + half;                        // exact: 100000 nodes
    const uint2* XW64 = (const uint2*)XW32;          // row = 32 uint2
    int beg = rowptr[node], end = rowptr[node + 1];
    float a0 = 0.f, a1 = 0.f, a2 = 0.f, a3 = 0.f;
    int j = beg;
    for (; j + 4 <= end; j += 4) {
        int s0 = csr_src[j + 0];
        int s1 = csr_src[j + 1];
        int s2 = csr_src[j + 2];
        int s3 = csr_src[j + 3];
        uint2 v0 = XW64[(size_t)s0 * 32 + li];
        uint2 v1 = XW64[(size_t)s1 * 32 + li];
        uint2 v2 = XW64[(size_t)s2 * 32 + li];
        uint2 v3 = XW64[(size_t)s3 * 32 + li];
        a0 += bflo(v0.x); a1 += bfhi(v0.x); a2 += bflo(v0.y); a3 += bfhi(v0.y);
        a0 += bflo(v1.x); a1 += bfhi(v1.x); a2 += bflo(v1.y); a3 += bfhi(v1.y);
        a0 += bflo(v2.x); a1 += bfhi(v2.x); a2 += bflo(v2.y); a3 += bfhi(v2.y);
        a0 += bflo(v3.x); a1 += bfhi(v3.x); a2 += bflo(v3.y); a3 += bfhi(v3.y);
    }
    for (; j < end; ++j) {
        int s = csr_src[j];
        uint2 v = XW64[(size_t)s * 32 + li];
        a0 += bflo(v.x); a1 += bfhi(v.x); a2 += bflo(v.y); a3 += bfhi(v.y);
    }
    uint2 vs = XW64[(size_t)node * 32 + li];
    a0 += bflo(vs.x); a1 += bfhi(vs.x); a2 += bflo(vs.y); a3 += bfhi(vs.y);
    float d = dis[node];
    uint2 r;
    r.x = (uint32)f2bf(a0 * d) | ((uint32)f2bf(a1 * d) << 16);
    r.y = (uint32)f2bf(a2 * d) | ((uint32)f2bf(a3 * d) << 16);
    ((uint2*)HP32)[(size_t)node * 32 + li] = r;
}

// ---------------------------------------------------------------------------
// BN stats over packed-bf16 HP: per-feature sum & sumsq.
// ---------------------------------------------------------------------------
__global__ __launch_bounds__(256) void k_stats(const uint32* __restrict__ HP32,
                                               float* __restrict__ stats) {
    int l = threadIdx.x & 63;
    int rg = threadIdx.x >> 6;
    float s0 = 0.f, s1 = 0.f, q0 = 0.f, q1 = 0.f;
    for (int r = blockIdx.x * 4 + rg; r < Nn; r += gridDim.x * 4) {
        uint32 v = HP32[(size_t)r * 64 + l];
        float a = bflo(v), b = bfhi(v);
        s0 += a; s1 += b;
        q0 = fmaf(a, a, q0); q1 = fmaf(b, b, q1);
    }
    __shared__ float sh[256];
    sh[threadIdx.x] = s0; __syncthreads();
    if (rg == 0) atomicAdd(&stats[2 * l], sh[l] + sh[l + 64] + sh[l + 128] + sh[l + 192]);
    __syncthreads();
    sh[threadIdx.x] = s1; __syncthreads();
    if (rg == 0) atomicAdd(&stats[2 * l + 1], sh[l] + sh[l + 64] + sh[l + 128] + sh[l + 192]);
    __syncthreads();
    sh[threadIdx.x] = q0; __syncthreads();
    if (rg == 0) atomicAdd(&stats[128 + 2 * l], sh[l] + sh[l + 64] + sh[l + 128] + sh[l + 192]);
    __syncthreads();
    sh[threadIdx.x] = q1; __syncthreads();
    if (rg == 0) atomicAdd(&stats[128 + 2 * l + 1], sh[l] + sh[l + 64] + sh[l + 128] + sh[l + 192]);
}

__global__ void k_bnfinal(const float* __restrict__ stats,
                          const float* __restrict__ g,
                          const float* __restrict__ bt,
                          float* __restrict__ bnp) {
    int f = threadIdx.x;
    float mu  = stats[f] * (1.0f / Nn);
    float var = stats[128 + f] * (1.0f / Nn) - mu * mu;
    float sc  = g[f] * rsqrtf(var + BN_EPS);
    bnp[f]       = sc;
    bnp[128 + f] = bt[f] - mu * sc;
}

// ---------------------------------------------------------------------------
// Fused BN+ReLU + mean-pool + FC1(relu) + FC2. One block (128 thr) per graph.
// ---------------------------------------------------------------------------
__global__ __launch_bounds__(128) void k_pool_fc(const ushort_t* __restrict__ HP16,
                                                 const float* __restrict__ bnp,
                                                 const int* __restrict__ batch,
                                                 const float* __restrict__ fcw1,
                                                 const float* __restrict__ fcb1,
                                                 const float* __restrict__ fcw2,
                                                 const float* __restrict__ fcb2,
                                                 float* __restrict__ out) {
    int g = blockIdx.x;
    int t = threadIdx.x;
    int lo = 0, hi = Nn;
    while (lo < hi) { int mid = (lo + hi) >> 1; if (batch[mid] < g) lo = mid + 1; else hi = mid; }
    int start = lo;
    hi = Nn;
    while (lo < hi) { int mid = (lo + hi) >> 1; if (batch[mid] < g + 1) lo = mid + 1; else hi = mid; }
    int end = lo;

    float sc = bnp[t], sh = bnp[128 + t];
    float acc = 0.f;
    for (int i = start; i < end; ++i) {
        union { uint32 u; float f; } c;
        c.u = (uint32)HP16[(size_t)i * 128 + t] << 16;
        acc += fmaxf(fmaf(c.f, sc, sh), 0.f);
    }
    float inv = 1.0f / fmaxf((float)(end - start), 1.0f);

    __shared__ float p[128];
    __shared__ float h1[64];
    p[t] = acc * inv;
    __syncthreads();
    if (t < 64) {
        float s = fcb1[t];
        for (int k = 0; k < 128; ++k) s = fmaf(p[k], fcw1[k * 64 + t], s);
        h1[t] = fmaxf(s, 0.f);
    }
    __syncthreads();
    if (t < 64) {
        float v = h1[t] * fcw2[t];
        for (int off = 32; off > 0; off >>= 1) v += __shfl_down(v, off, 64);
        if (t == 0) out[g] = v + fcb2[0];
    }
}

// ---------------------------------------------------------------------------
extern "C" void kernel_launch(void* const* d_in, const int* in_sizes, int n_in,
                              void* d_out, int out_size, void* d_ws, size_t ws_size,
                              hipStream_t stream) {
    const float* x     = (const float*)d_in[0];
    const int*   ei    = (const int*)d_in[1];
    const int*   batch = (const int*)d_in[2];
    const float* W1  = (const float*)d_in[3];
    const float* b1  = (const float*)d_in[4];
    const float* g1  = (const float*)d_in[5];
    const float* bt1 = (const float*)d_in[6];
    const float* W2  = (const float*)d_in[7];
    const float* b2  = (const float*)d_in[8];
    const float* g2  = (const float*)d_in[9];
    const float* bt2 = (const float*)d_in[10];
    const float* W3  = (const float*)d_in[11];
    const float* b3  = (const float*)d_in[12];
    const float* g3  = (const float*)d_in[13];
    const float* bt3 = (const float*)d_in[14];
    const float* fcw1 = (const float*)d_in[15];
    const float* fcb1 = (const float*)d_in[16];
    const float* fcw2 = (const float*)d_in[17];
    const float* fcb2 = (const float*)d_in[18];
    float* out = (float*)d_out;

    // Workspace layout
    ushort_t* XWb    = (ushort_t*)d_ws;                       // [N*128] bf16
    uint32*   HP32   = (uint32*)(XWb + (size_t)Nn * HH);      // [N*64] bf16x2
    float*    dis    = (float*)(HP32 + (size_t)Nn * 64);      // [N]
    unsigned* cnt    = (unsigned*)(dis + Nn);                 // [N]
    int*      rowptr = (int*)(cnt + Nn);                      // [N+1]
    int*      bsum   = rowptr + (Nn + 1);                     // [512]
    int*      blkhist = bsum + 512;                           // [512*196]
    int*      blkoff  = blkhist + NBLK_E * NBK;               // [512*196]
    uint32*   pairs  = (uint32*)(blkoff + NBLK_E * NBK);      // [E]
    int*      csr_src = (int*)(pairs + Ee);                   // [E]
    float*    stats  = (float*)(csr_src + Ee);                // [3*256]
    float*    bnp    = stats + 768;                           // [3*256]

    hipMemsetAsync(cnt, 0, (size_t)Nn * sizeof(unsigned), stream);
    hipMemsetAsync(stats, 0, 768 * sizeof(float), stream);

    const int* src = ei;
    const int* dst = ei + Ee;

    k_count<<<NBLK_E, 256, 0, stream>>>(dst, cnt, blkhist);
    k_dis<<<(Nn + 255) / 256, 256, 0, stream>>>(cnt, dis);
    int nblk = (Nn + 255) / 256;  // 391
    k_scan1<<<nblk, 256, 0, stream>>>(cnt, rowptr, bsum);
    k_scan2<<<1, 512, 0, stream>>>(bsum, nblk);
    k_scan3<<<nblk, 256, 0, stream>>>(rowptr, bsum);
    k_bscan<<<NBK, 512, 0, stream>>>(rowptr, blkhist, blkoff);
    k_fill1<<<NBLK_E, 256, 0, stream>>>(src, dst, blkoff, pairs);
    k_fill2<<<NBK, 1024, 0, stream>>>(rowptr, pairs, csr_src);

    const float* Ws_[3]  = {W1, W2, W3};
    const float* bs_[3]  = {b1, b2, b3};
    const float* gs_[3]  = {g1, g2, g3};
    const float* bts_[3] = {bt1, bt2, bt3};
    for (int l = 0; l < 3; ++l) {
        const float* bnp_in = (l == 0) ? nullptr : (bnp + (l - 1) * 256);
        k_gemm<<<768, 256, 0, stream>>>(x, HP32, Ws_[l], bs_[l], bnp_in, dis, XWb);
        k_agg<<<12500, 256, 0, stream>>>((const uint32*)XWb, dis, rowptr, csr_src, HP32);
        k_stats<<<1024, 256, 0, stream>>>(HP32, stats + l * 256);
        k_bnfinal<<<1, 128, 0, stream>>>(stats + l * 256, gs_[l], bts_[l], bnp + l * 256);
    }
    k_pool_fc<<<Gg, 128, 0, stream>>>((const ushort_t*)HP32, bnp + 512, batch,
                                      fcw1, fcb1, fcw2, fcb2, out);
}

// Round 6
// 581.253 us; speedup vs baseline: 1.5033x; 1.0686x over previous
//
#include <hip/hip_runtime.h>
#include <math.h>

#define Nn 100000
#define Ee 1600000
#define Gg 2048
#define HH 128
#define BN_EPS 1e-5f

#define NBK 196        // ceil(100000/512) buckets of 512 nodes
#define NBLK_E 500     // edge-pass blocks
#define CHUNK4 800     // int4s per block (500*3200 = 1.6M edges)

typedef unsigned int uint32;
typedef unsigned short ushort_t;
typedef __attribute__((ext_vector_type(8))) short short8_t;
typedef __attribute__((ext_vector_type(8))) unsigned short ushort8_t;
typedef __attribute__((ext_vector_type(4))) float f32x4_t;

__device__ __forceinline__ ushort_t f2bf(float f) {
    union { float f; uint32 u; } c; c.f = f;
    uint32 r = (c.u + 0x7FFFu + ((c.u >> 16) & 1u)) >> 16;   // RTNE
    return (ushort_t)r;
}
__device__ __forceinline__ float bflo(uint32 v) {
    union { uint32 u; float f; } c; c.u = v << 16; return c.f;
}
__device__ __forceinline__ float bfhi(uint32 v) {
    union { uint32 u; float f; } c; c.u = v & 0xFFFF0000u; return c.f;
}

// ---------------------------------------------------------------------------
// Count: per-BLOCK bucket histogram only. NO global atomics.
// ---------------------------------------------------------------------------
__global__ __launch_bounds__(256) void k_count(const int* __restrict__ dst,
                                               int* __restrict__ blkhist) {
    __shared__ unsigned h[NBK];
    int tid = threadIdx.x;
    for (int i = tid; i < NBK; i += 256) h[i] = 0;
    __syncthreads();
    const int4* d4 = (const int4*)dst + blockIdx.x * CHUNK4;
    for (int i = tid; i < CHUNK4; i += 256) {
        int4 v = d4[i];
        atomicAdd(&h[v.x >> 9], 1u);
        atomicAdd(&h[v.y >> 9], 1u);
        atomicAdd(&h[v.z >> 9], 1u);
        atomicAdd(&h[v.w >> 9], 1u);
    }
    __syncthreads();
    for (int i = tid; i < NBK; i += 256)
        blkhist[blockIdx.x * NBK + i] = (int)h[i];
}

// ---------------------------------------------------------------------------
// Scan blkhist across blocks (one workgroup per bucket).
// ---------------------------------------------------------------------------
__global__ __launch_bounds__(512) void k_bscan1(const int* __restrict__ blkhist,
                                                int* __restrict__ blkoff_rel,
                                                int* __restrict__ total) {
    __shared__ int tmp[512];
    int bucket = blockIdx.x;
    int t = threadIdx.x;
    int v = (t < NBLK_E) ? blkhist[t * NBK + bucket] : 0;
    tmp[t] = v;
    __syncthreads();
    for (int off = 1; off < 512; off <<= 1) {
        int u = (t >= off) ? tmp[t - off] : 0;
        __syncthreads();
        tmp[t] += u;
        __syncthreads();
    }
    if (t < NBLK_E) blkoff_rel[t * NBK + bucket] = tmp[t] - v;
    if (t == 511) total[bucket] = tmp[t];
}

// Exclusive scan of bucket totals -> bucket_base.
__global__ void k_bscan2(const int* __restrict__ total,
                         int* __restrict__ bucket_base) {
    __shared__ int tmp[256];
    int t = threadIdx.x;  // 256 >= NBK
    int v = (t < NBK) ? total[t] : 0;
    tmp[t] = v;
    __syncthreads();
    for (int off = 1; off < 256; off <<= 1) {
        int u = (t >= off) ? tmp[t - off] : 0;
        __syncthreads();
        tmp[t] += u;
        __syncthreads();
    }
    if (t < NBK) bucket_base[t] = tmp[t] - v;
}

// ---------------------------------------------------------------------------
// Fill pass 1: counting-sort append; LDS atomics only, contiguous runs.
// ---------------------------------------------------------------------------
__global__ __launch_bounds__(256) void k_fill1(const int* __restrict__ src,
                                               const int* __restrict__ dst,
                                               const int* __restrict__ bucket_base,
                                               const int* __restrict__ blkoff_rel,
                                               uint32* __restrict__ pairs) {
    __shared__ int loff[NBK];
    __shared__ unsigned lh[NBK];
    int tid = threadIdx.x;
    for (int i = tid; i < NBK; i += 256) {
        loff[i] = bucket_base[i] + blkoff_rel[blockIdx.x * NBK + i];
        lh[i] = 0;
    }
    __syncthreads();
    const int4* s4 = (const int4*)src + blockIdx.x * CHUNK4;
    const int4* d4 = (const int4*)dst + blockIdx.x * CHUNK4;
    for (int i = tid; i < CHUNK4; i += 256) {
        int4 s = s4[i];
        int4 d = d4[i];
        int b0 = d.x >> 9; int r0 = (int)atomicAdd(&lh[b0], 1u);
        pairs[loff[b0] + r0] = ((uint32)(d.x & 511) << 17) | (uint32)s.x;
        int b1 = d.y >> 9; int r1 = (int)atomicAdd(&lh[b1], 1u);
        pairs[loff[b1] + r1] = ((uint32)(d.y & 511) << 17) | (uint32)s.y;
        int b2 = d.z >> 9; int r2 = (int)atomicAdd(&lh[b2], 1u);
        pairs[loff[b2] + r2] = ((uint32)(d.z & 511) << 17) | (uint32)s.z;
        int b3 = d.w >> 9; int r3 = (int)atomicAdd(&lh[b3], 1u);
        pairs[loff[b3] + r3] = ((uint32)(d.w & 511) << 17) | (uint32)s.w;
    }
}

// ---------------------------------------------------------------------------
// Fill pass 2: one block (1024 thr) per bucket.
// Pass A: count per-node via LDS; scan -> rowptr + dis. Pass B: scatter.
// ---------------------------------------------------------------------------
__global__ __launch_bounds__(1024) void k_fill2(const int* __restrict__ bucket_base,
                                                const int* __restrict__ total,
                                                const uint32* __restrict__ pairs,
                                                int* __restrict__ csr_src,
                                                int* __restrict__ rowptr,
                                                float* __restrict__ dis) {
    __shared__ unsigned lcnt[512];
    __shared__ int tmp[512];
    __shared__ int lcur[512];
    int b = blockIdx.x;
    int node0 = b * 512;
    int tid = threadIdx.x;
    for (int i = tid; i < 512; i += 1024) lcnt[i] = 0;
    __syncthreads();
    int beg = bucket_base[b];
    int endp = beg + total[b];
    for (int j = beg + tid; j < endp; j += 1024)
        atomicAdd(&lcnt[pairs[j] >> 17], 1u);
    __syncthreads();
    if (tid < 512) tmp[tid] = (int)lcnt[tid];
    __syncthreads();
    for (int off = 1; off < 512; off <<= 1) {
        int u = (tid < 512 && tid >= off) ? tmp[tid - off] : 0;
        __syncthreads();
        if (tid < 512) tmp[tid] += u;
        __syncthreads();
    }
    if (tid < 512) {
        int excl = tmp[tid] - (int)lcnt[tid];
        int n = node0 + tid;
        if (n <= Nn) rowptr[n] = beg + excl;
        if (n < Nn) dis[n] = rsqrtf((float)lcnt[tid] + 1.0f);
        lcur[tid] = beg + excl;
    }
    __syncthreads();
    for (int j = beg + tid; j < endp; j += 1024) {
        uint32 p = pairs[j];
        int dl = (int)(p >> 17);
        int s = (int)(p & 0x1FFFFu);
        int pos = atomicAdd(&lcur[dl], 1);
        csr_src[pos] = s;
    }
}

// ---------------------------------------------------------------------------
// MFMA GEMM: XW' = dis * (Xin @ W + b), bf16 out. W staged once per block;
// grid-stride over 64-row tiles.
// ---------------------------------------------------------------------------
__global__ __launch_bounds__(256) void k_gemm(const float* __restrict__ Xf,
                                              const uint32* __restrict__ Xb,
                                              const float* __restrict__ W,
                                              const float* __restrict__ Bv,
                                              const float* __restrict__ bnp,
                                              const float* __restrict__ dis,
                                              ushort_t* __restrict__ XWb) {
    __shared__ ushort_t Wlds[128 * 136];
    __shared__ ushort_t Xlds[64 * 136];
    const int tid = threadIdx.x;

    // Stage W: Wlds[col][k] = bf16(W[k][col])
    {
        int col4 = tid & 31, krow = tid >> 5;
        const float4* W4 = (const float4*)W;
#pragma unroll
        for (int it = 0; it < 16; ++it) {
            int k = krow + it * 8;
            float4 v = W4[k * 32 + col4];
            int c0 = col4 * 4;
            Wlds[(c0 + 0) * 136 + k] = f2bf(v.x);
            Wlds[(c0 + 1) * 136 + k] = f2bf(v.y);
            Wlds[(c0 + 2) * 136 + k] = f2bf(v.z);
            Wlds[(c0 + 3) * 136 + k] = f2bf(v.w);
        }
    }

    const int wid = tid >> 6, lane = tid & 63;
    const int arow = wid * 16 + (lane & 15);
    const int koff = (lane >> 4) * 8;
    const int bcol = lane & 15;
    const int ntiles = (Nn + 63) / 64;  // 1563

    for (int t = blockIdx.x; t < ntiles; t += gridDim.x) {
        const int rowbase = t * 64;
        __syncthreads();  // previous tile's Xlds fully consumed
        {
            int row = tid >> 2, q = tid & 3;
            int g = rowbase + row;
            if (bnp == nullptr) {
                const float4* Xr = (const float4*)(Xf + (size_t)g * 128);
#pragma unroll
                for (int it = 0; it < 8; ++it) {
                    int c4 = q + it * 4;
                    float4 v;
                    if (g < Nn) v = Xr[c4];
                    else { v.x = v.y = v.z = v.w = 0.f; }
                    ushort4 o;
                    o.x = f2bf(v.x); o.y = f2bf(v.y); o.z = f2bf(v.z); o.w = f2bf(v.w);
                    *(ushort4*)&Xlds[row * 136 + c4 * 4] = o;
                }
            } else {
                const uint4* Hr = (const uint4*)(Xb + (size_t)g * 64);
#pragma unroll
                for (int it = 0; it < 4; ++it) {
                    int i4 = q + it * 4;
                    int c0 = i4 * 8;
                    ushort8_t o;
                    if (g < Nn) {
                        uint4 u = Hr[i4];
                        float4 sca = *(const float4*)&bnp[c0];
                        float4 scb = *(const float4*)&bnp[c0 + 4];
                        float4 sha = *(const float4*)&bnp[128 + c0];
                        float4 shb = *(const float4*)&bnp[128 + c0 + 4];
                        o[0] = f2bf(fmaxf(fmaf(bflo(u.x), sca.x, sha.x), 0.f));
                        o[1] = f2bf(fmaxf(fmaf(bfhi(u.x), sca.y, sha.y), 0.f));
                        o[2] = f2bf(fmaxf(fmaf(bflo(u.y), sca.z, sha.z), 0.f));
                        o[3] = f2bf(fmaxf(fmaf(bfhi(u.y), sca.w, sha.w), 0.f));
                        o[4] = f2bf(fmaxf(fmaf(bflo(u.z), scb.x, shb.x), 0.f));
                        o[5] = f2bf(fmaxf(fmaf(bfhi(u.z), scb.y, shb.y), 0.f));
                        o[6] = f2bf(fmaxf(fmaf(bflo(u.w), scb.z, shb.z), 0.f));
                        o[7] = f2bf(fmaxf(fmaf(bfhi(u.w), scb.w, shb.w), 0.f));
                    } else {
                        for (int j = 0; j < 8; ++j) o[j] = 0;
                    }
                    *(ushort8_t*)&Xlds[row * 136 + c0] = o;
                }
            }
        }
        __syncthreads();

        f32x4_t acc[8];
#pragma unroll
        for (int nt = 0; nt < 8; ++nt) acc[nt] = (f32x4_t){0.f, 0.f, 0.f, 0.f};

#pragma unroll
        for (int kt = 0; kt < 4; ++kt) {
            short8_t a = *(const short8_t*)&Xlds[arow * 136 + kt * 32 + koff];
#pragma unroll
            for (int nt = 0; nt < 8; ++nt) {
                short8_t b = *(const short8_t*)&Wlds[(nt * 16 + bcol) * 136 + kt * 32 + koff];
                acc[nt] = __builtin_amdgcn_mfma_f32_16x16x32_bf16(a, b, acc[nt], 0, 0, 0);
            }
        }

        int r0 = rowbase + wid * 16 + (lane >> 4) * 4;
        float dv[4];
#pragma unroll
        for (int i = 0; i < 4; ++i) dv[i] = (r0 + i < Nn) ? dis[r0 + i] : 0.f;
#pragma unroll
        for (int nt = 0; nt < 8; ++nt) {
            int col = nt * 16 + bcol;
            float bs = Bv[col];
#pragma unroll
            for (int i = 0; i < 4; ++i) {
                int rg = r0 + i;
                if (rg < Nn) XWb[(size_t)rg * 128 + col] = f2bf((acc[nt][i] + bs) * dv[i]);
            }
        }
    }
}

// ---------------------------------------------------------------------------
// Aggregate: HP[i] = dis[i]*(sum XW'[src] + XW'[i]); bf16 out.
// 2 nodes per wave, 8B/lane rows, 4-deep unroll -> 8 gathers in flight.
// ---------------------------------------------------------------------------
__global__ __launch_bounds__(256) void k_agg(const uint32* __restrict__ XW32,
                                             const float* __restrict__ dis,
                                             const int* __restrict__ rowptr,
                                             const int* __restrict__ csr_src,
                                             uint32* __restrict__ HP32) {
    int wv = blockIdx.x * 4 + (threadIdx.x >> 6);
    int lane = threadIdx.x & 63;
    int half = lane >> 5, li = lane & 31;
    int node = wv * 2 + half;
    const uint2* XW64 = (const uint2*)XW32;
    int beg = rowptr[node], end = rowptr[node + 1];
    float a0 = 0.f, a1 = 0.f, a2 = 0.f, a3 = 0.f;
    int j = beg;
    for (; j + 4 <= end; j += 4) {
        int s0 = csr_src[j + 0];
        int s1 = csr_src[j + 1];
        int s2 = csr_src[j + 2];
        int s3 = csr_src[j + 3];
        uint2 v0 = XW64[(size_t)s0 * 32 + li];
        uint2 v1 = XW64[(size_t)s1 * 32 + li];
        uint2 v2 = XW64[(size_t)s2 * 32 + li];
        uint2 v3 = XW64[(size_t)s3 * 32 + li];
        a0 += bflo(v0.x); a1 += bfhi(v0.x); a2 += bflo(v0.y); a3 += bfhi(v0.y);
        a0 += bflo(v1.x); a1 += bfhi(v1.x); a2 += bflo(v1.y); a3 += bfhi(v1.y);
        a0 += bflo(v2.x); a1 += bfhi(v2.x); a2 += bflo(v2.y); a3 += bfhi(v2.y);
        a0 += bflo(v3.x); a1 += bfhi(v3.x); a2 += bflo(v3.y); a3 += bfhi(v3.y);
    }
    for (; j < end; ++j) {
        int s = csr_src[j];
        uint2 v = XW64[(size_t)s * 32 + li];
        a0 += bflo(v.x); a1 += bfhi(v.x); a2 += bflo(v.y); a3 += bfhi(v.y);
    }
    uint2 vs = XW64[(size_t)node * 32 + li];
    a0 += bflo(vs.x); a1 += bfhi(vs.x); a2 += bflo(vs.y); a3 += bfhi(vs.y);
    float d = dis[node];
    uint2 r;
    r.x = (uint32)f2bf(a0 * d) | ((uint32)f2bf(a1 * d) << 16);
    r.y = (uint32)f2bf(a2 * d) | ((uint32)f2bf(a3 * d) << 16);
    ((uint2*)HP32)[(size_t)node * 32 + li] = r;
}

// ---------------------------------------------------------------------------
// BN stats over packed-bf16 HP: per-feature sum & sumsq.
// ---------------------------------------------------------------------------
__global__ __launch_bounds__(256) void k_stats(const uint32* __restrict__ HP32,
                                               float* __restrict__ stats) {
    int l = threadIdx.x & 63;
    int rg = threadIdx.x >> 6;
    float s0 = 0.f, s1 = 0.f, q0 = 0.f, q1 = 0.f;
    for (int r = blockIdx.x * 4 + rg; r < Nn; r += gridDim.x * 4) {
        uint32 v = HP32[(size_t)r * 64 + l];
        float a = bflo(v), b = bfhi(v);
        s0 += a; s1 += b;
        q0 = fmaf(a, a, q0); q1 = fmaf(b, b, q1);
    }
    __shared__ float sh[256];
    sh[threadIdx.x] = s0; __syncthreads();
    if (rg == 0) atomicAdd(&stats[2 * l], sh[l] + sh[l + 64] + sh[l + 128] + sh[l + 192]);
    __syncthreads();
    sh[threadIdx.x] = s1; __syncthreads();
    if (rg == 0) atomicAdd(&stats[2 * l + 1], sh[l] + sh[l + 64] + sh[l + 128] + sh[l + 192]);
    __syncthreads();
    sh[threadIdx.x] = q0; __syncthreads();
    if (rg == 0) atomicAdd(&stats[128 + 2 * l], sh[l] + sh[l + 64] + sh[l + 128] + sh[l + 192]);
    __syncthreads();
    sh[threadIdx.x] = q1; __syncthreads();
    if (rg == 0) atomicAdd(&stats[128 + 2 * l + 1], sh[l] + sh[l + 64] + sh[l + 128] + sh[l + 192]);
}

__global__ void k_bnfinal(const float* __restrict__ stats,
                          const float* __restrict__ g,
                          const float* __restrict__ bt,
                          float* __restrict__ bnp) {
    int f = threadIdx.x;
    float mu  = stats[f] * (1.0f / Nn);
    float var = stats[128 + f] * (1.0f / Nn) - mu * mu;
    float sc  = g[f] * rsqrtf(var + BN_EPS);
    bnp[f]       = sc;
    bnp[128 + f] = bt[f] - mu * sc;
}

// ---------------------------------------------------------------------------
// Fused BN+ReLU + mean-pool + FC1(relu) + FC2. One block (128 thr) per graph.
// ---------------------------------------------------------------------------
__global__ __launch_bounds__(128) void k_pool_fc(const ushort_t* __restrict__ HP16,
                                                 const float* __restrict__ bnp,
                                                 const int* __restrict__ batch,
                                                 const float* __restrict__ fcw1,
                                                 const float* __restrict__ fcb1,
                                                 const float* __restrict__ fcw2,
                                                 const float* __restrict__ fcb2,
                                                 float* __restrict__ out) {
    int g = blockIdx.x;
    int t = threadIdx.x;
    int lo = 0, hi = Nn;
    while (lo < hi) { int mid = (lo + hi) >> 1; if (batch[mid] < g) lo = mid + 1; else hi = mid; }
    int start = lo;
    hi = Nn;
    while (lo < hi) { int mid = (lo + hi) >> 1; if (batch[mid] < g + 1) lo = mid + 1; else hi = mid; }
    int end = lo;

    float sc = bnp[t], sh = bnp[128 + t];
    float acc = 0.f;
    for (int i = start; i < end; ++i) {
        union { uint32 u; float f; } c;
        c.u = (uint32)HP16[(size_t)i * 128 + t] << 16;
        acc += fmaxf(fmaf(c.f, sc, sh), 0.f);
    }
    float inv = 1.0f / fmaxf((float)(end - start), 1.0f);

    __shared__ float p[128];
    __shared__ float h1[64];
    p[t] = acc * inv;
    __syncthreads();
    if (t < 64) {
        float s = fcb1[t];
        for (int k = 0; k < 128; ++k) s = fmaf(p[k], fcw1[k * 64 + t], s);
        h1[t] = fmaxf(s, 0.f);
    }
    __syncthreads();
    if (t < 64) {
        float v = h1[t] * fcw2[t];
        for (int off = 32; off > 0; off >>= 1) v += __shfl_down(v, off, 64);
        if (t == 0) out[g] = v + fcb2[0];
    }
}

// ---------------------------------------------------------------------------
extern "C" void kernel_launch(void* const* d_in, const int* in_sizes, int n_in,
                              void* d_out, int out_size, void* d_ws, size_t ws_size,
                              hipStream_t stream) {
    const float* x     = (const float*)d_in[0];
    const int*   ei    = (const int*)d_in[1];
    const int*   batch = (const int*)d_in[2];
    const float* W1  = (const float*)d_in[3];
    const float* b1  = (const float*)d_in[4];
    const float* g1  = (const float*)d_in[5];
    const float* bt1 = (const float*)d_in[6];
    const float* W2  = (const float*)d_in[7];
    const float* b2  = (const float*)d_in[8];
    const float* g2  = (const float*)d_in[9];
    const float* bt2 = (const float*)d_in[10];
    const float* W3  = (const float*)d_in[11];
    const float* b3  = (const float*)d_in[12];
    const float* g3  = (const float*)d_in[13];
    const float* bt3 = (const float*)d_in[14];
    const float* fcw1 = (const float*)d_in[15];
    const float* fcb1 = (const float*)d_in[16];
    const float* fcw2 = (const float*)d_in[17];
    const float* fcb2 = (const float*)d_in[18];
    float* out = (float*)d_out;

    // Workspace layout
    ushort_t* XWb     = (ushort_t*)d_ws;                      // [N*128] bf16
    uint32*   HP32    = (uint32*)(XWb + (size_t)Nn * HH);     // [N*64] bf16x2
    float*    dis     = (float*)(HP32 + (size_t)Nn * 64);     // [N]
    int*      rowptr  = (int*)(dis + Nn);                     // [N+1]
    int*      blkhist = rowptr + (Nn + 1);                    // [500*196]
    int*      blkoff_rel = blkhist + NBLK_E * NBK;            // [500*196]
    int*      total   = blkoff_rel + NBLK_E * NBK;            // [196]
    int*      bucket_base = total + NBK;                      // [196]
    uint32*   pairs   = (uint32*)(bucket_base + NBK);         // [E]
    int*      csr_src = (int*)(pairs + Ee);                   // [E]
    float*    stats   = (float*)(csr_src + Ee);               // [3*256]
    float*    bnp     = stats + 768;                          // [3*256]

    hipMemsetAsync(stats, 0, 768 * sizeof(float), stream);

    const int* src = ei;
    const int* dst = ei + Ee;

    k_count<<<NBLK_E, 256, 0, stream>>>(dst, blkhist);
    k_bscan1<<<NBK, 512, 0, stream>>>(blkhist, blkoff_rel, total);
    k_bscan2<<<1, 256, 0, stream>>>(total, bucket_base);
    k_fill1<<<NBLK_E, 256, 0, stream>>>(src, dst, bucket_base, blkoff_rel, pairs);
    k_fill2<<<NBK, 1024, 0, stream>>>(bucket_base, total, pairs, csr_src, rowptr, dis);

    const float* Ws_[3]  = {W1, W2, W3};
    const float* bs_[3]  = {b1, b2, b3};
    const float* gs_[3]  = {g1, g2, g3};
    const float* bts_[3] = {bt1, bt2, bt3};
    for (int l = 0; l < 3; ++l) {
        const float* bnp_in = (l == 0) ? nullptr : (bnp + (l - 1) * 256);
        k_gemm<<<768, 256, 0, stream>>>(x, HP32, Ws_[l], bs_[l], bnp_in, dis, XWb);
        k_agg<<<12500, 256, 0, stream>>>((const uint32*)XWb, dis, rowptr, csr_src, HP32);
        k_stats<<<1024, 256, 0, stream>>>(HP32, stats + l * 256);
        k_bnfinal<<<1, 128, 0, stream>>>(stats + l * 256, gs_[l], bts_[l], bnp + l * 256);
    }
    k_pool_fc<<<Gg, 128, 0, stream>>>((const ushort_t*)HP32, bnp + 512, batch,
                                      fcw1, fcb1, fcw2, fcb2, out);
}

// Round 8
// 406.790 us; speedup vs baseline: 2.1480x; 1.4289x over previous
//
#include <hip/hip_runtime.h>
#include <math.h>

#define Nn 100000
#define Ee 1600000
#define Gg 2048
#define HH 128
#define BN_EPS 1e-5f

#define NBK 196        // ceil(100000/512) buckets of 512 nodes
#define NBLK_E 500     // edge-pass blocks
#define CHUNK4 800     // int4s per block (500*3200 = 1.6M edges)
#define NSTATB 256     // stats level-1 blocks

typedef unsigned int uint32;
typedef unsigned short ushort_t;
typedef __attribute__((ext_vector_type(8))) short short8_t;
typedef __attribute__((ext_vector_type(8))) unsigned short ushort8_t;
typedef __attribute__((ext_vector_type(4))) float f32x4_t;

__device__ __forceinline__ ushort_t f2bf(float f) {
    union { float f; uint32 u; } c; c.f = f;
    uint32 r = (c.u + 0x7FFFu + ((c.u >> 16) & 1u)) >> 16;   // RTNE
    return (ushort_t)r;
}
__device__ __forceinline__ float bflo(uint32 v) {
    union { uint32 u; float f; } c; c.u = v << 16; return c.f;
}
__device__ __forceinline__ float bfhi(uint32 v) {
    union { uint32 u; float f; } c; c.u = v & 0xFFFF0000u; return c.f;
}

// ---------------------------------------------------------------------------
// Count: per-BLOCK bucket histogram only. NO global atomics.
// ---------------------------------------------------------------------------
__global__ __launch_bounds__(256) void k_count(const int* __restrict__ dst,
                                               int* __restrict__ blkhist) {
    __shared__ unsigned h[NBK];
    int tid = threadIdx.x;
    for (int i = tid; i < NBK; i += 256) h[i] = 0;
    __syncthreads();
    const int4* d4 = (const int4*)dst + blockIdx.x * CHUNK4;
    for (int i = tid; i < CHUNK4; i += 256) {
        int4 v = d4[i];
        atomicAdd(&h[v.x >> 9], 1u);
        atomicAdd(&h[v.y >> 9], 1u);
        atomicAdd(&h[v.z >> 9], 1u);
        atomicAdd(&h[v.w >> 9], 1u);
    }
    __syncthreads();
    for (int i = tid; i < NBK; i += 256)
        blkhist[blockIdx.x * NBK + i] = (int)h[i];
}

// ---------------------------------------------------------------------------
// Scan blkhist across blocks (one workgroup per bucket).
// ---------------------------------------------------------------------------
__global__ __launch_bounds__(512) void k_bscan1(const int* __restrict__ blkhist,
                                                int* __restrict__ blkoff_rel,
                                                int* __restrict__ total) {
    __shared__ int tmp[512];
    int bucket = blockIdx.x;
    int t = threadIdx.x;
    int v = (t < NBLK_E) ? blkhist[t * NBK + bucket] : 0;
    tmp[t] = v;
    __syncthreads();
    for (int off = 1; off < 512; off <<= 1) {
        int u = (t >= off) ? tmp[t - off] : 0;
        __syncthreads();
        tmp[t] += u;
        __syncthreads();
    }
    if (t < NBLK_E) blkoff_rel[t * NBK + bucket] = tmp[t] - v;
    if (t == 511) total[bucket] = tmp[t];
}

// Exclusive scan of bucket totals -> bucket_base.
__global__ void k_bscan2(const int* __restrict__ total,
                         int* __restrict__ bucket_base) {
    __shared__ int tmp[256];
    int t = threadIdx.x;  // 256 >= NBK
    int v = (t < NBK) ? total[t] : 0;
    tmp[t] = v;
    __syncthreads();
    for (int off = 1; off < 256; off <<= 1) {
        int u = (t >= off) ? tmp[t - off] : 0;
        __syncthreads();
        tmp[t] += u;
        __syncthreads();
    }
    if (t < NBK) bucket_base[t] = tmp[t] - v;
}

// ---------------------------------------------------------------------------
// Fill pass 1: counting-sort append; LDS atomics only, contiguous runs.
// ---------------------------------------------------------------------------
__global__ __launch_bounds__(256) void k_fill1(const int* __restrict__ src,
                                               const int* __restrict__ dst,
                                               const int* __restrict__ bucket_base,
                                               const int* __restrict__ blkoff_rel,
                                               uint32* __restrict__ pairs) {
    __shared__ int loff[NBK];
    __shared__ unsigned lh[NBK];
    int tid = threadIdx.x;
    for (int i = tid; i < NBK; i += 256) {
        loff[i] = bucket_base[i] + blkoff_rel[blockIdx.x * NBK + i];
        lh[i] = 0;
    }
    __syncthreads();
    const int4* s4 = (const int4*)src + blockIdx.x * CHUNK4;
    const int4* d4 = (const int4*)dst + blockIdx.x * CHUNK4;
    for (int i = tid; i < CHUNK4; i += 256) {
        int4 s = s4[i];
        int4 d = d4[i];
        int b0 = d.x >> 9; int r0 = (int)atomicAdd(&lh[b0], 1u);
        pairs[loff[b0] + r0] = ((uint32)(d.x & 511) << 17) | (uint32)s.x;
        int b1 = d.y >> 9; int r1 = (int)atomicAdd(&lh[b1], 1u);
        pairs[loff[b1] + r1] = ((uint32)(d.y & 511) << 17) | (uint32)s.y;
        int b2 = d.z >> 9; int r2 = (int)atomicAdd(&lh[b2], 1u);
        pairs[loff[b2] + r2] = ((uint32)(d.z & 511) << 17) | (uint32)s.z;
        int b3 = d.w >> 9; int r3 = (int)atomicAdd(&lh[b3], 1u);
        pairs[loff[b3] + r3] = ((uint32)(d.w & 511) << 17) | (uint32)s.w;
    }
}

// ---------------------------------------------------------------------------
// Fill pass 2: one block (1024 thr) per bucket.
// Pass A: count per-node via LDS; scan -> rowptr + dis. Pass B: scatter.
// ---------------------------------------------------------------------------
__global__ __launch_bounds__(1024) void k_fill2(const int* __restrict__ bucket_base,
                                                const int* __restrict__ total,
                                                const uint32* __restrict__ pairs,
                                                int* __restrict__ csr_src,
                                                int* __restrict__ rowptr,
                                                float* __restrict__ dis) {
    __shared__ unsigned lcnt[512];
    __shared__ int tmp[512];
    __shared__ int lcur[512];
    int b = blockIdx.x;
    int node0 = b * 512;
    int tid = threadIdx.x;
    for (int i = tid; i < 512; i += 1024) lcnt[i] = 0;
    __syncthreads();
    int beg = bucket_base[b];
    int endp = beg + total[b];
    for (int j = beg + tid; j < endp; j += 1024)
        atomicAdd(&lcnt[pairs[j] >> 17], 1u);
    __syncthreads();
    if (tid < 512) tmp[tid] = (int)lcnt[tid];
    __syncthreads();
    for (int off = 1; off < 512; off <<= 1) {
        int u = (tid < 512 && tid >= off) ? tmp[tid - off] : 0;
        __syncthreads();
        if (tid < 512) tmp[tid] += u;
        __syncthreads();
    }
    if (tid < 512) {
        int excl = tmp[tid] - (int)lcnt[tid];
        int n = node0 + tid;
        if (n <= Nn) rowptr[n] = beg + excl;
        if (n < Nn) dis[n] = rsqrtf((float)lcnt[tid] + 1.0f);
        lcur[tid] = beg + excl;
    }
    __syncthreads();
    for (int j = beg + tid; j < endp; j += 1024) {
        uint32 p = pairs[j];
        int dl = (int)(p >> 17);
        int s = (int)(p & 0x1FFFFu);
        int pos = atomicAdd(&lcur[dl], 1);
        csr_src[pos] = s;
    }
}

// ---------------------------------------------------------------------------
// MFMA GEMM: XW' = dis * (Xin @ W + b), bf16 out. W staged once per block;
// grid-stride over 64-row tiles.
// ---------------------------------------------------------------------------
__global__ __launch_bounds__(256) void k_gemm(const float* __restrict__ Xf,
                                              const uint32* __restrict__ Xb,
                                              const float* __restrict__ W,
                                              const float* __restrict__ Bv,
                                              const float* __restrict__ bnp,
                                              const float* __restrict__ dis,
                                              ushort_t* __restrict__ XWb) {
    __shared__ ushort_t Wlds[128 * 136];
    __shared__ ushort_t Xlds[64 * 136];
    const int tid = threadIdx.x;

    // Stage W: Wlds[col][k] = bf16(W[k][col])
    {
        int col4 = tid & 31, krow = tid >> 5;
        const float4* W4 = (const float4*)W;
#pragma unroll
        for (int it = 0; it < 16; ++it) {
            int k = krow + it * 8;
            float4 v = W4[k * 32 + col4];
            int c0 = col4 * 4;
            Wlds[(c0 + 0) * 136 + k] = f2bf(v.x);
            Wlds[(c0 + 1) * 136 + k] = f2bf(v.y);
            Wlds[(c0 + 2) * 136 + k] = f2bf(v.z);
            Wlds[(c0 + 3) * 136 + k] = f2bf(v.w);
        }
    }

    const int wid = tid >> 6, lane = tid & 63;
    const int arow = wid * 16 + (lane & 15);
    const int koff = (lane >> 4) * 8;
    const int bcol = lane & 15;
    const int ntiles = (Nn + 63) / 64;  // 1563

    for (int t = blockIdx.x; t < ntiles; t += gridDim.x) {
        const int rowbase = t * 64;
        __syncthreads();  // previous tile's Xlds fully consumed
        {
            int row = tid >> 2, q = tid & 3;
            int g = rowbase + row;
            if (bnp == nullptr) {
                const float4* Xr = (const float4*)(Xf + (size_t)g * 128);
#pragma unroll
                for (int it = 0; it < 8; ++it) {
                    int c4 = q + it * 4;
                    float4 v;
                    if (g < Nn) v = Xr[c4];
                    else { v.x = v.y = v.z = v.w = 0.f; }
                    ushort4 o;
                    o.x = f2bf(v.x); o.y = f2bf(v.y); o.z = f2bf(v.z); o.w = f2bf(v.w);
                    *(ushort4*)&Xlds[row * 136 + c4 * 4] = o;
                }
            } else {
                const uint4* Hr = (const uint4*)(Xb + (size_t)g * 64);
#pragma unroll
                for (int it = 0; it < 4; ++it) {
                    int i4 = q + it * 4;
                    int c0 = i4 * 8;
                    ushort8_t o;
                    if (g < Nn) {
                        uint4 u = Hr[i4];
                        float4 sca = *(const float4*)&bnp[c0];
                        float4 scb = *(const float4*)&bnp[c0 + 4];
                        float4 sha = *(const float4*)&bnp[128 + c0];
                        float4 shb = *(const float4*)&bnp[128 + c0 + 4];
                        o[0] = f2bf(fmaxf(fmaf(bflo(u.x), sca.x, sha.x), 0.f));
                        o[1] = f2bf(fmaxf(fmaf(bfhi(u.x), sca.y, sha.y), 0.f));
                        o[2] = f2bf(fmaxf(fmaf(bflo(u.y), sca.z, sha.z), 0.f));
                        o[3] = f2bf(fmaxf(fmaf(bfhi(u.y), sca.w, sha.w), 0.f));
                        o[4] = f2bf(fmaxf(fmaf(bflo(u.z), scb.x, shb.x), 0.f));
                        o[5] = f2bf(fmaxf(fmaf(bfhi(u.z), scb.y, shb.y), 0.f));
                        o[6] = f2bf(fmaxf(fmaf(bflo(u.w), scb.z, shb.z), 0.f));
                        o[7] = f2bf(fmaxf(fmaf(bfhi(u.w), scb.w, shb.w), 0.f));
                    } else {
                        for (int j = 0; j < 8; ++j) o[j] = 0;
                    }
                    *(ushort8_t*)&Xlds[row * 136 + c0] = o;
                }
            }
        }
        __syncthreads();

        f32x4_t acc[8];
#pragma unroll
        for (int nt = 0; nt < 8; ++nt) acc[nt] = (f32x4_t){0.f, 0.f, 0.f, 0.f};

#pragma unroll
        for (int kt = 0; kt < 4; ++kt) {
            short8_t a = *(const short8_t*)&Xlds[arow * 136 + kt * 32 + koff];
#pragma unroll
            for (int nt = 0; nt < 8; ++nt) {
                short8_t b = *(const short8_t*)&Wlds[(nt * 16 + bcol) * 136 + kt * 32 + koff];
                acc[nt] = __builtin_amdgcn_mfma_f32_16x16x32_bf16(a, b, acc[nt], 0, 0, 0);
            }
        }

        int r0 = rowbase + wid * 16 + (lane >> 4) * 4;
        float dv[4];
#pragma unroll
        for (int i = 0; i < 4; ++i) dv[i] = (r0 + i < Nn) ? dis[r0 + i] : 0.f;
#pragma unroll
        for (int nt = 0; nt < 8; ++nt) {
            int col = nt * 16 + bcol;
            float bs = Bv[col];
#pragma unroll
            for (int i = 0; i < 4; ++i) {
                int rg = r0 + i;
                if (rg < Nn) XWb[(size_t)rg * 128 + col] = f2bf((acc[nt][i] + bs) * dv[i]);
            }
        }
    }
}

// ---------------------------------------------------------------------------
// Aggregate: HP[i] = dis[i]*(sum XW'[src] + XW'[i]); bf16 out.
// 2 nodes per wave, 8B/lane rows, 4-deep unroll -> 8 gathers in flight.
// ---------------------------------------------------------------------------
__global__ __launch_bounds__(256) void k_agg(const uint32* __restrict__ XW32,
                                             const float* __restrict__ dis,
                                             const int* __restrict__ rowptr,
                                             const int* __restrict__ csr_src,
                                             uint32* __restrict__ HP32) {
    int wv = blockIdx.x * 4 + (threadIdx.x >> 6);
    int lane = threadIdx.x & 63;
    int half = lane >> 5, li = lane & 31;
    int node = wv * 2 + half;
    const uint2* XW64 = (const uint2*)XW32;
    int beg = rowptr[node], end = rowptr[node + 1];
    float a0 = 0.f, a1 = 0.f, a2 = 0.f, a3 = 0.f;
    int j = beg;
    for (; j + 4 <= end; j += 4) {
        int s0 = csr_src[j + 0];
        int s1 = csr_src[j + 1];
        int s2 = csr_src[j + 2];
        int s3 = csr_src[j + 3];
        uint2 v0 = XW64[(size_t)s0 * 32 + li];
        uint2 v1 = XW64[(size_t)s1 * 32 + li];
        uint2 v2 = XW64[(size_t)s2 * 32 + li];
        uint2 v3 = XW64[(size_t)s3 * 32 + li];
        a0 += bflo(v0.x); a1 += bfhi(v0.x); a2 += bflo(v0.y); a3 += bfhi(v0.y);
        a0 += bflo(v1.x); a1 += bfhi(v1.x); a2 += bflo(v1.y); a3 += bfhi(v1.y);
        a0 += bflo(v2.x); a1 += bfhi(v2.x); a2 += bflo(v2.y); a3 += bfhi(v2.y);
        a0 += bflo(v3.x); a1 += bfhi(v3.x); a2 += bflo(v3.y); a3 += bfhi(v3.y);
    }
    for (; j < end; ++j) {
        int s = csr_src[j];
        uint2 v = XW64[(size_t)s * 32 + li];
        a0 += bflo(v.x); a1 += bfhi(v.x); a2 += bflo(v.y); a3 += bfhi(v.y);
    }
    uint2 vs = XW64[(size_t)node * 32 + li];
    a0 += bflo(vs.x); a1 += bfhi(vs.x); a2 += bflo(vs.y); a3 += bfhi(vs.y);
    float d = dis[node];
    uint2 r;
    r.x = (uint32)f2bf(a0 * d) | ((uint32)f2bf(a1 * d) << 16);
    r.y = (uint32)f2bf(a2 * d) | ((uint32)f2bf(a3 * d) << 16);
    ((uint2*)HP32)[(size_t)node * 32 + li] = r;
}

// ---------------------------------------------------------------------------
// BN stats level 1: 256 blocks; register accum; LDS reduce; ONE coalesced
// partials-row write per block. Zero global atomics.
// Lane covers features 4li..4li+3 (uint2 = 8B of a row); 8 row-slots/block.
// partials[b][f] = sum(feature f), partials[b][128+f] = sumsq(feature f).
// ---------------------------------------------------------------------------
__global__ __launch_bounds__(256) void k_statsA(const uint32* __restrict__ HP32,
                                                float* __restrict__ partials) {
    const uint2* HPu2 = (const uint2*)HP32;
    int tid = threadIdx.x;
    int li = tid & 31;          // uint2 index within row
    int s  = tid >> 5;          // row slot 0..7
    float s0 = 0.f, s1 = 0.f, s2 = 0.f, s3 = 0.f;
    float q0 = 0.f, q1 = 0.f, q2 = 0.f, q3 = 0.f;
    for (int r = blockIdx.x * 8 + s; r < Nn; r += NSTATB * 8) {
        uint2 v = HPu2[(size_t)r * 32 + li];
        float a = bflo(v.x), b = bfhi(v.x), c = bflo(v.y), d = bfhi(v.y);
        s0 += a; s1 += b; s2 += c; s3 += d;
        q0 = fmaf(a, a, q0); q1 = fmaf(b, b, q1);
        q2 = fmaf(c, c, q2); q3 = fmaf(d, d, q3);
    }
    __shared__ float arr[8 * 256];
    float* mine = &arr[s * 256 + li * 4];
    mine[0] = s0; mine[1] = s1; mine[2] = s2; mine[3] = s3;
    mine[128] = q0; mine[129] = q1; mine[130] = q2; mine[131] = q3;
    __syncthreads();
    float tot = 0.f;
#pragma unroll
    for (int k = 0; k < 8; ++k) tot += arr[k * 256 + tid];
    partials[blockIdx.x * 256 + tid] = tot;
}

// ---------------------------------------------------------------------------
// BN stats level 2 + bnfinal: 1 block x 1024 thr. Sums 256 partial rows
// (coalesced), then computes scale/shift.
// ---------------------------------------------------------------------------
__global__ __launch_bounds__(1024) void k_statsB(const float* __restrict__ partials,
                                                 const float* __restrict__ g,
                                                 const float* __restrict__ bt,
                                                 float* __restrict__ bnp) {
    int tid = threadIdx.x;
    int sub = tid >> 8;         // 0..3
    int t = tid & 255;
    float acc = 0.f;
#pragma unroll 8
    for (int r = sub * 64; r < sub * 64 + 64; ++r)
        acc += partials[r * 256 + t];
    __shared__ float red[4 * 256];
    red[sub * 256 + t] = acc;
    __syncthreads();
    __shared__ float tot[256];
    if (tid < 256)
        tot[tid] = red[tid] + red[256 + tid] + red[512 + tid] + red[768 + tid];
    __syncthreads();
    if (tid < 128) {
        float mu  = tot[tid] * (1.0f / Nn);
        float var = tot[128 + tid] * (1.0f / Nn) - mu * mu;
        float sc  = g[tid] * rsqrtf(var + BN_EPS);
        bnp[tid]       = sc;
        bnp[128 + tid] = bt[tid] - mu * sc;
    }
}

// ---------------------------------------------------------------------------
// Fused BN+ReLU + mean-pool + FC1(relu) + FC2. One block (128 thr) per graph.
// ---------------------------------------------------------------------------
__global__ __launch_bounds__(128) void k_pool_fc(const ushort_t* __restrict__ HP16,
                                                 const float* __restrict__ bnp,
                                                 const int* __restrict__ batch,
                                                 const float* __restrict__ fcw1,
                                                 const float* __restrict__ fcb1,
                                                 const float* __restrict__ fcw2,
                                                 const float* __restrict__ fcb2,
                                                 float* __restrict__ out) {
    int g = blockIdx.x;
    int t = threadIdx.x;
    int lo = 0, hi = Nn;
    while (lo < hi) { int mid = (lo + hi) >> 1; if (batch[mid] < g) lo = mid + 1; else hi = mid; }
    int start = lo;
    hi = Nn;
    while (lo < hi) { int mid = (lo + hi) >> 1; if (batch[mid] < g + 1) lo = mid + 1; else hi = mid; }
    int end = lo;

    float sc = bnp[t], sh = bnp[128 + t];
    float acc = 0.f;
    for (int i = start; i < end; ++i) {
        union { uint32 u; float f; } c;
        c.u = (uint32)HP16[(size_t)i * 128 + t] << 16;
        acc += fmaxf(fmaf(c.f, sc, sh), 0.f);
    }
    float inv = 1.0f / fmaxf((float)(end - start), 1.0f);

    __shared__ float p[128];
    __shared__ float h1[64];
    p[t] = acc * inv;
    __syncthreads();
    if (t < 64) {
        float s = fcb1[t];
        for (int k = 0; k < 128; ++k) s = fmaf(p[k], fcw1[k * 64 + t], s);
        h1[t] = fmaxf(s, 0.f);
    }
    __syncthreads();
    if (t < 64) {
        float v = h1[t] * fcw2[t];
        for (int off = 32; off > 0; off >>= 1) v += __shfl_down(v, off, 64);
        if (t == 0) out[g] = v + fcb2[0];
    }
}

// ---------------------------------------------------------------------------
extern "C" void kernel_launch(void* const* d_in, const int* in_sizes, int n_in,
                              void* d_out, int out_size, void* d_ws, size_t ws_size,
                              hipStream_t stream) {
    const float* x     = (const float*)d_in[0];
    const int*   ei    = (const int*)d_in[1];
    const int*   batch = (const int*)d_in[2];
    const float* W1  = (const float*)d_in[3];
    const float* b1  = (const float*)d_in[4];
    const float* g1  = (const float*)d_in[5];
    const float* bt1 = (const float*)d_in[6];
    const float* W2  = (const float*)d_in[7];
    const float* b2  = (const float*)d_in[8];
    const float* g2  = (const float*)d_in[9];
    const float* bt2 = (const float*)d_in[10];
    const float* W3  = (const float*)d_in[11];
    const float* b3  = (const float*)d_in[12];
    const float* g3  = (const float*)d_in[13];
    const float* bt3 = (const float*)d_in[14];
    const float* fcw1 = (const float*)d_in[15];
    const float* fcb1 = (const float*)d_in[16];
    const float* fcw2 = (const float*)d_in[17];
    const float* fcb2 = (const float*)d_in[18];
    float* out = (float*)d_out;

    // Workspace layout
    ushort_t* XWb     = (ushort_t*)d_ws;                      // [N*128] bf16
    uint32*   HP32    = (uint32*)(XWb + (size_t)Nn * HH);     // [N*64] bf16x2
    float*    dis     = (float*)(HP32 + (size_t)Nn * 64);     // [N]
    int*      rowptr  = (int*)(dis + Nn);                     // [N+1]
    int*      blkhist = rowptr + (Nn + 1);                    // [500*196]
    int*      blkoff_rel = blkhist + NBLK_E * NBK;            // [500*196]
    int*      total   = blkoff_rel + NBLK_E * NBK;            // [196]
    int*      bucket_base = total + NBK;                      // [196]
    uint32*   pairs   = (uint32*)(bucket_base + NBK);         // [E]
    int*      csr_src = (int*)(pairs + Ee);                   // [E]
    float*    partials = (float*)(csr_src + Ee);              // [256*256]
    float*    bnp     = partials + NSTATB * 256;              // [3*256]

    const int* src = ei;
    const int* dst = ei + Ee;

    k_count<<<NBLK_E, 256, 0, stream>>>(dst, blkhist);
    k_bscan1<<<NBK, 512, 0, stream>>>(blkhist, blkoff_rel, total);
    k_bscan2<<<1, 256, 0, stream>>>(total, bucket_base);
    k_fill1<<<NBLK_E, 256, 0, stream>>>(src, dst, bucket_base, blkoff_rel, pairs);
    k_fill2<<<NBK, 1024, 0, stream>>>(bucket_base, total, pairs, csr_src, rowptr, dis);

    const float* Ws_[3]  = {W1, W2, W3};
    const float* bs_[3]  = {b1, b2, b3};
    const float* gs_[3]  = {g1, g2, g3};
    const float* bts_[3] = {bt1, bt2, bt3};
    for (int l = 0; l < 3; ++l) {
        const float* bnp_in = (l == 0) ? nullptr : (bnp + (l - 1) * 256);
        k_gemm<<<768, 256, 0, stream>>>(x, HP32, Ws_[l], bs_[l], bnp_in, dis, XWb);
        k_agg<<<12500, 256, 0, stream>>>((const uint32*)XWb, dis, rowptr, csr_src, HP32);
        k_statsA<<<NSTATB, 256, 0, stream>>>(HP32, partials);
        k_statsB<<<1, 1024, 0, stream>>>(partials, gs_[l], bts_[l], bnp + l * 256);
    }
    k_pool_fc<<<Gg, 128, 0, stream>>>((const ushort_t*)HP32, bnp + 512, batch,
                                      fcw1, fcb1, fcw2, fcb2, out);
}

// Round 9
// 400.872 us; speedup vs baseline: 2.1798x; 1.0148x over previous
//
#include <hip/hip_runtime.h>
#include <math.h>

#define Nn 100000
#define Ee 1600000
#define Gg 2048
#define HH 128
#define BN_EPS 1e-5f

#define NBK 196        // ceil(100000/512) buckets of 512 nodes
#define NBLK_E 500     // edge-pass blocks
#define CHUNK4 800     // int4s per block (500*3200 = 1.6M edges)
#define NSTATB 256     // stats level-1 blocks

typedef unsigned int uint32;
typedef unsigned short ushort_t;
typedef __attribute__((ext_vector_type(8))) short short8_t;
typedef __attribute__((ext_vector_type(8))) unsigned short ushort8_t;
typedef __attribute__((ext_vector_type(4))) float f32x4_t;

__device__ __forceinline__ ushort_t f2bf(float f) {
    union { float f; uint32 u; } c; c.f = f;
    uint32 r = (c.u + 0x7FFFu + ((c.u >> 16) & 1u)) >> 16;   // RTNE
    return (ushort_t)r;
}
__device__ __forceinline__ float bflo(uint32 v) {
    union { uint32 u; float f; } c; c.u = v << 16; return c.f;
}
__device__ __forceinline__ float bfhi(uint32 v) {
    union { uint32 u; float f; } c; c.u = v & 0xFFFF0000u; return c.f;
}

// ---------------------------------------------------------------------------
// Count: per-BLOCK bucket histogram only. NO global atomics.
// ---------------------------------------------------------------------------
__global__ __launch_bounds__(256) void k_count(const int* __restrict__ dst,
                                               int* __restrict__ blkhist) {
    __shared__ unsigned h[NBK];
    int tid = threadIdx.x;
    for (int i = tid; i < NBK; i += 256) h[i] = 0;
    __syncthreads();
    const int4* d4 = (const int4*)dst + blockIdx.x * CHUNK4;
    for (int i = tid; i < CHUNK4; i += 256) {
        int4 v = d4[i];
        atomicAdd(&h[v.x >> 9], 1u);
        atomicAdd(&h[v.y >> 9], 1u);
        atomicAdd(&h[v.z >> 9], 1u);
        atomicAdd(&h[v.w >> 9], 1u);
    }
    __syncthreads();
    for (int i = tid; i < NBK; i += 256)
        blkhist[blockIdx.x * NBK + i] = (int)h[i];
}

// ---------------------------------------------------------------------------
// Scan blkhist across blocks (one workgroup per bucket).
// ---------------------------------------------------------------------------
__global__ __launch_bounds__(512) void k_bscan1(const int* __restrict__ blkhist,
                                                int* __restrict__ blkoff_rel,
                                                int* __restrict__ total) {
    __shared__ int tmp[512];
    int bucket = blockIdx.x;
    int t = threadIdx.x;
    int v = (t < NBLK_E) ? blkhist[t * NBK + bucket] : 0;
    tmp[t] = v;
    __syncthreads();
    for (int off = 1; off < 512; off <<= 1) {
        int u = (t >= off) ? tmp[t - off] : 0;
        __syncthreads();
        tmp[t] += u;
        __syncthreads();
    }
    if (t < NBLK_E) blkoff_rel[t * NBK + bucket] = tmp[t] - v;
    if (t == 511) total[bucket] = tmp[t];
}

// Exclusive scan of bucket totals -> bucket_base.
__global__ void k_bscan2(const int* __restrict__ total,
                         int* __restrict__ bucket_base) {
    __shared__ int tmp[256];
    int t = threadIdx.x;  // 256 >= NBK
    int v = (t < NBK) ? total[t] : 0;
    tmp[t] = v;
    __syncthreads();
    for (int off = 1; off < 256; off <<= 1) {
        int u = (t >= off) ? tmp[t - off] : 0;
        __syncthreads();
        tmp[t] += u;
        __syncthreads();
    }
    if (t < NBK) bucket_base[t] = tmp[t] - v;
}

// ---------------------------------------------------------------------------
// Fill pass 1: counting-sort append; LDS atomics only, contiguous runs.
// ---------------------------------------------------------------------------
__global__ __launch_bounds__(256) void k_fill1(const int* __restrict__ src,
                                               const int* __restrict__ dst,
                                               const int* __restrict__ bucket_base,
                                               const int* __restrict__ blkoff_rel,
                                               uint32* __restrict__ pairs) {
    __shared__ int loff[NBK];
    __shared__ unsigned lh[NBK];
    int tid = threadIdx.x;
    for (int i = tid; i < NBK; i += 256) {
        loff[i] = bucket_base[i] + blkoff_rel[blockIdx.x * NBK + i];
        lh[i] = 0;
    }
    __syncthreads();
    const int4* s4 = (const int4*)src + blockIdx.x * CHUNK4;
    const int4* d4 = (const int4*)dst + blockIdx.x * CHUNK4;
    for (int i = tid; i < CHUNK4; i += 256) {
        int4 s = s4[i];
        int4 d = d4[i];
        int b0 = d.x >> 9; int r0 = (int)atomicAdd(&lh[b0], 1u);
        pairs[loff[b0] + r0] = ((uint32)(d.x & 511) << 17) | (uint32)s.x;
        int b1 = d.y >> 9; int r1 = (int)atomicAdd(&lh[b1], 1u);
        pairs[loff[b1] + r1] = ((uint32)(d.y & 511) << 17) | (uint32)s.y;
        int b2 = d.z >> 9; int r2 = (int)atomicAdd(&lh[b2], 1u);
        pairs[loff[b2] + r2] = ((uint32)(d.z & 511) << 17) | (uint32)s.z;
        int b3 = d.w >> 9; int r3 = (int)atomicAdd(&lh[b3], 1u);
        pairs[loff[b3] + r3] = ((uint32)(d.w & 511) << 17) | (uint32)s.w;
    }
}

// ---------------------------------------------------------------------------
// Fill pass 2: one block (1024 thr) per bucket.
// Pass A: count per-node via LDS; scan -> rowptr + dis. Pass B: scatter.
// ---------------------------------------------------------------------------
__global__ __launch_bounds__(1024) void k_fill2(const int* __restrict__ bucket_base,
                                                const int* __restrict__ total,
                                                const uint32* __restrict__ pairs,
                                                int* __restrict__ csr_src,
                                                int* __restrict__ rowptr,
                                                float* __restrict__ dis) {
    __shared__ unsigned lcnt[512];
    __shared__ int tmp[512];
    __shared__ int lcur[512];
    int b = blockIdx.x;
    int node0 = b * 512;
    int tid = threadIdx.x;
    for (int i = tid; i < 512; i += 1024) lcnt[i] = 0;
    __syncthreads();
    int beg = bucket_base[b];
    int endp = beg + total[b];
    for (int j = beg + tid; j < endp; j += 1024)
        atomicAdd(&lcnt[pairs[j] >> 17], 1u);
    __syncthreads();
    if (tid < 512) tmp[tid] = (int)lcnt[tid];
    __syncthreads();
    for (int off = 1; off < 512; off <<= 1) {
        int u = (tid < 512 && tid >= off) ? tmp[tid - off] : 0;
        __syncthreads();
        if (tid < 512) tmp[tid] += u;
        __syncthreads();
    }
    if (tid < 512) {
        int excl = tmp[tid] - (int)lcnt[tid];
        int n = node0 + tid;
        if (n <= Nn) rowptr[n] = beg + excl;
        if (n < Nn) dis[n] = rsqrtf((float)lcnt[tid] + 1.0f);
        lcur[tid] = beg + excl;
    }
    __syncthreads();
    for (int j = beg + tid; j < endp; j += 1024) {
        uint32 p = pairs[j];
        int dl = (int)(p >> 17);
        int s = (int)(p & 0x1FFFFu);
        int pos = atomicAdd(&lcur[dl], 1);
        csr_src[pos] = s;
    }
}

// ---------------------------------------------------------------------------
// MFMA GEMM: XW' = dis * (Xin @ W + b), bf16 out. W staged once per block;
// grid-stride over 64-row tiles.
// ---------------------------------------------------------------------------
__global__ __launch_bounds__(256) void k_gemm(const float* __restrict__ Xf,
                                              const uint32* __restrict__ Xb,
                                              const float* __restrict__ W,
                                              const float* __restrict__ Bv,
                                              const float* __restrict__ bnp,
                                              const float* __restrict__ dis,
                                              ushort_t* __restrict__ XWb) {
    __shared__ ushort_t Wlds[128 * 136];
    __shared__ ushort_t Xlds[64 * 136];
    const int tid = threadIdx.x;

    // Stage W: Wlds[col][k] = bf16(W[k][col])
    {
        int col4 = tid & 31, krow = tid >> 5;
        const float4* W4 = (const float4*)W;
#pragma unroll
        for (int it = 0; it < 16; ++it) {
            int k = krow + it * 8;
            float4 v = W4[k * 32 + col4];
            int c0 = col4 * 4;
            Wlds[(c0 + 0) * 136 + k] = f2bf(v.x);
            Wlds[(c0 + 1) * 136 + k] = f2bf(v.y);
            Wlds[(c0 + 2) * 136 + k] = f2bf(v.z);
            Wlds[(c0 + 3) * 136 + k] = f2bf(v.w);
        }
    }

    const int wid = tid >> 6, lane = tid & 63;
    const int arow = wid * 16 + (lane & 15);
    const int koff = (lane >> 4) * 8;
    const int bcol = lane & 15;
    const int ntiles = (Nn + 63) / 64;  // 1563

    for (int t = blockIdx.x; t < ntiles; t += gridDim.x) {
        const int rowbase = t * 64;
        __syncthreads();  // previous tile's Xlds fully consumed
        {
            int row = tid >> 2, q = tid & 3;
            int g = rowbase + row;
            if (bnp == nullptr) {
                const float4* Xr = (const float4*)(Xf + (size_t)g * 128);
#pragma unroll
                for (int it = 0; it < 8; ++it) {
                    int c4 = q + it * 4;
                    float4 v;
                    if (g < Nn) v = Xr[c4];
                    else { v.x = v.y = v.z = v.w = 0.f; }
                    ushort4 o;
                    o.x = f2bf(v.x); o.y = f2bf(v.y); o.z = f2bf(v.z); o.w = f2bf(v.w);
                    *(ushort4*)&Xlds[row * 136 + c4 * 4] = o;
                }
            } else {
                const uint4* Hr = (const uint4*)(Xb + (size_t)g * 64);
#pragma unroll
                for (int it = 0; it < 4; ++it) {
                    int i4 = q + it * 4;
                    int c0 = i4 * 8;
                    ushort8_t o;
                    if (g < Nn) {
                        uint4 u = Hr[i4];
                        float4 sca = *(const float4*)&bnp[c0];
                        float4 scb = *(const float4*)&bnp[c0 + 4];
                        float4 sha = *(const float4*)&bnp[128 + c0];
                        float4 shb = *(const float4*)&bnp[128 + c0 + 4];
                        o[0] = f2bf(fmaxf(fmaf(bflo(u.x), sca.x, sha.x), 0.f));
                        o[1] = f2bf(fmaxf(fmaf(bfhi(u.x), sca.y, sha.y), 0.f));
                        o[2] = f2bf(fmaxf(fmaf(bflo(u.y), sca.z, sha.z), 0.f));
                        o[3] = f2bf(fmaxf(fmaf(bfhi(u.y), sca.w, sha.w), 0.f));
                        o[4] = f2bf(fmaxf(fmaf(bflo(u.z), scb.x, shb.x), 0.f));
                        o[5] = f2bf(fmaxf(fmaf(bfhi(u.z), scb.y, shb.y), 0.f));
                        o[6] = f2bf(fmaxf(fmaf(bflo(u.w), scb.z, shb.z), 0.f));
                        o[7] = f2bf(fmaxf(fmaf(bfhi(u.w), scb.w, shb.w), 0.f));
                    } else {
                        for (int j = 0; j < 8; ++j) o[j] = 0;
                    }
                    *(ushort8_t*)&Xlds[row * 136 + c0] = o;
                }
            }
        }
        __syncthreads();

        f32x4_t acc[8];
#pragma unroll
        for (int nt = 0; nt < 8; ++nt) acc[nt] = (f32x4_t){0.f, 0.f, 0.f, 0.f};

#pragma unroll
        for (int kt = 0; kt < 4; ++kt) {
            short8_t a = *(const short8_t*)&Xlds[arow * 136 + kt * 32 + koff];
#pragma unroll
            for (int nt = 0; nt < 8; ++nt) {
                short8_t b = *(const short8_t*)&Wlds[(nt * 16 + bcol) * 136 + kt * 32 + koff];
                acc[nt] = __builtin_amdgcn_mfma_f32_16x16x32_bf16(a, b, acc[nt], 0, 0, 0);
            }
        }

        int r0 = rowbase + wid * 16 + (lane >> 4) * 4;
        float dv[4];
#pragma unroll
        for (int i = 0; i < 4; ++i) dv[i] = (r0 + i < Nn) ? dis[r0 + i] : 0.f;
#pragma unroll
        for (int nt = 0; nt < 8; ++nt) {
            int col = nt * 16 + bcol;
            float bs = Bv[col];
#pragma unroll
            for (int i = 0; i < 4; ++i) {
                int rg = r0 + i;
                if (rg < Nn) XWb[(size_t)rg * 128 + col] = f2bf((acc[nt][i] + bs) * dv[i]);
            }
        }
    }
}

// ---------------------------------------------------------------------------
// Aggregate: HP[i] = dis[i]*(sum XW'[src] + XW'[i]); bf16 out.
// 2 nodes per wave, 8B/lane rows. 8-deep unroll with ALL index loads issued
// first, then ALL gathers, then accumulation -> 8 gathers in flight per wave.
// ---------------------------------------------------------------------------
__global__ __launch_bounds__(256) void k_agg(const uint32* __restrict__ XW32,
                                             const float* __restrict__ dis,
                                             const int* __restrict__ rowptr,
                                             const int* __restrict__ csr_src,
                                             uint32* __restrict__ HP32) {
    int wv = blockIdx.x * 4 + (threadIdx.x >> 6);
    int lane = threadIdx.x & 63;
    int half = lane >> 5, li = lane & 31;
    int node = wv * 2 + half;
    const uint2* XW64 = (const uint2*)XW32;
    int beg = rowptr[node], end = rowptr[node + 1];
    float a0 = 0.f, a1 = 0.f, a2 = 0.f, a3 = 0.f;
    int j = beg;
    for (; j + 8 <= end; j += 8) {
        // phase 1: indices
        int s0 = csr_src[j + 0];
        int s1 = csr_src[j + 1];
        int s2 = csr_src[j + 2];
        int s3 = csr_src[j + 3];
        int s4 = csr_src[j + 4];
        int s5 = csr_src[j + 5];
        int s6 = csr_src[j + 6];
        int s7 = csr_src[j + 7];
        // phase 2: issue all 8 gathers
        uint2 v0 = XW64[(size_t)s0 * 32 + li];
        uint2 v1 = XW64[(size_t)s1 * 32 + li];
        uint2 v2 = XW64[(size_t)s2 * 32 + li];
        uint2 v3 = XW64[(size_t)s3 * 32 + li];
        uint2 v4 = XW64[(size_t)s4 * 32 + li];
        uint2 v5 = XW64[(size_t)s5 * 32 + li];
        uint2 v6 = XW64[(size_t)s6 * 32 + li];
        uint2 v7 = XW64[(size_t)s7 * 32 + li];
        // phase 3: accumulate
        a0 += bflo(v0.x); a1 += bfhi(v0.x); a2 += bflo(v0.y); a3 += bfhi(v0.y);
        a0 += bflo(v1.x); a1 += bfhi(v1.x); a2 += bflo(v1.y); a3 += bfhi(v1.y);
        a0 += bflo(v2.x); a1 += bfhi(v2.x); a2 += bflo(v2.y); a3 += bfhi(v2.y);
        a0 += bflo(v3.x); a1 += bfhi(v3.x); a2 += bflo(v3.y); a3 += bfhi(v3.y);
        a0 += bflo(v4.x); a1 += bfhi(v4.x); a2 += bflo(v4.y); a3 += bfhi(v4.y);
        a0 += bflo(v5.x); a1 += bfhi(v5.x); a2 += bflo(v5.y); a3 += bfhi(v5.y);
        a0 += bflo(v6.x); a1 += bfhi(v6.x); a2 += bflo(v6.y); a3 += bfhi(v6.y);
        a0 += bflo(v7.x); a1 += bfhi(v7.x); a2 += bflo(v7.y); a3 += bfhi(v7.y);
    }
    for (; j + 2 <= end; j += 2) {
        int s0 = csr_src[j + 0];
        int s1 = csr_src[j + 1];
        uint2 v0 = XW64[(size_t)s0 * 32 + li];
        uint2 v1 = XW64[(size_t)s1 * 32 + li];
        a0 += bflo(v0.x); a1 += bfhi(v0.x); a2 += bflo(v0.y); a3 += bfhi(v0.y);
        a0 += bflo(v1.x); a1 += bfhi(v1.x); a2 += bflo(v1.y); a3 += bfhi(v1.y);
    }
    if (j < end) {
        int s = csr_src[j];
        uint2 v = XW64[(size_t)s * 32 + li];
        a0 += bflo(v.x); a1 += bfhi(v.x); a2 += bflo(v.y); a3 += bfhi(v.y);
    }
    uint2 vs = XW64[(size_t)node * 32 + li];
    a0 += bflo(vs.x); a1 += bfhi(vs.x); a2 += bflo(vs.y); a3 += bfhi(vs.y);
    float d = dis[node];
    uint2 r;
    r.x = (uint32)f2bf(a0 * d) | ((uint32)f2bf(a1 * d) << 16);
    r.y = (uint32)f2bf(a2 * d) | ((uint32)f2bf(a3 * d) << 16);
    ((uint2*)HP32)[(size_t)node * 32 + li] = r;
}

// ---------------------------------------------------------------------------
// BN stats level 1: 256 blocks; register accum; LDS reduce; ONE coalesced
// partials-row write per block. Zero global atomics.
// ---------------------------------------------------------------------------
__global__ __launch_bounds__(256) void k_statsA(const uint32* __restrict__ HP32,
                                                float* __restrict__ partials) {
    const uint2* HPu2 = (const uint2*)HP32;
    int tid = threadIdx.x;
    int li = tid & 31;          // uint2 index within row
    int s  = tid >> 5;          // row slot 0..7
    float s0 = 0.f, s1 = 0.f, s2 = 0.f, s3 = 0.f;
    float q0 = 0.f, q1 = 0.f, q2 = 0.f, q3 = 0.f;
    for (int r = blockIdx.x * 8 + s; r < Nn; r += NSTATB * 8) {
        uint2 v = HPu2[(size_t)r * 32 + li];
        float a = bflo(v.x), b = bfhi(v.x), c = bflo(v.y), d = bfhi(v.y);
        s0 += a; s1 += b; s2 += c; s3 += d;
        q0 = fmaf(a, a, q0); q1 = fmaf(b, b, q1);
        q2 = fmaf(c, c, q2); q3 = fmaf(d, d, q3);
    }
    __shared__ float arr[8 * 256];
    float* mine = &arr[s * 256 + li * 4];
    mine[0] = s0; mine[1] = s1; mine[2] = s2; mine[3] = s3;
    mine[128] = q0; mine[129] = q1; mine[130] = q2; mine[131] = q3;
    __syncthreads();
    float tot = 0.f;
#pragma unroll
    for (int k = 0; k < 8; ++k) tot += arr[k * 256 + tid];
    partials[blockIdx.x * 256 + tid] = tot;
}

// ---------------------------------------------------------------------------
// BN stats level 2 + bnfinal: 1 block x 1024 thr.
// ---------------------------------------------------------------------------
__global__ __launch_bounds__(1024) void k_statsB(const float* __restrict__ partials,
                                                 const float* __restrict__ g,
                                                 const float* __restrict__ bt,
                                                 float* __restrict__ bnp) {
    int tid = threadIdx.x;
    int sub = tid >> 8;         // 0..3
    int t = tid & 255;
    float acc = 0.f;
#pragma unroll 8
    for (int r = sub * 64; r < sub * 64 + 64; ++r)
        acc += partials[r * 256 + t];
    __shared__ float red[4 * 256];
    red[sub * 256 + t] = acc;
    __syncthreads();
    __shared__ float tot[256];
    if (tid < 256)
        tot[tid] = red[tid] + red[256 + tid] + red[512 + tid] + red[768 + tid];
    __syncthreads();
    if (tid < 128) {
        float mu  = tot[tid] * (1.0f / Nn);
        float var = tot[128 + tid] * (1.0f / Nn) - mu * mu;
        float sc  = g[tid] * rsqrtf(var + BN_EPS);
        bnp[tid]       = sc;
        bnp[128 + tid] = bt[tid] - mu * sc;
    }
}

// ---------------------------------------------------------------------------
// Fused BN+ReLU + mean-pool + FC1(relu) + FC2. One block (128 thr) per graph.
// ---------------------------------------------------------------------------
__global__ __launch_bounds__(128) void k_pool_fc(const ushort_t* __restrict__ HP16,
                                                 const float* __restrict__ bnp,
                                                 const int* __restrict__ batch,
                                                 const float* __restrict__ fcw1,
                                                 const float* __restrict__ fcb1,
                                                 const float* __restrict__ fcw2,
                                                 const float* __restrict__ fcb2,
                                                 float* __restrict__ out) {
    int g = blockIdx.x;
    int t = threadIdx.x;
    int lo = 0, hi = Nn;
    while (lo < hi) { int mid = (lo + hi) >> 1; if (batch[mid] < g) lo = mid + 1; else hi = mid; }
    int start = lo;
    hi = Nn;
    while (lo < hi) { int mid = (lo + hi) >> 1; if (batch[mid] < g + 1) lo = mid + 1; else hi = mid; }
    int end = lo;

    float sc = bnp[t], sh = bnp[128 + t];
    float acc = 0.f;
    for (int i = start; i < end; ++i) {
        union { uint32 u; float f; } c;
        c.u = (uint32)HP16[(size_t)i * 128 + t] << 16;
        acc += fmaxf(fmaf(c.f, sc, sh), 0.f);
    }
    float inv = 1.0f / fmaxf((float)(end - start), 1.0f);

    __shared__ float p[128];
    __shared__ float h1[64];
    p[t] = acc * inv;
    __syncthreads();
    if (t < 64) {
        float s = fcb1[t];
        for (int k = 0; k < 128; ++k) s = fmaf(p[k], fcw1[k * 64 + t], s);
        h1[t] = fmaxf(s, 0.f);
    }
    __syncthreads();
    if (t < 64) {
        float v = h1[t] * fcw2[t];
        for (int off = 32; off > 0; off >>= 1) v += __shfl_down(v, off, 64);
        if (t == 0) out[g] = v + fcb2[0];
    }
}

// ---------------------------------------------------------------------------
extern "C" void kernel_launch(void* const* d_in, const int* in_sizes, int n_in,
                              void* d_out, int out_size, void* d_ws, size_t ws_size,
                              hipStream_t stream) {
    const float* x     = (const float*)d_in[0];
    const int*   ei    = (const int*)d_in[1];
    const int*   batch = (const int*)d_in[2];
    const float* W1  = (const float*)d_in[3];
    const float* b1  = (const float*)d_in[4];
    const float* g1  = (const float*)d_in[5];
    const float* bt1 = (const float*)d_in[6];
    const float* W2  = (const float*)d_in[7];
    const float* b2  = (const float*)d_in[8];
    const float* g2  = (const float*)d_in[9];
    const float* bt2 = (const float*)d_in[10];
    const float* W3  = (const float*)d_in[11];
    const float* b3  = (const float*)d_in[12];
    const float* g3  = (const float*)d_in[13];
    const float* bt3 = (const float*)d_in[14];
    const float* fcw1 = (const float*)d_in[15];
    const float* fcb1 = (const float*)d_in[16];
    const float* fcw2 = (const float*)d_in[17];
    const float* fcb2 = (const float*)d_in[18];
    float* out = (float*)d_out;

    // Workspace layout
    ushort_t* XWb     = (ushort_t*)d_ws;                      // [N*128] bf16
    uint32*   HP32    = (uint32*)(XWb + (size_t)Nn * HH);     // [N*64] bf16x2
    float*    dis     = (float*)(HP32 + (size_t)Nn * 64);     // [N]
    int*      rowptr  = (int*)(dis + Nn);                     // [N+1]
    int*      blkhist = rowptr + (Nn + 1);                    // [500*196]
    int*      blkoff_rel = blkhist + NBLK_E * NBK;            // [500*196]
    int*      total   = blkoff_rel + NBLK_E * NBK;            // [196]
    int*      bucket_base = total + NBK;                      // [196]
    uint32*   pairs   = (uint32*)(bucket_base + NBK);         // [E]
    int*      csr_src = (int*)(pairs + Ee);                   // [E]
    float*    partials = (float*)(csr_src + Ee);              // [256*256]
    float*    bnp     = partials + NSTATB * 256;              // [3*256]

    const int* src = ei;
    const int* dst = ei + Ee;

    k_count<<<NBLK_E, 256, 0, stream>>>(dst, blkhist);
    k_bscan1<<<NBK, 512, 0, stream>>>(blkhist, blkoff_rel, total);
    k_bscan2<<<1, 256, 0, stream>>>(total, bucket_base);
    k_fill1<<<NBLK_E, 256, 0, stream>>>(src, dst, bucket_base, blkoff_rel, pairs);
    k_fill2<<<NBK, 1024, 0, stream>>>(bucket_base, total, pairs, csr_src, rowptr, dis);

    const float* Ws_[3]  = {W1, W2, W3};
    const float* bs_[3]  = {b1, b2, b3};
    const float* gs_[3]  = {g1, g2, g3};
    const float* bts_[3] = {bt1, bt2, bt3};
    for (int l = 0; l < 3; ++l) {
        const float* bnp_in = (l == 0) ? nullptr : (bnp + (l - 1) * 256);
        k_gemm<<<768, 256, 0, stream>>>(x, HP32, Ws_[l], bs_[l], bnp_in, dis, XWb);
        k_agg<<<12500, 256, 0, stream>>>((const uint32*)XWb, dis, rowptr, csr_src, HP32);
        k_statsA<<<NSTATB, 256, 0, stream>>>(HP32, partials);
        k_statsB<<<1, 1024, 0, stream>>>(partials, gs_[l], bts_[l], bnp + l * 256);
    }
    k_pool_fc<<<Gg, 128, 0, stream>>>((const ushort_t*)HP32, bnp + 512, batch,
                                      fcw1, fcb1, fcw2, fcb2, out);
}

// Round 10
// 361.666 us; speedup vs baseline: 2.4160x; 1.1084x over previous
//
#include <hip/hip_runtime.h>
#include <math.h>

#define Nn 100000
#define Ee 1600000
#define Gg 2048
#define HH 128
#define BN_EPS 1e-5f

#define NBK 196        // ceil(100000/512) buckets of 512 nodes
#define NBLK_E 500     // edge-pass blocks
#define CHUNK4 800     // int4s per block (500*3200 = 1.6M edges)
#define NSTATB 256     // stats level-1 blocks

typedef unsigned int uint32;
typedef unsigned short ushort_t;
typedef __attribute__((ext_vector_type(8))) short short8_t;
typedef __attribute__((ext_vector_type(8))) unsigned short ushort8_t;
typedef __attribute__((ext_vector_type(4))) float f32x4_t;

__device__ __forceinline__ ushort_t f2bf(float f) {
    union { float f; uint32 u; } c; c.f = f;
    uint32 r = (c.u + 0x7FFFu + ((c.u >> 16) & 1u)) >> 16;   // RTNE
    return (ushort_t)r;
}
__device__ __forceinline__ float bflo(uint32 v) {
    union { uint32 u; float f; } c; c.u = v << 16; return c.f;
}
__device__ __forceinline__ float bfhi(uint32 v) {
    union { uint32 u; float f; } c; c.u = v & 0xFFFF0000u; return c.f;
}

// ---------------------------------------------------------------------------
// Count: per-BLOCK bucket histogram only. NO global atomics.
// ---------------------------------------------------------------------------
__global__ __launch_bounds__(256) void k_count(const int* __restrict__ dst,
                                               int* __restrict__ blkhist) {
    __shared__ unsigned h[NBK];
    int tid = threadIdx.x;
    for (int i = tid; i < NBK; i += 256) h[i] = 0;
    __syncthreads();
    const int4* d4 = (const int4*)dst + blockIdx.x * CHUNK4;
    for (int i = tid; i < CHUNK4; i += 256) {
        int4 v = d4[i];
        atomicAdd(&h[v.x >> 9], 1u);
        atomicAdd(&h[v.y >> 9], 1u);
        atomicAdd(&h[v.z >> 9], 1u);
        atomicAdd(&h[v.w >> 9], 1u);
    }
    __syncthreads();
    for (int i = tid; i < NBK; i += 256)
        blkhist[blockIdx.x * NBK + i] = (int)h[i];
}

// ---------------------------------------------------------------------------
// Scan blkhist across blocks (one workgroup per bucket).
// ---------------------------------------------------------------------------
__global__ __launch_bounds__(512) void k_bscan1(const int* __restrict__ blkhist,
                                                int* __restrict__ blkoff_rel,
                                                int* __restrict__ total) {
    __shared__ int tmp[512];
    int bucket = blockIdx.x;
    int t = threadIdx.x;
    int v = (t < NBLK_E) ? blkhist[t * NBK + bucket] : 0;
    tmp[t] = v;
    __syncthreads();
    for (int off = 1; off < 512; off <<= 1) {
        int u = (t >= off) ? tmp[t - off] : 0;
        __syncthreads();
        tmp[t] += u;
        __syncthreads();
    }
    if (t < NBLK_E) blkoff_rel[t * NBK + bucket] = tmp[t] - v;
    if (t == 511) total[bucket] = tmp[t];
}

// Exclusive scan of bucket totals -> bucket_base.
__global__ void k_bscan2(const int* __restrict__ total,
                         int* __restrict__ bucket_base) {
    __shared__ int tmp[256];
    int t = threadIdx.x;  // 256 >= NBK
    int v = (t < NBK) ? total[t] : 0;
    tmp[t] = v;
    __syncthreads();
    for (int off = 1; off < 256; off <<= 1) {
        int u = (t >= off) ? tmp[t - off] : 0;
        __syncthreads();
        tmp[t] += u;
        __syncthreads();
    }
    if (t < NBK) bucket_base[t] = tmp[t] - v;
}

// ---------------------------------------------------------------------------
// Fill pass 1: counting-sort append; LDS atomics only, contiguous runs.
// ---------------------------------------------------------------------------
__global__ __launch_bounds__(256) void k_fill1(const int* __restrict__ src,
                                               const int* __restrict__ dst,
                                               const int* __restrict__ bucket_base,
                                               const int* __restrict__ blkoff_rel,
                                               uint32* __restrict__ pairs) {
    __shared__ int loff[NBK];
    __shared__ unsigned lh[NBK];
    int tid = threadIdx.x;
    for (int i = tid; i < NBK; i += 256) {
        loff[i] = bucket_base[i] + blkoff_rel[blockIdx.x * NBK + i];
        lh[i] = 0;
    }
    __syncthreads();
    const int4* s4 = (const int4*)src + blockIdx.x * CHUNK4;
    const int4* d4 = (const int4*)dst + blockIdx.x * CHUNK4;
    for (int i = tid; i < CHUNK4; i += 256) {
        int4 s = s4[i];
        int4 d = d4[i];
        int b0 = d.x >> 9; int r0 = (int)atomicAdd(&lh[b0], 1u);
        pairs[loff[b0] + r0] = ((uint32)(d.x & 511) << 17) | (uint32)s.x;
        int b1 = d.y >> 9; int r1 = (int)atomicAdd(&lh[b1], 1u);
        pairs[loff[b1] + r1] = ((uint32)(d.y & 511) << 17) | (uint32)s.y;
        int b2 = d.z >> 9; int r2 = (int)atomicAdd(&lh[b2], 1u);
        pairs[loff[b2] + r2] = ((uint32)(d.z & 511) << 17) | (uint32)s.z;
        int b3 = d.w >> 9; int r3 = (int)atomicAdd(&lh[b3], 1u);
        pairs[loff[b3] + r3] = ((uint32)(d.w & 511) << 17) | (uint32)s.w;
    }
}

// ---------------------------------------------------------------------------
// Fill pass 2: one block (1024 thr) per bucket.
// Pass A: count per-node via LDS; scan -> rowptr + dis. Pass B: scatter.
// ---------------------------------------------------------------------------
__global__ __launch_bounds__(1024) void k_fill2(const int* __restrict__ bucket_base,
                                                const int* __restrict__ total,
                                                const uint32* __restrict__ pairs,
                                                int* __restrict__ csr_src,
                                                int* __restrict__ rowptr,
                                                float* __restrict__ dis) {
    __shared__ unsigned lcnt[512];
    __shared__ int tmp[512];
    __shared__ int lcur[512];
    int b = blockIdx.x;
    int node0 = b * 512;
    int tid = threadIdx.x;
    for (int i = tid; i < 512; i += 1024) lcnt[i] = 0;
    __syncthreads();
    int beg = bucket_base[b];
    int endp = beg + total[b];
    for (int j = beg + tid; j < endp; j += 1024)
        atomicAdd(&lcnt[pairs[j] >> 17], 1u);
    __syncthreads();
    if (tid < 512) tmp[tid] = (int)lcnt[tid];
    __syncthreads();
    for (int off = 1; off < 512; off <<= 1) {
        int u = (tid < 512 && tid >= off) ? tmp[tid - off] : 0;
        __syncthreads();
        if (tid < 512) tmp[tid] += u;
        __syncthreads();
    }
    if (tid < 512) {
        int excl = tmp[tid] - (int)lcnt[tid];
        int n = node0 + tid;
        if (n <= Nn) rowptr[n] = beg + excl;
        if (n < Nn) dis[n] = rsqrtf((float)lcnt[tid] + 1.0f);
        lcur[tid] = beg + excl;
    }
    __syncthreads();
    for (int j = beg + tid; j < endp; j += 1024) {
        uint32 p = pairs[j];
        int dl = (int)(p >> 17);
        int s = (int)(p & 0x1FFFFu);
        int pos = atomicAdd(&lcur[dl], 1);
        csr_src[pos] = s;
    }
}

// ---------------------------------------------------------------------------
// W prep: Wb[l][col][k] = bf16(Wl[k][col]) once per call (3 layers).
// ---------------------------------------------------------------------------
__global__ __launch_bounds__(256) void k_wprep(const float* __restrict__ W1,
                                               const float* __restrict__ W2,
                                               const float* __restrict__ W3,
                                               ushort_t* __restrict__ Wb) {
    int l = blockIdx.x >> 6, part = blockIdx.x & 63;
    const float* W = (l == 0) ? W1 : (l == 1) ? W2 : W3;
    int i = part * 256 + threadIdx.x;   // 0..16383, k-major for coalesced read
    int k = i >> 7, col = i & 127;
    Wb[l * 16384 + col * 128 + k] = f2bf(W[k * 128 + col]);
}

// ---------------------------------------------------------------------------
// MFMA GEMM: XW' = dis * (Xin @ W + b), bf16 out. One 64-row tile per block
// (grid 1563). Epilogue transposes through LDS for coalesced uint4 stores.
// ---------------------------------------------------------------------------
__global__ __launch_bounds__(256) void k_gemm(const float* __restrict__ Xf,
                                              const uint32* __restrict__ Xb,
                                              const ushort_t* __restrict__ Wb,
                                              const float* __restrict__ Bv,
                                              const float* __restrict__ bnp,
                                              const float* __restrict__ dis,
                                              ushort_t* __restrict__ XWb) {
    __shared__ ushort_t Wlds[128 * 136];
    __shared__ ushort_t Xlds[64 * 136];
    const int tid = threadIdx.x;
    const int rowbase = blockIdx.x * 64;

    // Stage W from pre-converted bf16 (coalesced 16B copies)
#pragma unroll
    for (int it = 0; it < 8; ++it) {
        int chunk = tid + it * 256;      // 2048 chunks of 8 ushorts
        int col = chunk >> 4, kg = chunk & 15;
        *(ushort8_t*)&Wlds[col * 136 + kg * 8] =
            *(const ushort8_t*)&Wb[col * 128 + kg * 8];
    }
    // Stage X tile (64 rows x 128), fused BN+ReLU on bf16 path
    {
        int row = tid >> 2, q = tid & 3;
        int g = rowbase + row;
        if (bnp == nullptr) {
            const float4* Xr = (const float4*)(Xf + (size_t)g * 128);
#pragma unroll
            for (int it = 0; it < 8; ++it) {
                int c4 = q + it * 4;
                float4 v;
                if (g < Nn) v = Xr[c4];
                else { v.x = v.y = v.z = v.w = 0.f; }
                ushort4 o;
                o.x = f2bf(v.x); o.y = f2bf(v.y); o.z = f2bf(v.z); o.w = f2bf(v.w);
                *(ushort4*)&Xlds[row * 136 + c4 * 4] = o;
            }
        } else {
            const uint4* Hr = (const uint4*)(Xb + (size_t)g * 64);
#pragma unroll
            for (int it = 0; it < 4; ++it) {
                int i4 = q + it * 4;
                int c0 = i4 * 8;
                ushort8_t o;
                if (g < Nn) {
                    uint4 u = Hr[i4];
                    float4 sca = *(const float4*)&bnp[c0];
                    float4 scb = *(const float4*)&bnp[c0 + 4];
                    float4 sha = *(const float4*)&bnp[128 + c0];
                    float4 shb = *(const float4*)&bnp[128 + c0 + 4];
                    o[0] = f2bf(fmaxf(fmaf(bflo(u.x), sca.x, sha.x), 0.f));
                    o[1] = f2bf(fmaxf(fmaf(bfhi(u.x), sca.y, sha.y), 0.f));
                    o[2] = f2bf(fmaxf(fmaf(bflo(u.y), sca.z, sha.z), 0.f));
                    o[3] = f2bf(fmaxf(fmaf(bfhi(u.y), sca.w, sha.w), 0.f));
                    o[4] = f2bf(fmaxf(fmaf(bflo(u.z), scb.x, shb.x), 0.f));
                    o[5] = f2bf(fmaxf(fmaf(bfhi(u.z), scb.y, shb.y), 0.f));
                    o[6] = f2bf(fmaxf(fmaf(bflo(u.w), scb.z, shb.z), 0.f));
                    o[7] = f2bf(fmaxf(fmaf(bfhi(u.w), scb.w, shb.w), 0.f));
                } else {
                    for (int j = 0; j < 8; ++j) o[j] = 0;
                }
                *(ushort8_t*)&Xlds[row * 136 + c0] = o;
            }
        }
    }
    __syncthreads();

    const int wid = tid >> 6, lane = tid & 63;
    const int arow = wid * 16 + (lane & 15);
    const int koff = (lane >> 4) * 8;
    const int bcol = lane & 15;

    f32x4_t acc[8];
#pragma unroll
    for (int nt = 0; nt < 8; ++nt) acc[nt] = (f32x4_t){0.f, 0.f, 0.f, 0.f};

#pragma unroll
    for (int kt = 0; kt < 4; ++kt) {
        short8_t a = *(const short8_t*)&Xlds[arow * 136 + kt * 32 + koff];
#pragma unroll
        for (int nt = 0; nt < 8; ++nt) {
            short8_t b = *(const short8_t*)&Wlds[(nt * 16 + bcol) * 136 + kt * 32 + koff];
            acc[nt] = __builtin_amdgcn_mfma_f32_16x16x32_bf16(a, b, acc[nt], 0, 0, 0);
        }
    }

    // Epilogue: (acc + bias) * dis -> bf16 into Xlds, then coalesced stores.
    int er = wid * 16 + (lane >> 4) * 4;
    int r0 = rowbase + er;
    float dv[4];
#pragma unroll
    for (int i = 0; i < 4; ++i) dv[i] = (r0 + i < Nn) ? dis[r0 + i] : 0.f;
    __syncthreads();   // A-fragment reads done; safe to overwrite Xlds
#pragma unroll
    for (int nt = 0; nt < 8; ++nt) {
        int col = nt * 16 + bcol;
        float bs = Bv[col];
#pragma unroll
        for (int i = 0; i < 4; ++i)
            Xlds[(er + i) * 136 + col] = f2bf((acc[nt][i] + bs) * dv[i]);
    }
    __syncthreads();
#pragma unroll
    for (int it = 0; it < 4; ++it) {
        int chunk = tid + it * 256;      // 1024 chunks of 16B
        int row = chunk >> 4, cg = chunk & 15;
        int g = rowbase + row;
        if (g < Nn)
            *(uint4*)&XWb[(size_t)g * 128 + cg * 8] =
                *(const uint4*)&Xlds[row * 136 + cg * 8];
    }
}

// ---------------------------------------------------------------------------
// Aggregate: HP[i] = dis[i]*(sum XW'[src] + XW'[i]); bf16 out.
// 2 nodes per wave, 8B/lane rows. Indices staged through LDS: one coalesced
// vmem load per 32 edges/half; inner loop reads them via broadcast ds_read.
// ---------------------------------------------------------------------------
__global__ __launch_bounds__(256) void k_agg(const uint32* __restrict__ XW32,
                                             const float* __restrict__ dis,
                                             const int* __restrict__ rowptr,
                                             const int* __restrict__ csr_src,
                                             uint32* __restrict__ HP32) {
    __shared__ int sidx[256];
    int w = threadIdx.x >> 6;
    int lane = threadIdx.x & 63;
    int half = lane >> 5, li = lane & 31;
    int node = (blockIdx.x * 4 + w) * 2 + half;
    const uint2* XW64 = (const uint2*)XW32;
    int beg = rowptr[node], end = rowptr[node + 1];
    int* widx = &sidx[w * 64];
    float a0 = 0.f, a1 = 0.f, a2 = 0.f, a3 = 0.f;
    int base = beg;
    while (__any(base < end)) {
        int j = base + li;
        if (j < end) widx[lane] = csr_src[j];
        __builtin_amdgcn_wave_barrier();
        int m = end - base; m = (m > 32) ? 32 : m;
        int k = 0;
        for (; k + 8 <= m; k += 8) {
            int s0 = widx[half * 32 + k + 0];
            int s1 = widx[half * 32 + k + 1];
            int s2 = widx[half * 32 + k + 2];
            int s3 = widx[half * 32 + k + 3];
            int s4 = widx[half * 32 + k + 4];
            int s5 = widx[half * 32 + k + 5];
            int s6 = widx[half * 32 + k + 6];
            int s7 = widx[half * 32 + k + 7];
            uint2 v0 = XW64[(size_t)s0 * 32 + li];
            uint2 v1 = XW64[(size_t)s1 * 32 + li];
            uint2 v2 = XW64[(size_t)s2 * 32 + li];
            uint2 v3 = XW64[(size_t)s3 * 32 + li];
            uint2 v4 = XW64[(size_t)s4 * 32 + li];
            uint2 v5 = XW64[(size_t)s5 * 32 + li];
            uint2 v6 = XW64[(size_t)s6 * 32 + li];
            uint2 v7 = XW64[(size_t)s7 * 32 + li];
            a0 += bflo(v0.x); a1 += bfhi(v0.x); a2 += bflo(v0.y); a3 += bfhi(v0.y);
            a0 += bflo(v1.x); a1 += bfhi(v1.x); a2 += bflo(v1.y); a3 += bfhi(v1.y);
            a0 += bflo(v2.x); a1 += bfhi(v2.x); a2 += bflo(v2.y); a3 += bfhi(v2.y);
            a0 += bflo(v3.x); a1 += bfhi(v3.x); a2 += bflo(v3.y); a3 += bfhi(v3.y);
            a0 += bflo(v4.x); a1 += bfhi(v4.x); a2 += bflo(v4.y); a3 += bfhi(v4.y);
            a0 += bflo(v5.x); a1 += bfhi(v5.x); a2 += bflo(v5.y); a3 += bfhi(v5.y);
            a0 += bflo(v6.x); a1 += bfhi(v6.x); a2 += bflo(v6.y); a3 += bfhi(v6.y);
            a0 += bflo(v7.x); a1 += bfhi(v7.x); a2 += bflo(v7.y); a3 += bfhi(v7.y);
        }
        for (; k < m; ++k) {
            int s = widx[half * 32 + k];
            uint2 v = XW64[(size_t)s * 32 + li];
            a0 += bflo(v.x); a1 += bfhi(v.x); a2 += bflo(v.y); a3 += bfhi(v.y);
        }
        base += 32;
        __builtin_amdgcn_wave_barrier();
    }
    uint2 vs = XW64[(size_t)node * 32 + li];
    a0 += bflo(vs.x); a1 += bfhi(vs.x); a2 += bflo(vs.y); a3 += bfhi(vs.y);
    float d = dis[node];
    uint2 r;
    r.x = (uint32)f2bf(a0 * d) | ((uint32)f2bf(a1 * d) << 16);
    r.y = (uint32)f2bf(a2 * d) | ((uint32)f2bf(a3 * d) << 16);
    ((uint2*)HP32)[(size_t)node * 32 + li] = r;
}

// ---------------------------------------------------------------------------
// BN stats level 1: 256 blocks; register accum; LDS reduce; ONE coalesced
// partials-row write per block. Zero global atomics.
// ---------------------------------------------------------------------------
__global__ __launch_bounds__(256) void k_statsA(const uint32* __restrict__ HP32,
                                                float* __restrict__ partials) {
    const uint2* HPu2 = (const uint2*)HP32;
    int tid = threadIdx.x;
    int li = tid & 31;          // uint2 index within row
    int s  = tid >> 5;          // row slot 0..7
    float s0 = 0.f, s1 = 0.f, s2 = 0.f, s3 = 0.f;
    float q0 = 0.f, q1 = 0.f, q2 = 0.f, q3 = 0.f;
    for (int r = blockIdx.x * 8 + s; r < Nn; r += NSTATB * 8) {
        uint2 v = HPu2[(size_t)r * 32 + li];
        float a = bflo(v.x), b = bfhi(v.x), c = bflo(v.y), d = bfhi(v.y);
        s0 += a; s1 += b; s2 += c; s3 += d;
        q0 = fmaf(a, a, q0); q1 = fmaf(b, b, q1);
        q2 = fmaf(c, c, q2); q3 = fmaf(d, d, q3);
    }
    __shared__ float arr[8 * 256];
    float* mine = &arr[s * 256 + li * 4];
    mine[0] = s0; mine[1] = s1; mine[2] = s2; mine[3] = s3;
    mine[128] = q0; mine[129] = q1; mine[130] = q2; mine[131] = q3;
    __syncthreads();
    float tot = 0.f;
#pragma unroll
    for (int k = 0; k < 8; ++k) tot += arr[k * 256 + tid];
    partials[blockIdx.x * 256 + tid] = tot;
}

// ---------------------------------------------------------------------------
// BN stats level 2 + bnfinal: 1 block x 1024 thr.
// ---------------------------------------------------------------------------
__global__ __launch_bounds__(1024) void k_statsB(const float* __restrict__ partials,
                                                 const float* __restrict__ g,
                                                 const float* __restrict__ bt,
                                                 float* __restrict__ bnp) {
    int tid = threadIdx.x;
    int sub = tid >> 8;         // 0..3
    int t = tid & 255;
    float acc = 0.f;
#pragma unroll 8
    for (int r = sub * 64; r < sub * 64 + 64; ++r)
        acc += partials[r * 256 + t];
    __shared__ float red[4 * 256];
    red[sub * 256 + t] = acc;
    __syncthreads();
    __shared__ float tot[256];
    if (tid < 256)
        tot[tid] = red[tid] + red[256 + tid] + red[512 + tid] + red[768 + tid];
    __syncthreads();
    if (tid < 128) {
        float mu  = tot[tid] * (1.0f / Nn);
        float var = tot[128 + tid] * (1.0f / Nn) - mu * mu;
        float sc  = g[tid] * rsqrtf(var + BN_EPS);
        bnp[tid]       = sc;
        bnp[128 + tid] = bt[tid] - mu * sc;
    }
}

// ---------------------------------------------------------------------------
// Fused BN+ReLU + mean-pool + FC1(relu) + FC2. One block (128 thr) per graph.
// ---------------------------------------------------------------------------
__global__ __launch_bounds__(128) void k_pool_fc(const ushort_t* __restrict__ HP16,
                                                 const float* __restrict__ bnp,
                                                 const int* __restrict__ batch,
                                                 const float* __restrict__ fcw1,
                                                 const float* __restrict__ fcb1,
                                                 const float* __restrict__ fcw2,
                                                 const float* __restrict__ fcb2,
                                                 float* __restrict__ out) {
    int g = blockIdx.x;
    int t = threadIdx.x;
    int lo = 0, hi = Nn;
    while (lo < hi) { int mid = (lo + hi) >> 1; if (batch[mid] < g) lo = mid + 1; else hi = mid; }
    int start = lo;
    hi = Nn;
    while (lo < hi) { int mid = (lo + hi) >> 1; if (batch[mid] < g + 1) lo = mid + 1; else hi = mid; }
    int end = lo;

    float sc = bnp[t], sh = bnp[128 + t];
    float acc = 0.f;
    for (int i = start; i < end; ++i) {
        union { uint32 u; float f; } c;
        c.u = (uint32)HP16[(size_t)i * 128 + t] << 16;
        acc += fmaxf(fmaf(c.f, sc, sh), 0.f);
    }
    float inv = 1.0f / fmaxf((float)(end - start), 1.0f);

    __shared__ float p[128];
    __shared__ float h1[64];
    p[t] = acc * inv;
    __syncthreads();
    if (t < 64) {
        float s = fcb1[t];
        for (int k = 0; k < 128; ++k) s = fmaf(p[k], fcw1[k * 64 + t], s);
        h1[t] = fmaxf(s, 0.f);
    }
    __syncthreads();
    if (t < 64) {
        float v = h1[t] * fcw2[t];
        for (int off = 32; off > 0; off >>= 1) v += __shfl_down(v, off, 64);
        if (t == 0) out[g] = v + fcb2[0];
    }
}

// ---------------------------------------------------------------------------
extern "C" void kernel_launch(void* const* d_in, const int* in_sizes, int n_in,
                              void* d_out, int out_size, void* d_ws, size_t ws_size,
                              hipStream_t stream) {
    const float* x     = (const float*)d_in[0];
    const int*   ei    = (const int*)d_in[1];
    const int*   batch = (const int*)d_in[2];
    const float* W1  = (const float*)d_in[3];
    const float* b1  = (const float*)d_in[4];
    const float* g1  = (const float*)d_in[5];
    const float* bt1 = (const float*)d_in[6];
    const float* W2  = (const float*)d_in[7];
    const float* b2  = (const float*)d_in[8];
    const float* g2  = (const float*)d_in[9];
    const float* bt2 = (const float*)d_in[10];
    const float* W3  = (const float*)d_in[11];
    const float* b3  = (const float*)d_in[12];
    const float* g3  = (const float*)d_in[13];
    const float* bt3 = (const float*)d_in[14];
    const float* fcw1 = (const float*)d_in[15];
    const float* fcb1 = (const float*)d_in[16];
    const float* fcw2 = (const float*)d_in[17];
    const float* fcb2 = (const float*)d_in[18];
    float* out = (float*)d_out;

    // Workspace layout
    ushort_t* XWb     = (ushort_t*)d_ws;                      // [N*128] bf16
    uint32*   HP32    = (uint32*)(XWb + (size_t)Nn * HH);     // [N*64] bf16x2
    float*    dis     = (float*)(HP32 + (size_t)Nn * 64);     // [N]
    int*      rowptr  = (int*)(dis + Nn);                     // [N+1]
    int*      blkhist = rowptr + (Nn + 1);                    // [500*196]
    int*      blkoff_rel = blkhist + NBLK_E * NBK;            // [500*196]
    int*      total   = blkoff_rel + NBLK_E * NBK;            // [196]
    int*      bucket_base = total + NBK;                      // [196]
    uint32*   pairs   = (uint32*)(bucket_base + NBK);         // [E]
    int*      csr_src = (int*)(pairs + Ee);                   // [E]
    float*    partials = (float*)(csr_src + Ee);              // [256*256]
    float*    bnp     = partials + NSTATB * 256;              // [3*256]
    ushort_t* Wb      = (ushort_t*)(bnp + 768);               // [3*128*128]

    const int* src = ei;
    const int* dst = ei + Ee;

    k_count<<<NBLK_E, 256, 0, stream>>>(dst, blkhist);
    k_wprep<<<192, 256, 0, stream>>>(W1, W2, W3, Wb);
    k_bscan1<<<NBK, 512, 0, stream>>>(blkhist, blkoff_rel, total);
    k_bscan2<<<1, 256, 0, stream>>>(total, bucket_base);
    k_fill1<<<NBLK_E, 256, 0, stream>>>(src, dst, bucket_base, blkoff_rel, pairs);
    k_fill2<<<NBK, 1024, 0, stream>>>(bucket_base, total, pairs, csr_src, rowptr, dis);

    const float* bs_[3]  = {b1, b2, b3};
    const float* gs_[3]  = {g1, g2, g3};
    const float* bts_[3] = {bt1, bt2, bt3};
    const int ngemm = (Nn + 63) / 64;  // 1563
    for (int l = 0; l < 3; ++l) {
        const float* bnp_in = (l == 0) ? nullptr : (bnp + (l - 1) * 256);
        k_gemm<<<ngemm, 256, 0, stream>>>(x, HP32, Wb + l * 16384, bs_[l], bnp_in, dis, XWb);
        k_agg<<<12500, 256, 0, stream>>>((const uint32*)XWb, dis, rowptr, csr_src, HP32);
        k_statsA<<<NSTATB, 256, 0, stream>>>(HP32, partials);
        k_statsB<<<1, 1024, 0, stream>>>(partials, gs_[l], bts_[l], bnp + l * 256);
    }
    k_pool_fc<<<Gg, 128, 0, stream>>>((const ushort_t*)HP32, bnp + 512, batch,
                                      fcw1, fcb1, fcw2, fcb2, out);
}

// Round 11
// 311.100 us; speedup vs baseline: 2.8088x; 1.1625x over previous
//
#include <hip/hip_runtime.h>
#include <math.h>

#define Nn 100000
#define Ee 1600000
#define Gg 2048
#define HH 128
#define BN_EPS 1e-5f

#define NBK 196        // ceil(100000/512) buckets of 512 nodes
#define NBLK_E 500     // edge-pass blocks
#define CHUNK4 800     // int4s per block (500*3200 = 1.6M edges)
#define NSTATB 256     // stats level-1 blocks

typedef unsigned int uint32;
typedef unsigned char uchar_t;
typedef unsigned short ushort_t;
typedef __attribute__((ext_vector_type(8))) short short8_t;
typedef __attribute__((ext_vector_type(8))) unsigned short ushort8_t;
typedef __attribute__((ext_vector_type(4))) float f32x4_t;

__device__ __forceinline__ ushort_t f2bf(float f) {
    union { float f; uint32 u; } c; c.f = f;
    uint32 r = (c.u + 0x7FFFu + ((c.u >> 16) & 1u)) >> 16;   // RTNE
    return (ushort_t)r;
}
__device__ __forceinline__ float bflo(uint32 v) {
    union { uint32 u; float f; } c; c.u = v << 16; return c.f;
}
__device__ __forceinline__ float bfhi(uint32 v) {
    union { uint32 u; float f; } c; c.u = v & 0xFFFF0000u; return c.f;
}
__device__ __forceinline__ int q8(float f, float inv) {
    float t = f * inv;
    t = fmaxf(fminf(t, 127.f), -127.f);
    return (int)rintf(t);
}

// ---------------------------------------------------------------------------
// Count: per-BLOCK bucket histogram only. NO global atomics.
// ---------------------------------------------------------------------------
__global__ __launch_bounds__(256) void k_count(const int* __restrict__ dst,
                                               int* __restrict__ blkhist) {
    __shared__ unsigned h[NBK];
    int tid = threadIdx.x;
    for (int i = tid; i < NBK; i += 256) h[i] = 0;
    __syncthreads();
    const int4* d4 = (const int4*)dst + blockIdx.x * CHUNK4;
    for (int i = tid; i < CHUNK4; i += 256) {
        int4 v = d4[i];
        atomicAdd(&h[v.x >> 9], 1u);
        atomicAdd(&h[v.y >> 9], 1u);
        atomicAdd(&h[v.z >> 9], 1u);
        atomicAdd(&h[v.w >> 9], 1u);
    }
    __syncthreads();
    for (int i = tid; i < NBK; i += 256)
        blkhist[blockIdx.x * NBK + i] = (int)h[i];
}

// ---------------------------------------------------------------------------
// Scan blkhist across blocks (one workgroup per bucket).
// ---------------------------------------------------------------------------
__global__ __launch_bounds__(512) void k_bscan1(const int* __restrict__ blkhist,
                                                int* __restrict__ blkoff_rel,
                                                int* __restrict__ total) {
    __shared__ int tmp[512];
    int bucket = blockIdx.x;
    int t = threadIdx.x;
    int v = (t < NBLK_E) ? blkhist[t * NBK + bucket] : 0;
    tmp[t] = v;
    __syncthreads();
    for (int off = 1; off < 512; off <<= 1) {
        int u = (t >= off) ? tmp[t - off] : 0;
        __syncthreads();
        tmp[t] += u;
        __syncthreads();
    }
    if (t < NBLK_E) blkoff_rel[t * NBK + bucket] = tmp[t] - v;
    if (t == 511) total[bucket] = tmp[t];
}

// Exclusive scan of bucket totals -> bucket_base.
__global__ void k_bscan2(const int* __restrict__ total,
                         int* __restrict__ bucket_base) {
    __shared__ int tmp[256];
    int t = threadIdx.x;  // 256 >= NBK
    int v = (t < NBK) ? total[t] : 0;
    tmp[t] = v;
    __syncthreads();
    for (int off = 1; off < 256; off <<= 1) {
        int u = (t >= off) ? tmp[t - off] : 0;
        __syncthreads();
        tmp[t] += u;
        __syncthreads();
    }
    if (t < NBK) bucket_base[t] = tmp[t] - v;
}

// ---------------------------------------------------------------------------
// Fill pass 1: counting-sort append; LDS atomics only, contiguous runs.
// ---------------------------------------------------------------------------
__global__ __launch_bounds__(256) void k_fill1(const int* __restrict__ src,
                                               const int* __restrict__ dst,
                                               const int* __restrict__ bucket_base,
                                               const int* __restrict__ blkoff_rel,
                                               uint32* __restrict__ pairs) {
    __shared__ int loff[NBK];
    __shared__ unsigned lh[NBK];
    int tid = threadIdx.x;
    for (int i = tid; i < NBK; i += 256) {
        loff[i] = bucket_base[i] + blkoff_rel[blockIdx.x * NBK + i];
        lh[i] = 0;
    }
    __syncthreads();
    const int4* s4 = (const int4*)src + blockIdx.x * CHUNK4;
    const int4* d4 = (const int4*)dst + blockIdx.x * CHUNK4;
    for (int i = tid; i < CHUNK4; i += 256) {
        int4 s = s4[i];
        int4 d = d4[i];
        int b0 = d.x >> 9; int r0 = (int)atomicAdd(&lh[b0], 1u);
        pairs[loff[b0] + r0] = ((uint32)(d.x & 511) << 17) | (uint32)s.x;
        int b1 = d.y >> 9; int r1 = (int)atomicAdd(&lh[b1], 1u);
        pairs[loff[b1] + r1] = ((uint32)(d.y & 511) << 17) | (uint32)s.y;
        int b2 = d.z >> 9; int r2 = (int)atomicAdd(&lh[b2], 1u);
        pairs[loff[b2] + r2] = ((uint32)(d.z & 511) << 17) | (uint32)s.z;
        int b3 = d.w >> 9; int r3 = (int)atomicAdd(&lh[b3], 1u);
        pairs[loff[b3] + r3] = ((uint32)(d.w & 511) << 17) | (uint32)s.w;
    }
}

// ---------------------------------------------------------------------------
// Fill pass 2: one block (1024 thr) per bucket.
// Pass A: count per-node via LDS; scan -> rowptr + dis. Pass B: scatter.
// ---------------------------------------------------------------------------
__global__ __launch_bounds__(1024) void k_fill2(const int* __restrict__ bucket_base,
                                                const int* __restrict__ total,
                                                const uint32* __restrict__ pairs,
                                                int* __restrict__ csr_src,
                                                int* __restrict__ rowptr,
                                                float* __restrict__ dis) {
    __shared__ unsigned lcnt[512];
    __shared__ int tmp[512];
    __shared__ int lcur[512];
    int b = blockIdx.x;
    int node0 = b * 512;
    int tid = threadIdx.x;
    for (int i = tid; i < 512; i += 1024) lcnt[i] = 0;
    __syncthreads();
    int beg = bucket_base[b];
    int endp = beg + total[b];
    for (int j = beg + tid; j < endp; j += 1024)
        atomicAdd(&lcnt[pairs[j] >> 17], 1u);
    __syncthreads();
    if (tid < 512) tmp[tid] = (int)lcnt[tid];
    __syncthreads();
    for (int off = 1; off < 512; off <<= 1) {
        int u = (tid < 512 && tid >= off) ? tmp[tid - off] : 0;
        __syncthreads();
        if (tid < 512) tmp[tid] += u;
        __syncthreads();
    }
    if (tid < 512) {
        int excl = tmp[tid] - (int)lcnt[tid];
        int n = node0 + tid;
        if (n <= Nn) rowptr[n] = beg + excl;
        if (n < Nn) dis[n] = rsqrtf((float)lcnt[tid] + 1.0f);
        lcur[tid] = beg + excl;
    }
    __syncthreads();
    for (int j = beg + tid; j < endp; j += 1024) {
        uint32 p = pairs[j];
        int dl = (int)(p >> 17);
        int s = (int)(p & 0x1FFFFu);
        int pos = atomicAdd(&lcur[dl], 1);
        csr_src[pos] = s;
    }
}

// ---------------------------------------------------------------------------
// W prep: Wb[l][col][k] = bf16(Wl[k][col]) once per call (3 layers).
// ---------------------------------------------------------------------------
__global__ __launch_bounds__(256) void k_wprep(const float* __restrict__ W1,
                                               const float* __restrict__ W2,
                                               const float* __restrict__ W3,
                                               ushort_t* __restrict__ Wb) {
    int l = blockIdx.x >> 6, part = blockIdx.x & 63;
    const float* W = (l == 0) ? W1 : (l == 1) ? W2 : W3;
    int i = part * 256 + threadIdx.x;
    int k = i >> 7, col = i & 127;
    Wb[l * 16384 + col * 128 + k] = f2bf(W[k * 128 + col]);
}

// ---------------------------------------------------------------------------
// MFMA GEMM: XW' = dis * (Xin @ W + b), int8 out with per-row scale.
// One 64-row tile per block. Epilogue: row-max via shfl, bf16 LDS transpose,
// quantize on coalesced store (rows = exactly one 128B line).
// ---------------------------------------------------------------------------
__global__ __launch_bounds__(256) void k_gemm(const float* __restrict__ Xf,
                                              const uint32* __restrict__ Xb,
                                              const ushort_t* __restrict__ Wb,
                                              const float* __restrict__ Bv,
                                              const float* __restrict__ bnp,
                                              const float* __restrict__ dis,
                                              uchar_t* __restrict__ XW8,
                                              float* __restrict__ sc_src) {
    __shared__ ushort_t Wlds[128 * 136];
    __shared__ ushort_t Xlds[64 * 136];
    __shared__ float smax[64];
    const int tid = threadIdx.x;
    const int rowbase = blockIdx.x * 64;

    // Stage W from pre-converted bf16 (coalesced 16B copies)
#pragma unroll
    for (int it = 0; it < 8; ++it) {
        int chunk = tid + it * 256;
        int col = chunk >> 4, kg = chunk & 15;
        *(ushort8_t*)&Wlds[col * 136 + kg * 8] =
            *(const ushort8_t*)&Wb[col * 128 + kg * 8];
    }
    // Stage X tile (64 rows x 128), fused BN+ReLU on bf16 path
    {
        int row = tid >> 2, q = tid & 3;
        int g = rowbase + row;
        if (bnp == nullptr) {
            const float4* Xr = (const float4*)(Xf + (size_t)g * 128);
#pragma unroll
            for (int it = 0; it < 8; ++it) {
                int c4 = q + it * 4;
                float4 v;
                if (g < Nn) v = Xr[c4];
                else { v.x = v.y = v.z = v.w = 0.f; }
                ushort4 o;
                o.x = f2bf(v.x); o.y = f2bf(v.y); o.z = f2bf(v.z); o.w = f2bf(v.w);
                *(ushort4*)&Xlds[row * 136 + c4 * 4] = o;
            }
        } else {
            const uint4* Hr = (const uint4*)(Xb + (size_t)g * 64);
#pragma unroll
            for (int it = 0; it < 4; ++it) {
                int i4 = q + it * 4;
                int c0 = i4 * 8;
                ushort8_t o;
                if (g < Nn) {
                    uint4 u = Hr[i4];
                    float4 sca = *(const float4*)&bnp[c0];
                    float4 scb = *(const float4*)&bnp[c0 + 4];
                    float4 sha = *(const float4*)&bnp[128 + c0];
                    float4 shb = *(const float4*)&bnp[128 + c0 + 4];
                    o[0] = f2bf(fmaxf(fmaf(bflo(u.x), sca.x, sha.x), 0.f));
                    o[1] = f2bf(fmaxf(fmaf(bfhi(u.x), sca.y, sha.y), 0.f));
                    o[2] = f2bf(fmaxf(fmaf(bflo(u.y), sca.z, sha.z), 0.f));
                    o[3] = f2bf(fmaxf(fmaf(bfhi(u.y), sca.w, sha.w), 0.f));
                    o[4] = f2bf(fmaxf(fmaf(bflo(u.z), scb.x, shb.x), 0.f));
                    o[5] = f2bf(fmaxf(fmaf(bfhi(u.z), scb.y, shb.y), 0.f));
                    o[6] = f2bf(fmaxf(fmaf(bflo(u.w), scb.z, shb.z), 0.f));
                    o[7] = f2bf(fmaxf(fmaf(bfhi(u.w), scb.w, shb.w), 0.f));
                } else {
                    for (int j = 0; j < 8; ++j) o[j] = 0;
                }
                *(ushort8_t*)&Xlds[row * 136 + c0] = o;
            }
        }
    }
    __syncthreads();

    const int wid = tid >> 6, lane = tid & 63;
    const int arow = wid * 16 + (lane & 15);
    const int koff = (lane >> 4) * 8;
    const int bcol = lane & 15;

    f32x4_t acc[8];
#pragma unroll
    for (int nt = 0; nt < 8; ++nt) acc[nt] = (f32x4_t){0.f, 0.f, 0.f, 0.f};

#pragma unroll
    for (int kt = 0; kt < 4; ++kt) {
        short8_t a = *(const short8_t*)&Xlds[arow * 136 + kt * 32 + koff];
#pragma unroll
        for (int nt = 0; nt < 8; ++nt) {
            short8_t b = *(const short8_t*)&Wlds[(nt * 16 + bcol) * 136 + kt * 32 + koff];
            acc[nt] = __builtin_amdgcn_mfma_f32_16x16x32_bf16(a, b, acc[nt], 0, 0, 0);
        }
    }

    // Epilogue: v = (acc + bias) * dis; row-max via shfl; bf16 into Xlds.
    int er = wid * 16 + (lane >> 4) * 4;
    int r0 = rowbase + er;
    float dv[4];
#pragma unroll
    for (int i = 0; i < 4; ++i) dv[i] = (r0 + i < Nn) ? dis[r0 + i] : 0.f;
    __syncthreads();   // A-fragment reads done; safe to overwrite Xlds
    float bs[8];
#pragma unroll
    for (int nt = 0; nt < 8; ++nt) bs[nt] = Bv[nt * 16 + bcol];
    float rmax[4];
#pragma unroll
    for (int i = 0; i < 4; ++i) {
        float m = 0.f;
#pragma unroll
        for (int nt = 0; nt < 8; ++nt) {
            float v = (acc[nt][i] + bs[nt]) * dv[i];
            m = fmaxf(m, fabsf(v));
            Xlds[(er + i) * 136 + nt * 16 + bcol] = f2bf(v);
        }
        // reduce across the 16 lanes (bcol) holding this row
        m = fmaxf(m, __shfl_xor(m, 1));
        m = fmaxf(m, __shfl_xor(m, 2));
        m = fmaxf(m, __shfl_xor(m, 4));
        m = fmaxf(m, __shfl_xor(m, 8));
        rmax[i] = m;
        if (bcol == 0) smax[er + i] = m;
    }
    __syncthreads();
    // Store phase: quantize bf16 tile to int8 rows (128B = 1 line) + scale.
#pragma unroll
    for (int it = 0; it < 4; ++it) {
        int chunk = tid + it * 256;      // 1024 chunks of 8 bytes
        int row = chunk >> 4, cg = chunk & 15;
        int g = rowbase + row;
        if (g < Nn) {
            float mx = smax[row];
            float inv = (mx > 0.f) ? (127.0f / mx) : 0.f;
            uint4 u = *(const uint4*)&Xlds[row * 136 + cg * 8];
            int b0 = q8(bflo(u.x), inv), b1 = q8(bfhi(u.x), inv);
            int b2 = q8(bflo(u.y), inv), b3 = q8(bfhi(u.y), inv);
            int b4 = q8(bflo(u.z), inv), b5 = q8(bfhi(u.z), inv);
            int b6 = q8(bflo(u.w), inv), b7 = q8(bfhi(u.w), inv);
            uint2 o;
            o.x = (uint32)(b0 & 255) | ((uint32)(b1 & 255) << 8) |
                  ((uint32)(b2 & 255) << 16) | ((uint32)(b3 & 255) << 24);
            o.y = (uint32)(b4 & 255) | ((uint32)(b5 & 255) << 8) |
                  ((uint32)(b6 & 255) << 16) | ((uint32)(b7 & 255) << 24);
            *(uint2*)&XW8[(size_t)g * 128 + cg * 8] = o;
            if (cg == 0) sc_src[g] = mx * (1.0f / 127.0f);
        }
    }
}

// ---------------------------------------------------------------------------
// Aggregate: HP[i] = dis[i]*(sum XW'[src] + XW'[i]); bf16 out.
// int8 rows (128B = 1 line); 2 nodes per wave, 4B/lane. (idx,scale) pairs
// staged in LDS: 2 coalesced/gather vmem per 32 edges, broadcast ds_reads.
// ---------------------------------------------------------------------------
__global__ __launch_bounds__(256) void k_agg(const uint32* __restrict__ XW32,
                                             const float* __restrict__ sc_src,
                                             const float* __restrict__ dis,
                                             const int* __restrict__ rowptr,
                                             const int* __restrict__ csr_src,
                                             uint32* __restrict__ HP32) {
    __shared__ uint2 spair[256];
    int w = threadIdx.x >> 6;
    int lane = threadIdx.x & 63;
    int half = lane >> 5, li = lane & 31;
    int node = (blockIdx.x * 4 + w) * 2 + half;
    int beg = rowptr[node], end = rowptr[node + 1];
    uint2* wpair = &spair[w * 64];
    float a0 = 0.f, a1 = 0.f, a2 = 0.f, a3 = 0.f;
    int base = beg;
    while (__any(base < end)) {
        int j = base + li;
        if (j < end) {
            int s = csr_src[j];
            float sc = sc_src[s];
            uint2 p; p.x = (uint32)s; p.y = __float_as_uint(sc);
            wpair[lane] = p;
        }
        __builtin_amdgcn_wave_barrier();
        int m = end - base; m = (m > 32) ? 32 : m;
        for (int k = 0; k < m; ++k) {
            uint2 p = wpair[half * 32 + k];
            uint32 u = XW32[(size_t)p.x * 32 + li];
            float sc = __uint_as_float(p.y);
            int b0 = (int)(u << 24) >> 24;
            int b1 = (int)(u << 16) >> 24;
            int b2 = (int)(u << 8) >> 24;
            int b3 = (int)u >> 24;
            a0 = fmaf((float)b0, sc, a0);
            a1 = fmaf((float)b1, sc, a1);
            a2 = fmaf((float)b2, sc, a2);
            a3 = fmaf((float)b3, sc, a3);
        }
        base += 32;
        __builtin_amdgcn_wave_barrier();
    }
    {   // self term
        uint32 u = XW32[(size_t)node * 32 + li];
        float sc = sc_src[node];
        int b0 = (int)(u << 24) >> 24;
        int b1 = (int)(u << 16) >> 24;
        int b2 = (int)(u << 8) >> 24;
        int b3 = (int)u >> 24;
        a0 = fmaf((float)b0, sc, a0);
        a1 = fmaf((float)b1, sc, a1);
        a2 = fmaf((float)b2, sc, a2);
        a3 = fmaf((float)b3, sc, a3);
    }
    float d = dis[node];
    uint2 r;
    r.x = (uint32)f2bf(a0 * d) | ((uint32)f2bf(a1 * d) << 16);
    r.y = (uint32)f2bf(a2 * d) | ((uint32)f2bf(a3 * d) << 16);
    ((uint2*)HP32)[(size_t)node * 32 + li] = r;
}

// ---------------------------------------------------------------------------
// BN stats level 1: 256 blocks; register accum; LDS reduce; ONE coalesced
// partials-row write per block. Zero global atomics.
// ---------------------------------------------------------------------------
__global__ __launch_bounds__(256) void k_statsA(const uint32* __restrict__ HP32,
                                                float* __restrict__ partials) {
    const uint2* HPu2 = (const uint2*)HP32;
    int tid = threadIdx.x;
    int li = tid & 31;
    int s  = tid >> 5;
    float s0 = 0.f, s1 = 0.f, s2 = 0.f, s3 = 0.f;
    float q0 = 0.f, q1 = 0.f, q2 = 0.f, q3 = 0.f;
    for (int r = blockIdx.x * 8 + s; r < Nn; r += NSTATB * 8) {
        uint2 v = HPu2[(size_t)r * 32 + li];
        float a = bflo(v.x), b = bfhi(v.x), c = bflo(v.y), d = bfhi(v.y);
        s0 += a; s1 += b; s2 += c; s3 += d;
        q0 = fmaf(a, a, q0); q1 = fmaf(b, b, q1);
        q2 = fmaf(c, c, q2); q3 = fmaf(d, d, q3);
    }
    __shared__ float arr[8 * 256];
    float* mine = &arr[s * 256 + li * 4];
    mine[0] = s0; mine[1] = s1; mine[2] = s2; mine[3] = s3;
    mine[128] = q0; mine[129] = q1; mine[130] = q2; mine[131] = q3;
    __syncthreads();
    float tot = 0.f;
#pragma unroll
    for (int k = 0; k < 8; ++k) tot += arr[k * 256 + tid];
    partials[blockIdx.x * 256 + tid] = tot;
}

// ---------------------------------------------------------------------------
// BN stats level 2 + bnfinal: 1 block x 1024 thr.
// ---------------------------------------------------------------------------
__global__ __launch_bounds__(1024) void k_statsB(const float* __restrict__ partials,
                                                 const float* __restrict__ g,
                                                 const float* __restrict__ bt,
                                                 float* __restrict__ bnp) {
    int tid = threadIdx.x;
    int sub = tid >> 8;
    int t = tid & 255;
    float acc = 0.f;
#pragma unroll 8
    for (int r = sub * 64; r < sub * 64 + 64; ++r)
        acc += partials[r * 256 + t];
    __shared__ float red[4 * 256];
    red[sub * 256 + t] = acc;
    __syncthreads();
    __shared__ float tot[256];
    if (tid < 256)
        tot[tid] = red[tid] + red[256 + tid] + red[512 + tid] + red[768 + tid];
    __syncthreads();
    if (tid < 128) {
        float mu  = tot[tid] * (1.0f / Nn);
        float var = tot[128 + tid] * (1.0f / Nn) - mu * mu;
        float sc  = g[tid] * rsqrtf(var + BN_EPS);
        bnp[tid]       = sc;
        bnp[128 + tid] = bt[tid] - mu * sc;
    }
}

// ---------------------------------------------------------------------------
// Fused BN+ReLU + mean-pool + FC1(relu) + FC2. One block (128 thr) per graph.
// ---------------------------------------------------------------------------
__global__ __launch_bounds__(128) void k_pool_fc(const ushort_t* __restrict__ HP16,
                                                 const float* __restrict__ bnp,
                                                 const int* __restrict__ batch,
                                                 const float* __restrict__ fcw1,
                                                 const float* __restrict__ fcb1,
                                                 const float* __restrict__ fcw2,
                                                 const float* __restrict__ fcb2,
                                                 float* __restrict__ out) {
    int g = blockIdx.x;
    int t = threadIdx.x;
    int lo = 0, hi = Nn;
    while (lo < hi) { int mid = (lo + hi) >> 1; if (batch[mid] < g) lo = mid + 1; else hi = mid; }
    int start = lo;
    hi = Nn;
    while (lo < hi) { int mid = (lo + hi) >> 1; if (batch[mid] < g + 1) lo = mid + 1; else hi = mid; }
    int end = lo;

    float sc = bnp[t], sh = bnp[128 + t];
    float acc = 0.f;
    for (int i = start; i < end; ++i) {
        union { uint32 u; float f; } c;
        c.u = (uint32)HP16[(size_t)i * 128 + t] << 16;
        acc += fmaxf(fmaf(c.f, sc, sh), 0.f);
    }
    float inv = 1.0f / fmaxf((float)(end - start), 1.0f);

    __shared__ float p[128];
    __shared__ float h1[64];
    p[t] = acc * inv;
    __syncthreads();
    if (t < 64) {
        float s = fcb1[t];
        for (int k = 0; k < 128; ++k) s = fmaf(p[k], fcw1[k * 64 + t], s);
        h1[t] = fmaxf(s, 0.f);
    }
    __syncthreads();
    if (t < 64) {
        float v = h1[t] * fcw2[t];
        for (int off = 32; off > 0; off >>= 1) v += __shfl_down(v, off, 64);
        if (t == 0) out[g] = v + fcb2[0];
    }
}

// ---------------------------------------------------------------------------
extern "C" void kernel_launch(void* const* d_in, const int* in_sizes, int n_in,
                              void* d_out, int out_size, void* d_ws, size_t ws_size,
                              hipStream_t stream) {
    const float* x     = (const float*)d_in[0];
    const int*   ei    = (const int*)d_in[1];
    const int*   batch = (const int*)d_in[2];
    const float* W1  = (const float*)d_in[3];
    const float* b1  = (const float*)d_in[4];
    const float* g1  = (const float*)d_in[5];
    const float* bt1 = (const float*)d_in[6];
    const float* W2  = (const float*)d_in[7];
    const float* b2  = (const float*)d_in[8];
    const float* g2  = (const float*)d_in[9];
    const float* bt2 = (const float*)d_in[10];
    const float* W3  = (const float*)d_in[11];
    const float* b3  = (const float*)d_in[12];
    const float* g3  = (const float*)d_in[13];
    const float* bt3 = (const float*)d_in[14];
    const float* fcw1 = (const float*)d_in[15];
    const float* fcb1 = (const float*)d_in[16];
    const float* fcw2 = (const float*)d_in[17];
    const float* fcb2 = (const float*)d_in[18];
    float* out = (float*)d_out;

    // Workspace layout
    uchar_t*  XW8     = (uchar_t*)d_ws;                       // [N*128] int8
    uint32*   HP32    = (uint32*)(XW8 + (size_t)Nn * HH);     // [N*64] bf16x2
    float*    sc_src  = (float*)(HP32 + (size_t)Nn * 64);     // [N]
    float*    dis     = sc_src + Nn;                          // [N]
    int*      rowptr  = (int*)(dis + Nn);                     // [N+1]
    int*      blkhist = rowptr + (Nn + 1);                    // [500*196]
    int*      blkoff_rel = blkhist + NBLK_E * NBK;            // [500*196]
    int*      total   = blkoff_rel + NBLK_E * NBK;            // [196]
    int*      bucket_base = total + NBK;                      // [196]
    uint32*   pairs   = (uint32*)(bucket_base + NBK);         // [E]
    int*      csr_src = (int*)(pairs + Ee);                   // [E]
    float*    partials = (float*)(csr_src + Ee);              // [256*256]
    float*    bnp     = partials + NSTATB * 256;              // [3*256]
    ushort_t* Wb      = (ushort_t*)(bnp + 768);               // [3*128*128]

    const int* src = ei;
    const int* dst = ei + Ee;

    k_count<<<NBLK_E, 256, 0, stream>>>(dst, blkhist);
    k_wprep<<<192, 256, 0, stream>>>(W1, W2, W3, Wb);
    k_bscan1<<<NBK, 512, 0, stream>>>(blkhist, blkoff_rel, total);
    k_bscan2<<<1, 256, 0, stream>>>(total, bucket_base);
    k_fill1<<<NBLK_E, 256, 0, stream>>>(src, dst, bucket_base, blkoff_rel, pairs);
    k_fill2<<<NBK, 1024, 0, stream>>>(bucket_base, total, pairs, csr_src, rowptr, dis);

    const float* bs_[3]  = {b1, b2, b3};
    const float* gs_[3]  = {g1, g2, g3};
    const float* bts_[3] = {bt1, bt2, bt3};
    const int ngemm = (Nn + 63) / 64;  // 1563
    for (int l = 0; l < 3; ++l) {
        const float* bnp_in = (l == 0) ? nullptr : (bnp + (l - 1) * 256);
        k_gemm<<<ngemm, 256, 0, stream>>>(x, HP32, Wb + l * 16384, bs_[l], bnp_in,
                                          dis, XW8, sc_src);
        k_agg<<<12500, 256, 0, stream>>>((const uint32*)XW8, sc_src, dis, rowptr,
                                         csr_src, HP32);
        k_statsA<<<NSTATB, 256, 0, stream>>>(HP32, partials);
        k_statsB<<<1, 1024, 0, stream>>>(partials, gs_[l], bts_[l], bnp + l * 256);
    }
    k_pool_fc<<<Gg, 128, 0, stream>>>((const ushort_t*)HP32, bnp + 512, batch,
                                      fcw1, fcb1, fcw2, fcb2, out);
}

// Round 12
// 307.579 us; speedup vs baseline: 2.8409x; 1.0114x over previous
//
#include <hip/hip_runtime.h>
#include <math.h>

#define Nn 100000
#define Ee 1600000
#define Gg 2048
#define HH 128
#define BN_EPS 1e-5f

#define NBK 196        // ceil(100000/512) buckets of 512 nodes
#define NBLK_E 500     // edge-pass blocks
#define CHUNK4 800     // int4s per block (500*3200 = 1.6M edges)
#define NSTATB 256     // stats level-1 blocks

typedef unsigned int uint32;
typedef unsigned char uchar_t;
typedef unsigned short ushort_t;
typedef __attribute__((ext_vector_type(8))) short short8_t;
typedef __attribute__((ext_vector_type(8))) unsigned short ushort8_t;
typedef __attribute__((ext_vector_type(4))) float f32x4_t;

__device__ __forceinline__ ushort_t f2bf(float f) {
    union { float f; uint32 u; } c; c.f = f;
    uint32 r = (c.u + 0x7FFFu + ((c.u >> 16) & 1u)) >> 16;   // RTNE
    return (ushort_t)r;
}
__device__ __forceinline__ float bflo(uint32 v) {
    union { uint32 u; float f; } c; c.u = v << 16; return c.f;
}
__device__ __forceinline__ float bfhi(uint32 v) {
    union { uint32 u; float f; } c; c.u = v & 0xFFFF0000u; return c.f;
}
__device__ __forceinline__ int q8(float f, float inv) {
    float t = f * inv;
    t = fmaxf(fminf(t, 127.f), -127.f);
    return (int)rintf(t);
}

// ---------------------------------------------------------------------------
// Count: per-BLOCK bucket histogram only. NO global atomics.
// ---------------------------------------------------------------------------
__global__ __launch_bounds__(256) void k_count(const int* __restrict__ dst,
                                               int* __restrict__ blkhist) {
    __shared__ unsigned h[NBK];
    int tid = threadIdx.x;
    for (int i = tid; i < NBK; i += 256) h[i] = 0;
    __syncthreads();
    const int4* d4 = (const int4*)dst + blockIdx.x * CHUNK4;
    for (int i = tid; i < CHUNK4; i += 256) {
        int4 v = d4[i];
        atomicAdd(&h[v.x >> 9], 1u);
        atomicAdd(&h[v.y >> 9], 1u);
        atomicAdd(&h[v.z >> 9], 1u);
        atomicAdd(&h[v.w >> 9], 1u);
    }
    __syncthreads();
    for (int i = tid; i < NBK; i += 256)
        blkhist[blockIdx.x * NBK + i] = (int)h[i];
}

// ---------------------------------------------------------------------------
// Scan blkhist across blocks (one workgroup per bucket).
// ---------------------------------------------------------------------------
__global__ __launch_bounds__(512) void k_bscan1(const int* __restrict__ blkhist,
                                                int* __restrict__ blkoff_rel,
                                                int* __restrict__ total) {
    __shared__ int tmp[512];
    int bucket = blockIdx.x;
    int t = threadIdx.x;
    int v = (t < NBLK_E) ? blkhist[t * NBK + bucket] : 0;
    tmp[t] = v;
    __syncthreads();
    for (int off = 1; off < 512; off <<= 1) {
        int u = (t >= off) ? tmp[t - off] : 0;
        __syncthreads();
        tmp[t] += u;
        __syncthreads();
    }
    if (t < NBLK_E) blkoff_rel[t * NBK + bucket] = tmp[t] - v;
    if (t == 511) total[bucket] = tmp[t];
}

// Exclusive scan of bucket totals -> bucket_base.
__global__ void k_bscan2(const int* __restrict__ total,
                         int* __restrict__ bucket_base) {
    __shared__ int tmp[256];
    int t = threadIdx.x;  // 256 >= NBK
    int v = (t < NBK) ? total[t] : 0;
    tmp[t] = v;
    __syncthreads();
    for (int off = 1; off < 256; off <<= 1) {
        int u = (t >= off) ? tmp[t - off] : 0;
        __syncthreads();
        tmp[t] += u;
        __syncthreads();
    }
    if (t < NBK) bucket_base[t] = tmp[t] - v;
}

// ---------------------------------------------------------------------------
// Fill pass 1: counting-sort append; LDS atomics only, contiguous runs.
// ---------------------------------------------------------------------------
__global__ __launch_bounds__(256) void k_fill1(const int* __restrict__ src,
                                               const int* __restrict__ dst,
                                               const int* __restrict__ bucket_base,
                                               const int* __restrict__ blkoff_rel,
                                               uint32* __restrict__ pairs) {
    __shared__ int loff[NBK];
    __shared__ unsigned lh[NBK];
    int tid = threadIdx.x;
    for (int i = tid; i < NBK; i += 256) {
        loff[i] = bucket_base[i] + blkoff_rel[blockIdx.x * NBK + i];
        lh[i] = 0;
    }
    __syncthreads();
    const int4* s4 = (const int4*)src + blockIdx.x * CHUNK4;
    const int4* d4 = (const int4*)dst + blockIdx.x * CHUNK4;
    for (int i = tid; i < CHUNK4; i += 256) {
        int4 s = s4[i];
        int4 d = d4[i];
        int b0 = d.x >> 9; int r0 = (int)atomicAdd(&lh[b0], 1u);
        pairs[loff[b0] + r0] = ((uint32)(d.x & 511) << 17) | (uint32)s.x;
        int b1 = d.y >> 9; int r1 = (int)atomicAdd(&lh[b1], 1u);
        pairs[loff[b1] + r1] = ((uint32)(d.y & 511) << 17) | (uint32)s.y;
        int b2 = d.z >> 9; int r2 = (int)atomicAdd(&lh[b2], 1u);
        pairs[loff[b2] + r2] = ((uint32)(d.z & 511) << 17) | (uint32)s.z;
        int b3 = d.w >> 9; int r3 = (int)atomicAdd(&lh[b3], 1u);
        pairs[loff[b3] + r3] = ((uint32)(d.w & 511) << 17) | (uint32)s.w;
    }
}

// ---------------------------------------------------------------------------
// Fill pass 2: one block (1024 thr) per bucket.
// Pass A: count per-node via LDS; scan -> rowptr + dis. Pass B: scatter.
// ---------------------------------------------------------------------------
__global__ __launch_bounds__(1024) void k_fill2(const int* __restrict__ bucket_base,
                                                const int* __restrict__ total,
                                                const uint32* __restrict__ pairs,
                                                int* __restrict__ csr_src,
                                                int* __restrict__ rowptr,
                                                float* __restrict__ dis) {
    __shared__ unsigned lcnt[512];
    __shared__ int tmp[512];
    __shared__ int lcur[512];
    int b = blockIdx.x;
    int node0 = b * 512;
    int tid = threadIdx.x;
    for (int i = tid; i < 512; i += 1024) lcnt[i] = 0;
    __syncthreads();
    int beg = bucket_base[b];
    int endp = beg + total[b];
    for (int j = beg + tid; j < endp; j += 1024)
        atomicAdd(&lcnt[pairs[j] >> 17], 1u);
    __syncthreads();
    if (tid < 512) tmp[tid] = (int)lcnt[tid];
    __syncthreads();
    for (int off = 1; off < 512; off <<= 1) {
        int u = (tid < 512 && tid >= off) ? tmp[tid - off] : 0;
        __syncthreads();
        if (tid < 512) tmp[tid] += u;
        __syncthreads();
    }
    if (tid < 512) {
        int excl = tmp[tid] - (int)lcnt[tid];
        int n = node0 + tid;
        if (n <= Nn) rowptr[n] = beg + excl;
        if (n < Nn) dis[n] = rsqrtf((float)lcnt[tid] + 1.0f);
        lcur[tid] = beg + excl;
    }
    __syncthreads();
    for (int j = beg + tid; j < endp; j += 1024) {
        uint32 p = pairs[j];
        int dl = (int)(p >> 17);
        int s = (int)(p & 0x1FFFFu);
        int pos = atomicAdd(&lcur[dl], 1);
        csr_src[pos] = s;
    }
}

// ---------------------------------------------------------------------------
// W prep: Wb[l][col][k] = bf16(Wl[k][col]) once per call (3 layers).
// ---------------------------------------------------------------------------
__global__ __launch_bounds__(256) void k_wprep(const float* __restrict__ W1,
                                               const float* __restrict__ W2,
                                               const float* __restrict__ W3,
                                               ushort_t* __restrict__ Wb) {
    int l = blockIdx.x >> 6, part = blockIdx.x & 63;
    const float* W = (l == 0) ? W1 : (l == 1) ? W2 : W3;
    int i = part * 256 + threadIdx.x;
    int k = i >> 7, col = i & 127;
    Wb[l * 16384 + col * 128 + k] = f2bf(W[k * 128 + col]);
}

// ---------------------------------------------------------------------------
// MFMA GEMM: XW' = dis * (Xin @ W + b), int8 out with per-row scale.
// One 64-row tile per block. Epilogue: row-max via shfl, bf16 LDS transpose,
// quantize on coalesced store (rows = exactly one 128B line).
// ---------------------------------------------------------------------------
__global__ __launch_bounds__(256) void k_gemm(const float* __restrict__ Xf,
                                              const uint32* __restrict__ Xb,
                                              const ushort_t* __restrict__ Wb,
                                              const float* __restrict__ Bv,
                                              const float* __restrict__ bnp,
                                              const float* __restrict__ dis,
                                              uchar_t* __restrict__ XW8,
                                              float* __restrict__ sc_src) {
    __shared__ ushort_t Wlds[128 * 136];
    __shared__ ushort_t Xlds[64 * 136];
    __shared__ float smax[64];
    const int tid = threadIdx.x;
    const int rowbase = blockIdx.x * 64;

    // Stage W from pre-converted bf16 (coalesced 16B copies)
#pragma unroll
    for (int it = 0; it < 8; ++it) {
        int chunk = tid + it * 256;
        int col = chunk >> 4, kg = chunk & 15;
        *(ushort8_t*)&Wlds[col * 136 + kg * 8] =
            *(const ushort8_t*)&Wb[col * 128 + kg * 8];
    }
    // Stage X tile (64 rows x 128), fused BN+ReLU on bf16 path
    {
        int row = tid >> 2, q = tid & 3;
        int g = rowbase + row;
        if (bnp == nullptr) {
            const float4* Xr = (const float4*)(Xf + (size_t)g * 128);
#pragma unroll
            for (int it = 0; it < 8; ++it) {
                int c4 = q + it * 4;
                float4 v;
                if (g < Nn) v = Xr[c4];
                else { v.x = v.y = v.z = v.w = 0.f; }
                ushort4 o;
                o.x = f2bf(v.x); o.y = f2bf(v.y); o.z = f2bf(v.z); o.w = f2bf(v.w);
                *(ushort4*)&Xlds[row * 136 + c4 * 4] = o;
            }
        } else {
            const uint4* Hr = (const uint4*)(Xb + (size_t)g * 64);
#pragma unroll
            for (int it = 0; it < 4; ++it) {
                int i4 = q + it * 4;
                int c0 = i4 * 8;
                ushort8_t o;
                if (g < Nn) {
                    uint4 u = Hr[i4];
                    float4 sca = *(const float4*)&bnp[c0];
                    float4 scb = *(const float4*)&bnp[c0 + 4];
                    float4 sha = *(const float4*)&bnp[128 + c0];
                    float4 shb = *(const float4*)&bnp[128 + c0 + 4];
                    o[0] = f2bf(fmaxf(fmaf(bflo(u.x), sca.x, sha.x), 0.f));
                    o[1] = f2bf(fmaxf(fmaf(bfhi(u.x), sca.y, sha.y), 0.f));
                    o[2] = f2bf(fmaxf(fmaf(bflo(u.y), sca.z, sha.z), 0.f));
                    o[3] = f2bf(fmaxf(fmaf(bfhi(u.y), sca.w, sha.w), 0.f));
                    o[4] = f2bf(fmaxf(fmaf(bflo(u.z), scb.x, shb.x), 0.f));
                    o[5] = f2bf(fmaxf(fmaf(bfhi(u.z), scb.y, shb.y), 0.f));
                    o[6] = f2bf(fmaxf(fmaf(bflo(u.w), scb.z, shb.z), 0.f));
                    o[7] = f2bf(fmaxf(fmaf(bfhi(u.w), scb.w, shb.w), 0.f));
                } else {
                    for (int j = 0; j < 8; ++j) o[j] = 0;
                }
                *(ushort8_t*)&Xlds[row * 136 + c0] = o;
            }
        }
    }
    __syncthreads();

    const int wid = tid >> 6, lane = tid & 63;
    const int arow = wid * 16 + (lane & 15);
    const int koff = (lane >> 4) * 8;
    const int bcol = lane & 15;

    f32x4_t acc[8];
#pragma unroll
    for (int nt = 0; nt < 8; ++nt) acc[nt] = (f32x4_t){0.f, 0.f, 0.f, 0.f};

#pragma unroll
    for (int kt = 0; kt < 4; ++kt) {
        short8_t a = *(const short8_t*)&Xlds[arow * 136 + kt * 32 + koff];
#pragma unroll
        for (int nt = 0; nt < 8; ++nt) {
            short8_t b = *(const short8_t*)&Wlds[(nt * 16 + bcol) * 136 + kt * 32 + koff];
            acc[nt] = __builtin_amdgcn_mfma_f32_16x16x32_bf16(a, b, acc[nt], 0, 0, 0);
        }
    }

    // Epilogue: v = (acc + bias) * dis; row-max via shfl; bf16 into Xlds.
    int er = wid * 16 + (lane >> 4) * 4;
    int r0 = rowbase + er;
    float dv[4];
#pragma unroll
    for (int i = 0; i < 4; ++i) dv[i] = (r0 + i < Nn) ? dis[r0 + i] : 0.f;
    __syncthreads();   // A-fragment reads done; safe to overwrite Xlds
    float bs[8];
#pragma unroll
    for (int nt = 0; nt < 8; ++nt) bs[nt] = Bv[nt * 16 + bcol];
#pragma unroll
    for (int i = 0; i < 4; ++i) {
        float m = 0.f;
#pragma unroll
        for (int nt = 0; nt < 8; ++nt) {
            float v = (acc[nt][i] + bs[nt]) * dv[i];
            m = fmaxf(m, fabsf(v));
            Xlds[(er + i) * 136 + nt * 16 + bcol] = f2bf(v);
        }
        m = fmaxf(m, __shfl_xor(m, 1));
        m = fmaxf(m, __shfl_xor(m, 2));
        m = fmaxf(m, __shfl_xor(m, 4));
        m = fmaxf(m, __shfl_xor(m, 8));
        if (bcol == 0) smax[er + i] = m;
    }
    __syncthreads();
    // Store phase: quantize bf16 tile to int8 rows (128B = 1 line) + scale.
#pragma unroll
    for (int it = 0; it < 4; ++it) {
        int chunk = tid + it * 256;      // 1024 chunks of 8 bytes
        int row = chunk >> 4, cg = chunk & 15;
        int g = rowbase + row;
        if (g < Nn) {
            float mx = smax[row];
            float inv = (mx > 0.f) ? (127.0f / mx) : 0.f;
            uint4 u = *(const uint4*)&Xlds[row * 136 + cg * 8];
            int b0 = q8(bflo(u.x), inv), b1 = q8(bfhi(u.x), inv);
            int b2 = q8(bflo(u.y), inv), b3 = q8(bfhi(u.y), inv);
            int b4 = q8(bflo(u.z), inv), b5 = q8(bfhi(u.z), inv);
            int b6 = q8(bflo(u.w), inv), b7 = q8(bfhi(u.w), inv);
            uint2 o;
            o.x = (uint32)(b0 & 255) | ((uint32)(b1 & 255) << 8) |
                  ((uint32)(b2 & 255) << 16) | ((uint32)(b3 & 255) << 24);
            o.y = (uint32)(b4 & 255) | ((uint32)(b5 & 255) << 8) |
                  ((uint32)(b6 & 255) << 16) | ((uint32)(b7 & 255) << 24);
            *(uint2*)&XW8[(size_t)g * 128 + cg * 8] = o;
            if (cg == 0) sc_src[g] = mx * (1.0f / 127.0f);
        }
    }
}

// ---------------------------------------------------------------------------
// Aggregate: HP[i] = dis[i]*(sum XW'[src] + XW'[i]); bf16 out.
// int8 rows (128B = 1 line); 2 nodes per wave, 4B/lane. (idx,scale) pairs
// staged in LDS. Inner loop 4-deep phase-separated: 4 pair reads, 4
// independent gathers in flight, then dequant -> restores MLP.
// ---------------------------------------------------------------------------
__global__ __launch_bounds__(256) void k_agg(const uint32* __restrict__ XW32,
                                             const float* __restrict__ sc_src,
                                             const float* __restrict__ dis,
                                             const int* __restrict__ rowptr,
                                             const int* __restrict__ csr_src,
                                             uint32* __restrict__ HP32) {
    __shared__ uint2 spair[256];
    int w = threadIdx.x >> 6;
    int lane = threadIdx.x & 63;
    int half = lane >> 5, li = lane & 31;
    int node = (blockIdx.x * 4 + w) * 2 + half;
    int beg = rowptr[node], end = rowptr[node + 1];
    uint2* wpair = &spair[w * 64];
    float a0 = 0.f, a1 = 0.f, a2 = 0.f, a3 = 0.f;
    int base = beg;
    while (__any(base < end)) {
        int j = base + li;
        if (j < end) {
            int s = csr_src[j];
            float sc = sc_src[s];
            uint2 p; p.x = (uint32)s; p.y = __float_as_uint(sc);
            wpair[lane] = p;
        }
        __builtin_amdgcn_wave_barrier();
        int m = end - base; m = (m > 32) ? 32 : m;
        int k = 0;
        for (; k + 4 <= m; k += 4) {
            uint2 p0 = wpair[half * 32 + k + 0];
            uint2 p1 = wpair[half * 32 + k + 1];
            uint2 p2 = wpair[half * 32 + k + 2];
            uint2 p3 = wpair[half * 32 + k + 3];
            uint32 u0 = XW32[(size_t)p0.x * 32 + li];
            uint32 u1 = XW32[(size_t)p1.x * 32 + li];
            uint32 u2 = XW32[(size_t)p2.x * 32 + li];
            uint32 u3 = XW32[(size_t)p3.x * 32 + li];
            float c0 = __uint_as_float(p0.y);
            float c1 = __uint_as_float(p1.y);
            float c2 = __uint_as_float(p2.y);
            float c3 = __uint_as_float(p3.y);
            a0 = fmaf((float)((int)(u0 << 24) >> 24), c0, a0);
            a1 = fmaf((float)((int)(u0 << 16) >> 24), c0, a1);
            a2 = fmaf((float)((int)(u0 <<  8) >> 24), c0, a2);
            a3 = fmaf((float)((int)u0 >> 24),          c0, a3);
            a0 = fmaf((float)((int)(u1 << 24) >> 24), c1, a0);
            a1 = fmaf((float)((int)(u1 << 16) >> 24), c1, a1);
            a2 = fmaf((float)((int)(u1 <<  8) >> 24), c1, a2);
            a3 = fmaf((float)((int)u1 >> 24),          c1, a3);
            a0 = fmaf((float)((int)(u2 << 24) >> 24), c2, a0);
            a1 = fmaf((float)((int)(u2 << 16) >> 24), c2, a1);
            a2 = fmaf((float)((int)(u2 <<  8) >> 24), c2, a2);
            a3 = fmaf((float)((int)u2 >> 24),          c2, a3);
            a0 = fmaf((float)((int)(u3 << 24) >> 24), c3, a0);
            a1 = fmaf((float)((int)(u3 << 16) >> 24), c3, a1);
            a2 = fmaf((float)((int)(u3 <<  8) >> 24), c3, a2);
            a3 = fmaf((float)((int)u3 >> 24),          c3, a3);
        }
        for (; k < m; ++k) {
            uint2 p = wpair[half * 32 + k];
            uint32 u = XW32[(size_t)p.x * 32 + li];
            float sc = __uint_as_float(p.y);
            a0 = fmaf((float)((int)(u << 24) >> 24), sc, a0);
            a1 = fmaf((float)((int)(u << 16) >> 24), sc, a1);
            a2 = fmaf((float)((int)(u <<  8) >> 24), sc, a2);
            a3 = fmaf((float)((int)u >> 24),          sc, a3);
        }
        base += 32;
        __builtin_amdgcn_wave_barrier();
    }
    {   // self term
        uint32 u = XW32[(size_t)node * 32 + li];
        float sc = sc_src[node];
        a0 = fmaf((float)((int)(u << 24) >> 24), sc, a0);
        a1 = fmaf((float)((int)(u << 16) >> 24), sc, a1);
        a2 = fmaf((float)((int)(u <<  8) >> 24), sc, a2);
        a3 = fmaf((float)((int)u >> 24),          sc, a3);
    }
    float d = dis[node];
    uint2 r;
    r.x = (uint32)f2bf(a0 * d) | ((uint32)f2bf(a1 * d) << 16);
    r.y = (uint32)f2bf(a2 * d) | ((uint32)f2bf(a3 * d) << 16);
    ((uint2*)HP32)[(size_t)node * 32 + li] = r;
}

// ---------------------------------------------------------------------------
// BN stats level 1: 256 blocks; register accum; LDS reduce; ONE coalesced
// partials-row write per block. Zero global atomics.
// ---------------------------------------------------------------------------
__global__ __launch_bounds__(256) void k_statsA(const uint32* __restrict__ HP32,
                                                float* __restrict__ partials) {
    const uint2* HPu2 = (const uint2*)HP32;
    int tid = threadIdx.x;
    int li = tid & 31;
    int s  = tid >> 5;
    float s0 = 0.f, s1 = 0.f, s2 = 0.f, s3 = 0.f;
    float q0 = 0.f, q1 = 0.f, q2 = 0.f, q3 = 0.f;
    for (int r = blockIdx.x * 8 + s; r < Nn; r += NSTATB * 8) {
        uint2 v = HPu2[(size_t)r * 32 + li];
        float a = bflo(v.x), b = bfhi(v.x), c = bflo(v.y), d = bfhi(v.y);
        s0 += a; s1 += b; s2 += c; s3 += d;
        q0 = fmaf(a, a, q0); q1 = fmaf(b, b, q1);
        q2 = fmaf(c, c, q2); q3 = fmaf(d, d, q3);
    }
    __shared__ float arr[8 * 256];
    float* mine = &arr[s * 256 + li * 4];
    mine[0] = s0; mine[1] = s1; mine[2] = s2; mine[3] = s3;
    mine[128] = q0; mine[129] = q1; mine[130] = q2; mine[131] = q3;
    __syncthreads();
    float tot = 0.f;
#pragma unroll
    for (int k = 0; k < 8; ++k) tot += arr[k * 256 + tid];
    partials[blockIdx.x * 256 + tid] = tot;
}

// ---------------------------------------------------------------------------
// BN stats level 2 + bnfinal: 1 block x 1024 thr.
// ---------------------------------------------------------------------------
__global__ __launch_bounds__(1024) void k_statsB(const float* __restrict__ partials,
                                                 const float* __restrict__ g,
                                                 const float* __restrict__ bt,
                                                 float* __restrict__ bnp) {
    int tid = threadIdx.x;
    int sub = tid >> 8;
    int t = tid & 255;
    float acc = 0.f;
#pragma unroll 8
    for (int r = sub * 64; r < sub * 64 + 64; ++r)
        acc += partials[r * 256 + t];
    __shared__ float red[4 * 256];
    red[sub * 256 + t] = acc;
    __syncthreads();
    __shared__ float tot[256];
    if (tid < 256)
        tot[tid] = red[tid] + red[256 + tid] + red[512 + tid] + red[768 + tid];
    __syncthreads();
    if (tid < 128) {
        float mu  = tot[tid] * (1.0f / Nn);
        float var = tot[128 + tid] * (1.0f / Nn) - mu * mu;
        float sc  = g[tid] * rsqrtf(var + BN_EPS);
        bnp[tid]       = sc;
        bnp[128 + tid] = bt[tid] - mu * sc;
    }
}

// ---------------------------------------------------------------------------
// Fused BN+ReLU + mean-pool + FC1(relu) + FC2. One block (128 thr) per graph.
// ---------------------------------------------------------------------------
__global__ __launch_bounds__(128) void k_pool_fc(const ushort_t* __restrict__ HP16,
                                                 const float* __restrict__ bnp,
                                                 const int* __restrict__ batch,
                                                 const float* __restrict__ fcw1,
                                                 const float* __restrict__ fcb1,
                                                 const float* __restrict__ fcw2,
                                                 const float* __restrict__ fcb2,
                                                 float* __restrict__ out) {
    int g = blockIdx.x;
    int t = threadIdx.x;
    int lo = 0, hi = Nn;
    while (lo < hi) { int mid = (lo + hi) >> 1; if (batch[mid] < g) lo = mid + 1; else hi = mid; }
    int start = lo;
    hi = Nn;
    while (lo < hi) { int mid = (lo + hi) >> 1; if (batch[mid] < g + 1) lo = mid + 1; else hi = mid; }
    int end = lo;

    float sc = bnp[t], sh = bnp[128 + t];
    float acc = 0.f;
    for (int i = start; i < end; ++i) {
        union { uint32 u; float f; } c;
        c.u = (uint32)HP16[(size_t)i * 128 + t] << 16;
        acc += fmaxf(fmaf(c.f, sc, sh), 0.f);
    }
    float inv = 1.0f / fmaxf((float)(end - start), 1.0f);

    __shared__ float p[128];
    __shared__ float h1[64];
    p[t] = acc * inv;
    __syncthreads();
    if (t < 64) {
        float s = fcb1[t];
        for (int k = 0; k < 128; ++k) s = fmaf(p[k], fcw1[k * 64 + t], s);
        h1[t] = fmaxf(s, 0.f);
    }
    __syncthreads();
    if (t < 64) {
        float v = h1[t] * fcw2[t];
        for (int off = 32; off > 0; off >>= 1) v += __shfl_down(v, off, 64);
        if (t == 0) out[g] = v + fcb2[0];
    }
}

// ---------------------------------------------------------------------------
extern "C" void kernel_launch(void* const* d_in, const int* in_sizes, int n_in,
                              void* d_out, int out_size, void* d_ws, size_t ws_size,
                              hipStream_t stream) {
    const float* x     = (const float*)d_in[0];
    const int*   ei    = (const int*)d_in[1];
    const int*   batch = (const int*)d_in[2];
    const float* W1  = (const float*)d_in[3];
    const float* b1  = (const float*)d_in[4];
    const float* g1  = (const float*)d_in[5];
    const float* bt1 = (const float*)d_in[6];
    const float* W2  = (const float*)d_in[7];
    const float* b2  = (const float*)d_in[8];
    const float* g2  = (const float*)d_in[9];
    const float* bt2 = (const float*)d_in[10];
    const float* W3  = (const float*)d_in[11];
    const float* b3  = (const float*)d_in[12];
    const float* g3  = (const float*)d_in[13];
    const float* bt3 = (const float*)d_in[14];
    const float* fcw1 = (const float*)d_in[15];
    const float* fcb1 = (const float*)d_in[16];
    const float* fcw2 = (const float*)d_in[17];
    const float* fcb2 = (const float*)d_in[18];
    float* out = (float*)d_out;

    // Workspace layout
    uchar_t*  XW8     = (uchar_t*)d_ws;                       // [N*128] int8
    uint32*   HP32    = (uint32*)(XW8 + (size_t)Nn * HH);     // [N*64] bf16x2
    float*    sc_src  = (float*)(HP32 + (size_t)Nn * 64);     // [N]
    float*    dis     = sc_src + Nn;                          // [N]
    int*      rowptr  = (int*)(dis + Nn);                     // [N+1]
    int*      blkhist = rowptr + (Nn + 1);                    // [500*196]
    int*      blkoff_rel = blkhist + NBLK_E * NBK;            // [500*196]
    int*      total   = blkoff_rel + NBLK_E * NBK;            // [196]
    int*      bucket_base = total + NBK;                      // [196]
    uint32*   pairs   = (uint32*)(bucket_base + NBK);         // [E]
    int*      csr_src = (int*)(pairs + Ee);                   // [E]
    float*    partials = (float*)(csr_src + Ee);              // [256*256]
    float*    bnp     = partials + NSTATB * 256;              // [3*256]
    ushort_t* Wb      = (ushort_t*)(bnp + 768);               // [3*128*128]

    const int* src = ei;
    const int* dst = ei + Ee;

    k_count<<<NBLK_E, 256, 0, stream>>>(dst, blkhist);
    k_wprep<<<192, 256, 0, stream>>>(W1, W2, W3, Wb);
    k_bscan1<<<NBK, 512, 0, stream>>>(blkhist, blkoff_rel, total);
    k_bscan2<<<1, 256, 0, stream>>>(total, bucket_base);
    k_fill1<<<NBLK_E, 256, 0, stream>>>(src, dst, bucket_base, blkoff_rel, pairs);
    k_fill2<<<NBK, 1024, 0, stream>>>(bucket_base, total, pairs, csr_src, rowptr, dis);

    const float* bs_[3]  = {b1, b2, b3};
    const float* gs_[3]  = {g1, g2, g3};
    const float* bts_[3] = {bt1, bt2, bt3};
    const int ngemm = (Nn + 63) / 64;  // 1563
    for (int l = 0; l < 3; ++l) {
        const float* bnp_in = (l == 0) ? nullptr : (bnp + (l - 1) * 256);
        k_gemm<<<ngemm, 256, 0, stream>>>(x, HP32, Wb + l * 16384, bs_[l], bnp_in,
                                          dis, XW8, sc_src);
        k_agg<<<12500, 256, 0, stream>>>((const uint32*)XW8, sc_src, dis, rowptr,
                                         csr_src, HP32);
        k_statsA<<<NSTATB, 256, 0, stream>>>(HP32, partials);
        k_statsB<<<1, 1024, 0, stream>>>(partials, gs_[l], bts_[l], bnp + l * 256);
    }
    k_pool_fc<<<Gg, 128, 0, stream>>>((const ushort_t*)HP32, bnp + 512, batch,
                                      fcw1, fcb1, fcw2, fcb2, out);
}